// Round 4
// baseline (12073.779 us; speedup 1.0000x reference)
//
#include <hip/hip_runtime.h>

#define NB 8192
#define NH 512
#define NZ 128
#define NIN 128
#define NN 512
#define NRW 16
#define NG 2048   // 4*NH

typedef _Float16 f16;
typedef _Float16 f16x8 __attribute__((ext_vector_type(8)));
typedef float f32x4 __attribute__((ext_vector_type(4)));

#define LO_SCALE 2048.0f
#define LO_INV   (1.0f / 2048.0f)

__device__ __forceinline__ float sigm(float x) { return 1.0f / (1.0f + expf(-x)); }

// ---------------- split-f16 MFMA GEMM ----------------
// C[M][N] = (Ahi+Alo/2048)[M][K] @ (Bhi+Blo/2048)[N][K]^T + bias + extra[eidx[row]]
// A stored row-major [M][K] f16 (K-major); B stored [N][K] f16 (K-major).
// 128x128 tile, 4 waves, mfma_f32_16x16x32_f16, BK=32, double-buffered LDS.

__device__ __forceinline__ void stage_tile(f16* __restrict__ sbuf,
                                           const f16* __restrict__ src,
                                           int rowbase, int K, int kb,
                                           int wid, int lane)
{
#pragma unroll
    for (int q = 0; q < 2; ++q) {
        const int lin = (((wid << 1) | q) << 6) | lane;  // 0..511
        const int row = lin >> 2;
        const int p = lin & 3;                            // global 16B slot
        const int sw = p ^ ((row >> 1) & 3);              // swizzled LDS slot
        const f16x8 v = *(const f16x8*)(src + (size_t)(rowbase + row) * K + kb + (p << 3));
        *(f16x8*)(sbuf + row * 32 + (sw << 3)) = v;
    }
}

__device__ __forceinline__ void comp_step(const f16* __restrict__ sAb,
                                          const f16* __restrict__ sBb,
                                          int wr, int wc, int lane,
                                          f32x4 (&acc)[4][4])
{
    const int r16 = lane & 15;
    const int sl = lane >> 4;
    f16x8 af[4], bf[4];
#pragma unroll
    for (int f = 0; f < 4; ++f) {
        const int arow = wr + f * 16 + r16;
        af[f] = *(const f16x8*)(sAb + arow * 32 + ((sl ^ ((arow >> 1) & 3)) << 3));
        const int brow = wc + f * 16 + r16;
        bf[f] = *(const f16x8*)(sBb + brow * 32 + ((sl ^ ((brow >> 1) & 3)) << 3));
    }
#pragma unroll
    for (int i = 0; i < 4; ++i)
#pragma unroll
        for (int j = 0; j < 4; ++j)
            acc[i][j] = __builtin_amdgcn_mfma_f32_16x16x32_f16(af[i], bf[j], acc[i][j], 0, 0, 0);
}

template<int HAS_EXTRA>
__global__ __launch_bounds__(256)
void mfma_split_gemm(const f16* __restrict__ Ahi, const f16* __restrict__ Alo,
                     const f16* __restrict__ Bhi, const f16* __restrict__ Blo,
                     const float* __restrict__ bias,
                     const float* __restrict__ extra, const int* __restrict__ eidx,
                     float* __restrict__ C, int N, int K)
{
    __shared__ f16 sA[2][128 * 32];
    __shared__ f16 sB[2][128 * 32];
    const int bm = blockIdx.y << 7;
    const int bn = blockIdx.x << 7;
    const int tid = threadIdx.x;
    const int wid = tid >> 6, lane = tid & 63;
    const int wr = ((wid >> 1) & 1) << 6;
    const int wc = (wid & 1) << 6;

    f32x4 accA[4][4];
    f32x4 accB[4][4];
#pragma unroll
    for (int i = 0; i < 4; ++i)
#pragma unroll
        for (int j = 0; j < 4; ++j) {
            accA[i][j] = (f32x4)(0.0f);
            accB[i][j] = (f32x4)(0.0f);
        }

    const int K1 = K >> 5;        // steps per phase
    const int NS = 3 * K1;

    stage_tile(sA[0], Ahi, bm, K, 0, wid, lane);
    stage_tile(sB[0], Bhi, bn, K, 0, wid, lane);

    for (int s = 0; s < NS; ++s) {
        const int cur = s & 1;
        const int nxt = s + 1;
        if (nxt < NS) {
            const f16* An;
            const f16* Bn;
            int kk;
            if (nxt < K1)            { An = Ahi; Bn = Bhi; kk = nxt << 5; }
            else if (nxt < 2 * K1)   { An = Alo; Bn = Bhi; kk = (nxt - K1) << 5; }
            else                     { An = Ahi; Bn = Blo; kk = (nxt - 2 * K1) << 5; }
            stage_tile(sA[cur ^ 1], An, bm, K, kk, wid, lane);
            stage_tile(sB[cur ^ 1], Bn, bn, K, kk, wid, lane);
        }
        __syncthreads();
        if (s < K1) comp_step(sA[cur], sB[cur], wr, wc, lane, accA);
        else        comp_step(sA[cur], sB[cur], wr, wc, lane, accB);
    }

    // epilogue
    const int r16 = lane & 15;
    const int rg = lane >> 4;
#pragma unroll
    for (int i = 0; i < 4; ++i) {
#pragma unroll
        for (int r = 0; r < 4; ++r) {
            const int row = bm + wr + i * 16 + rg * 4 + r;
            const float* exrow = nullptr;
            if (HAS_EXTRA) {
                const int e = eidx ? eidx[row] : row;
                exrow = extra + (size_t)e * N;
            }
#pragma unroll
            for (int j = 0; j < 4; ++j) {
                const int col = bn + wc + j * 16 + r16;
                float v = accA[i][j][r] + accB[i][j][r] * LO_INV;
                if (bias) v += bias[col];
                if (HAS_EXTRA) v += exrow[col];
                C[(size_t)row * N + col] = v;
            }
        }
    }
}

// ---------------- f32 vector GEMM (prep/init only) ----------------
template<int ACT>
__global__ __launch_bounds__(256)
void gemm128(const float* __restrict__ A, int lda,
             const float* __restrict__ W, int ldw,
             const float* __restrict__ bias,
             float* __restrict__ C, int ldc, int K)
{
    __shared__ float As[16][128];
    __shared__ float Bs[16][128];
    const int bm = blockIdx.y << 7, bn = blockIdx.x << 7;
    const int tid = threadIdx.x;
    const int tx = tid & 15, ty = tid >> 4;
    const int sar = tid >> 1, sac = (tid & 1) << 3;
    const int sbk = tid >> 4, sbc = (tid & 15) << 3;
    float acc[2][2][4][4] = {};
    const float* Ap = A + (size_t)(bm + sar) * lda + sac;
    const float* Wp = W + (size_t)sbk * ldw + bn + sbc;
    for (int kb = 0; kb < K; kb += 16) {
        const float4 av0 = *(const float4*)(Ap + kb);
        const float4 av1 = *(const float4*)(Ap + kb + 4);
        const float4 bv0 = *(const float4*)(Wp + (size_t)kb * ldw);
        const float4 bv1 = *(const float4*)(Wp + (size_t)kb * ldw + 4);
        __syncthreads();
        As[sac + 0][sar] = av0.x; As[sac + 1][sar] = av0.y;
        As[sac + 2][sar] = av0.z; As[sac + 3][sar] = av0.w;
        As[sac + 4][sar] = av1.x; As[sac + 5][sar] = av1.y;
        As[sac + 6][sar] = av1.z; As[sac + 7][sar] = av1.w;
        *(float4*)&Bs[sbk][sbc] = bv0;
        *(float4*)&Bs[sbk][sbc + 4] = bv1;
        __syncthreads();
#pragma unroll
        for (int kk = 0; kk < 16; ++kk) {
            float a[2][4], b[2][4];
            *(float4*)a[0] = *(const float4*)&As[kk][ty << 2];
            *(float4*)a[1] = *(const float4*)&As[kk][64 + (ty << 2)];
            *(float4*)b[0] = *(const float4*)&Bs[kk][tx << 2];
            *(float4*)b[1] = *(const float4*)&Bs[kk][64 + (tx << 2)];
#pragma unroll
            for (int rh = 0; rh < 2; ++rh)
#pragma unroll
                for (int ch = 0; ch < 2; ++ch)
#pragma unroll
                    for (int i = 0; i < 4; ++i)
#pragma unroll
                        for (int j = 0; j < 4; ++j)
                            acc[rh][ch][i][j] = fmaf(a[rh][i], b[ch][j], acc[rh][ch][i][j]);
        }
    }
    float4 bi4[2] = {make_float4(0.f, 0.f, 0.f, 0.f), make_float4(0.f, 0.f, 0.f, 0.f)};
    if (bias) {
        bi4[0] = *(const float4*)(bias + bn + (tx << 2));
        bi4[1] = *(const float4*)(bias + bn + 64 + (tx << 2));
    }
#pragma unroll
    for (int rh = 0; rh < 2; ++rh)
#pragma unroll
        for (int i = 0; i < 4; ++i) {
            const int row = bm + rh * 64 + (ty << 2) + i;
#pragma unroll
            for (int ch = 0; ch < 2; ++ch) {
                const int col = bn + ch * 64 + (tx << 2);
                float v0 = acc[rh][ch][i][0] + bi4[ch].x;
                float v1 = acc[rh][ch][i][1] + bi4[ch].y;
                float v2 = acc[rh][ch][i][2] + bi4[ch].z;
                float v3 = acc[rh][ch][i][3] + bi4[ch].w;
                if (ACT == 1) { v0 = tanhf(v0); v1 = tanhf(v1); v2 = tanhf(v2); v3 = tanhf(v3); }
                *(float4*)(C + (size_t)row * ldc + col) = make_float4(v0, v1, v2, v3);
            }
        }
}

// ---------------- transpose + split: in[K][N] f32 -> hi/lo [N][K] f16 ----------------
__global__ __launch_bounds__(256)
void tsplit(const float* __restrict__ in, int ldin, int K,
            f16* __restrict__ ohi, f16* __restrict__ olo)
{
    __shared__ float t[32][33];
    const int kb = blockIdx.x << 5, nb = blockIdx.y << 5;
    const int cx = threadIdx.x & 31, ry = threadIdx.x >> 5;
#pragma unroll
    for (int q = 0; q < 4; ++q)
        t[ry + q * 8][cx] = in[(size_t)(kb + ry + q * 8) * ldin + nb + cx];
    __syncthreads();
#pragma unroll
    for (int q = 0; q < 4; ++q) {
        const int n = ry + q * 8;
        const float v = t[cx][n];
        const f16 hi = (f16)v;
        ohi[(size_t)(nb + n) * K + kb + cx] = hi;
        olo[(size_t)(nb + n) * K + kb + cx] = (f16)((v - (float)hi) * LO_SCALE);
    }
}

// ---------------- split f32 h -> hi/lo f16 ----------------
__global__ __launch_bounds__(256)
void split_h(const float* __restrict__ h, f16* __restrict__ hi, f16* __restrict__ lo)
{
    const size_t i = (size_t)blockIdx.x * 256 + threadIdx.x;
    const float v = h[i];
    const f16 a = (f16)v;
    hi[i] = a;
    lo[i] = (f16)((v - (float)a) * LO_SCALE);
}

// ---------------- LSTM pointwise: gates -> c, h(split) ----------------
__global__ __launch_bounds__(256)
void lstm_pw(const float* __restrict__ gates, float* __restrict__ c,
             f16* __restrict__ h_hi, f16* __restrict__ h_lo)
{
    const size_t idx = (size_t)blockIdx.x * 256 + threadIdx.x;
    const int b = (int)(idx >> 9);
    const int j = (int)(idx & 511);
    const float* gr = gates + (size_t)b * NG;
    const float ig = gr[j];
    const float gg = gr[512 + j];
    const float fg = gr[1024 + j];
    const float og = gr[1536 + j];
    const float cx = c[idx];
    const float cy = cx * sigm(fg + 1.0f) + sigm(ig) * tanhf(gg);
    const float hy = sigm(og) * tanhf(cy);
    c[idx] = cy;
    const f16 a = (f16)hy;
    h_hi[idx] = a;
    h_lo[idx] = (f16)((hy - (float)a) * LO_SCALE);
}

// ---------------- argmax + one-hot ----------------
__global__ __launch_bounds__(256)
void argmax_onehot(const float* __restrict__ logits, const float* __restrict__ gu,
                   float* __restrict__ out0, int* __restrict__ kidx, int t)
{
    const int b = blockIdx.x;
    const int tid = threadIdx.x;
    const float* lrow = logits + (size_t)b * NN;
    const float* urow = gu + ((size_t)t * NB + b) * NN;
    float best = -INFINITY;
    int bi = 0x7fffffff;
#pragma unroll
    for (int q = 0; q < 2; ++q) {
        const int j = tid + q * 256;
        const float u = urow[j];
        const float g = -logf(-logf(u + 1e-20f) + 1e-20f);
        const float v = lrow[j] + g;
        if (v > best || (v == best && j < bi)) { best = v; bi = j; }
    }
#pragma unroll
    for (int off = 32; off > 0; off >>= 1) {
        const float ov = __shfl_down(best, off);
        const int oi = __shfl_down(bi, off);
        if (ov > best || (ov == best && oi < bi)) { best = ov; bi = oi; }
    }
    __shared__ float sv[4];
    __shared__ int si[4];
    const int lane = tid & 63, w = tid >> 6;
    if (lane == 0) { sv[w] = best; si[w] = bi; }
    __syncthreads();
    if (tid == 0) {
        for (int q = 1; q < 4; ++q)
            if (sv[q] > best || (sv[q] == best && si[q] < bi)) { best = sv[q]; bi = si[q]; }
        si[0] = bi;
        kidx[(size_t)t * NB + b] = bi;
    }
    __syncthreads();
    const int win = si[0];
    float* orow = out0 + ((size_t)b * NRW + t) * NN;
#pragma unroll
    for (int q = 0; q < 2; ++q) {
        const int j = tid + q * 256;
        orow[j] = (j == win) ? 1.0f : 0.0f;
    }
}

// ---------------- out1 row-dot from split h ----------------
__global__ __launch_bounds__(256)
void rowdot(const f16* __restrict__ hhi, const f16* __restrict__ hlo,
            const float* __restrict__ Woutl, const float* __restrict__ boutl,
            float* __restrict__ out1, int t)
{
    const int w = threadIdx.x >> 6;
    const int lane = threadIdx.x & 63;
    const int b = blockIdx.x * 4 + w;
    const f16* hr = hhi + (size_t)b * NH;
    const f16* lr = hlo + (size_t)b * NH;
    float s = 0.f;
#pragma unroll
    for (int q = 0; q < 8; ++q) {
        const int j = lane + q * 64;
        const float hv = (float)hr[j] + (float)lr[j] * LO_INV;
        s = fmaf(hv, Woutl[j], s);
    }
#pragma unroll
    for (int off = 32; off > 0; off >>= 1) s += __shfl_down(s, off);
    if (lane == 0) out1[(size_t)b * NRW + t] = s + boutl[0];
}

extern "C" void kernel_launch(void* const* d_in, const int* in_sizes, int n_in,
                              void* d_out, int out_size, void* d_ws, size_t ws_size,
                              hipStream_t stream)
{
    const float* latent  = (const float*)d_in[0];
    const float* gu      = (const float*)d_in[2];
    const float* W_int   = (const float*)d_in[3];
    const float* b_int   = (const float*)d_in[4];
    const float* W_intl  = (const float*)d_in[5];
    const float* b_intl  = (const float*)d_in[6];
    const float* W_hup   = (const float*)d_in[7];
    const float* b_hup   = (const float*)d_in[8];
    const float* W_cup   = (const float*)d_in[9];
    const float* b_cup   = (const float*)d_in[10];
    const float* W_hupl  = (const float*)d_in[11];
    const float* b_hupl  = (const float*)d_in[12];
    const float* W_cupl  = (const float*)d_in[13];
    const float* b_cupl  = (const float*)d_in[14];
    const float* W_lstm  = (const float*)d_in[15];
    const float* b_lstm  = (const float*)d_in[16];
    const float* W_up    = (const float*)d_in[17];
    const float* b_up    = (const float*)d_in[18];
    const float* W_down  = (const float*)d_in[19];
    const float* W_downl = (const float*)d_in[20];
    const float* W_outl  = (const float*)d_in[21];
    const float* b_outl  = (const float*)d_in[22];

    float* out0 = (float*)d_out;                 // [B, RW, N]
    float* out1 = out0 + (size_t)NB * NRW * NN;  // [B, RW, 1]

    // workspace layout (f32 units)
    float* ws = (float*)d_ws;
    float* c      = ws;                               // NB*NH
    float* logits = c + (size_t)NB * NH;              // NB*NN
    float* gates  = logits + (size_t)NB * NN;         // NB*NG (also htmp alias)
    float* gdown  = gates + (size_t)NB * NG;          // NN*NG
    float* gdownl = gdown + (size_t)NN * NG;          // NN*NG
    float* fend   = gdownl + (size_t)NN * NG;
    f16* h_hi   = (f16*)fend;                         // NB*NH f16
    f16* h_lo   = h_hi + (size_t)NB * NH;
    f16* WlT_hi = h_lo + (size_t)NB * NH;             // NG*NH f16
    f16* WlT_lo = WlT_hi + (size_t)NG * NH;
    f16* WupT_hi = WlT_lo + (size_t)NG * NH;          // NN*NH f16
    f16* WupT_lo = WupT_hi + (size_t)NN * NH;
    int* kidx = (int*)(WupT_lo + (size_t)NN * NH);    // NRW*NB

    const dim3 blk(256);
    const dim3 g_gates(NG / 128, NB / 128);   // 16 x 64
    const dim3 g_log(NN / 128, NB / 128);     // 4 x 64
    const dim3 g_init(NN / 128, NB / 128);    // 4 x 64
    const dim3 g_pre(NG / 128, NN / 128);     // 16 x 4
    const dim3 g_sph(NB * NH / 256);

    // ---- prep: transpose+split weights; gather-fused G_down matrices ----
    tsplit<<<dim3(NH / 32, NG / 32), blk, 0, stream>>>(W_lstm + (size_t)NIN * NG, NG, NH, WlT_hi, WlT_lo);
    tsplit<<<dim3(NH / 32, NN / 32), blk, 0, stream>>>(W_up, NH, NH, WupT_hi, WupT_lo);
    gemm128<0><<<g_pre, blk, 0, stream>>>(W_down, NIN, W_lstm, NG, nullptr, gdown, NG, NIN);
    gemm128<0><<<g_pre, blk, 0, stream>>>(W_downl, NIN, W_lstm, NG, nullptr, gdownl, NG, NIN);

    // ---- loop 1 init ----
    gemm128<1><<<g_init, blk, 0, stream>>>(latent, NZ, W_int, NH, b_int, logits, NH, NZ);
    gemm128<1><<<g_init, blk, 0, stream>>>(logits, NH, W_hup, NH, b_hup, gates, NH, NH);
    split_h<<<g_sph, blk, 0, stream>>>(gates, h_hi, h_lo);
    gemm128<1><<<g_init, blk, 0, stream>>>(logits, NH, W_cup, NH, b_cup, c, NH, NH);

    for (int t = 0; t < NRW; ++t) {
        if (t == 0)
            mfma_split_gemm<0><<<g_gates, blk, 0, stream>>>(h_hi, h_lo, WlT_hi, WlT_lo, b_lstm,
                                                            nullptr, nullptr, gates, NG, NH);
        else
            mfma_split_gemm<1><<<g_gates, blk, 0, stream>>>(h_hi, h_lo, WlT_hi, WlT_lo, b_lstm,
                                                            gdown, kidx + (size_t)(t - 1) * NB,
                                                            gates, NG, NH);
        lstm_pw<<<g_sph, blk, 0, stream>>>(gates, c, h_hi, h_lo);
        mfma_split_gemm<0><<<g_log, blk, 0, stream>>>(h_hi, h_lo, WupT_hi, WupT_lo, b_up,
                                                      nullptr, nullptr, logits, NN, NH);
        argmax_onehot<<<dim3(NB), blk, 0, stream>>>(logits, gu, out0, kidx, t);
    }

    // ---- loop 2 init ----
    gemm128<1><<<g_init, blk, 0, stream>>>(latent, NZ, W_intl, NH, b_intl, logits, NH, NZ);
    gemm128<1><<<g_init, blk, 0, stream>>>(logits, NH, W_hupl, NH, b_hupl, gates, NH, NH);
    split_h<<<g_sph, blk, 0, stream>>>(gates, h_hi, h_lo);
    gemm128<1><<<g_init, blk, 0, stream>>>(logits, NH, W_cupl, NH, b_cupl, c, NH, NH);

    for (int t = 0; t < NRW; ++t) {
        mfma_split_gemm<1><<<g_gates, blk, 0, stream>>>(h_hi, h_lo, WlT_hi, WlT_lo, b_lstm,
                                                        gdownl, kidx + (size_t)t * NB,
                                                        gates, NG, NH);
        lstm_pw<<<g_sph, blk, 0, stream>>>(gates, c, h_hi, h_lo);
        rowdot<<<dim3(NB / 4), blk, 0, stream>>>(h_hi, h_lo, W_outl, b_outl, out1, t);
    }
}

// Round 5
// 4282.276 us; speedup vs baseline: 2.8195x; 2.8195x over previous
//
#include <hip/hip_runtime.h>

#define NB 8192
#define NH 512
#define NZ 128
#define NIN 128
#define NN 512
#define NRW 16
#define NG 2048   // 4*NH

typedef _Float16 f16;
typedef _Float16 f16x8 __attribute__((ext_vector_type(8)));
typedef float f32x4 __attribute__((ext_vector_type(4)));

#define LO_SCALE 2048.0f
#define LO_INV   (1.0f / 2048.0f)

__device__ __forceinline__ float sigm(float x) { return 1.0f / (1.0f + expf(-x)); }

// ---------------- async 16B global->LDS ----------------
__device__ __forceinline__ void gload16(const f16* g, f16* l)
{
    __builtin_amdgcn_global_load_lds(
        (const __attribute__((address_space(1))) void*)g,
        (__attribute__((address_space(3))) void*)l, 16, 0, 0);
}

// Stage one 128x32 f16 tile (8KB) via 2 global_load_lds per thread.
// LDS layout: linear [row][32] with XOR-swizzled 16B slots; the swizzle is
// applied by permuting the GLOBAL source slot (rule #21: linear dest +
// inverse-swizzled source + swizzled read).
__device__ __forceinline__ void stage_tile(f16* tilebase, const f16* src,
                                           int rowbase, int K, int kb,
                                           int wid, int lane)
{
#pragma unroll
    for (int q = 0; q < 2; ++q) {
        const int iw = wid * 2 + q;                 // 0..7
        const int chunk = (iw << 6) | lane;         // 16B chunk idx 0..511
        const int row = chunk >> 2;                 // 0..127
        const int p = (chunk & 3) ^ (row & 3);      // global slot (involution)
        const f16* g = src + (size_t)(rowbase + row) * K + kb + (p << 3);
        gload16(g, tilebase + (iw << 9));           // uniform base; HW adds lane*16B
    }
}

// Swizzled fragment read: 16 rows x 32k per ds_read_b128 across the wave.
__device__ __forceinline__ f16x8 frag(const f16* tile, int row, int sl)
{
    return *(const f16x8*)(tile + row * 32 + ((sl ^ (row & 3)) << 3));
}

// ---------------- fused split-f16 MFMA GEMM ----------------
// C[M][N] = (Ahi+Alo/2048)[M][K] @ (Bhi+Blo/2048)[N][K]^T + bias
//           (+ extra[eidx[row]]) , optional tanh.
// 128x128 tile, 4 waves, BK=32, double-buffered LDS, 48 MFMA / K-step.
template<int HAS_EXTRA, int ACT>
__global__ __launch_bounds__(256, 2)
void mfma_gemm(const f16* __restrict__ Ahi, const f16* __restrict__ Alo,
               const f16* __restrict__ Bhi, const f16* __restrict__ Blo,
               const float* __restrict__ bias,
               const float* __restrict__ extra, const int* __restrict__ eidx,
               float* __restrict__ C, int N, int K)
{
    __shared__ f16 sT[2][4][128 * 32];   // [dbuf][Ahi,Alo,Bhi,Blo][tile] = 64KB
    const int bm = blockIdx.y << 7;
    const int bn = blockIdx.x << 7;
    const int tid = threadIdx.x;
    const int wid = tid >> 6, lane = tid & 63;
    const int wr = ((wid >> 1) & 1) << 6;
    const int wc = (wid & 1) << 6;

    f32x4 accA[4][4], accB[4][4];
#pragma unroll
    for (int i = 0; i < 4; ++i)
#pragma unroll
        for (int j = 0; j < 4; ++j) { accA[i][j] = (f32x4)(0.0f); accB[i][j] = (f32x4)(0.0f); }

    const int NT = K >> 5;

    stage_tile(sT[0][0], Ahi, bm, K, 0, wid, lane);
    stage_tile(sT[0][1], Alo, bm, K, 0, wid, lane);
    stage_tile(sT[0][2], Bhi, bn, K, 0, wid, lane);
    stage_tile(sT[0][3], Blo, bn, K, 0, wid, lane);

    const int r16 = lane & 15, sl = lane >> 4;

    for (int kt = 0; kt < NT; ++kt) {
        const int cur = kt & 1;
        __syncthreads();                 // compiler drains vmcnt(0): buf[cur] ready
        if (kt + 1 < NT) {
            const int kb = (kt + 1) << 5;
            stage_tile(sT[cur ^ 1][0], Ahi, bm, K, kb, wid, lane);
            stage_tile(sT[cur ^ 1][1], Alo, bm, K, kb, wid, lane);
            stage_tile(sT[cur ^ 1][2], Bhi, bn, K, kb, wid, lane);
            stage_tile(sT[cur ^ 1][3], Blo, bn, K, kb, wid, lane);
        }
        f16x8 ah[4], al[4], bh[4], bl[4];
#pragma unroll
        for (int f = 0; f < 4; ++f) {
            ah[f] = frag(sT[cur][0], wr + f * 16 + r16, sl);
            al[f] = frag(sT[cur][1], wr + f * 16 + r16, sl);
            bh[f] = frag(sT[cur][2], wc + f * 16 + r16, sl);
            bl[f] = frag(sT[cur][3], wc + f * 16 + r16, sl);
        }
#pragma unroll
        for (int i = 0; i < 4; ++i)
#pragma unroll
            for (int j = 0; j < 4; ++j) {
                accA[i][j] = __builtin_amdgcn_mfma_f32_16x16x32_f16(ah[i], bh[j], accA[i][j], 0, 0, 0);
                accB[i][j] = __builtin_amdgcn_mfma_f32_16x16x32_f16(al[i], bh[j], accB[i][j], 0, 0, 0);
                accB[i][j] = __builtin_amdgcn_mfma_f32_16x16x32_f16(ah[i], bl[j], accB[i][j], 0, 0, 0);
            }
    }

    // epilogue: C/D layout col=lane&15, row=(lane>>4)*4+reg (validated r4)
    const int rg = lane >> 4;
#pragma unroll
    for (int i = 0; i < 4; ++i) {
#pragma unroll
        for (int r = 0; r < 4; ++r) {
            const int row = bm + wr + i * 16 + rg * 4 + r;
            const float* exrow = nullptr;
            if (HAS_EXTRA) exrow = extra + (size_t)eidx[row] * N;
#pragma unroll
            for (int j = 0; j < 4; ++j) {
                const int col = bn + wc + j * 16 + r16;
                float v = accA[i][j][r] + accB[i][j][r] * LO_INV;
                if (bias) v += bias[col];
                if (HAS_EXTRA) v += exrow[col];
                if (ACT == 1) v = tanhf(v);
                C[(size_t)row * N + col] = v;
            }
        }
    }
}

// ---------------- f32 vector GEMM (K=128 prep/init only) ----------------
template<int ACT>
__global__ __launch_bounds__(256)
void gemm128(const float* __restrict__ A, int lda,
             const float* __restrict__ W, int ldw,
             const float* __restrict__ bias,
             float* __restrict__ C, int ldc, int K)
{
    __shared__ float As[16][128];
    __shared__ float Bs[16][128];
    const int bm = blockIdx.y << 7, bn = blockIdx.x << 7;
    const int tid = threadIdx.x;
    const int tx = tid & 15, ty = tid >> 4;
    const int sar = tid >> 1, sac = (tid & 1) << 3;
    const int sbk = tid >> 4, sbc = (tid & 15) << 3;
    float acc[2][2][4][4] = {};
    const float* Ap = A + (size_t)(bm + sar) * lda + sac;
    const float* Wp = W + (size_t)sbk * ldw + bn + sbc;
    for (int kb = 0; kb < K; kb += 16) {
        const float4 av0 = *(const float4*)(Ap + kb);
        const float4 av1 = *(const float4*)(Ap + kb + 4);
        const float4 bv0 = *(const float4*)(Wp + (size_t)kb * ldw);
        const float4 bv1 = *(const float4*)(Wp + (size_t)kb * ldw + 4);
        __syncthreads();
        As[sac + 0][sar] = av0.x; As[sac + 1][sar] = av0.y;
        As[sac + 2][sar] = av0.z; As[sac + 3][sar] = av0.w;
        As[sac + 4][sar] = av1.x; As[sac + 5][sar] = av1.y;
        As[sac + 6][sar] = av1.z; As[sac + 7][sar] = av1.w;
        *(float4*)&Bs[sbk][sbc] = bv0;
        *(float4*)&Bs[sbk][sbc + 4] = bv1;
        __syncthreads();
#pragma unroll
        for (int kk = 0; kk < 16; ++kk) {
            float a[2][4], b[2][4];
            *(float4*)a[0] = *(const float4*)&As[kk][ty << 2];
            *(float4*)a[1] = *(const float4*)&As[kk][64 + (ty << 2)];
            *(float4*)b[0] = *(const float4*)&Bs[kk][tx << 2];
            *(float4*)b[1] = *(const float4*)&Bs[kk][64 + (tx << 2)];
#pragma unroll
            for (int rh = 0; rh < 2; ++rh)
#pragma unroll
                for (int ch = 0; ch < 2; ++ch)
#pragma unroll
                    for (int i = 0; i < 4; ++i)
#pragma unroll
                        for (int j = 0; j < 4; ++j)
                            acc[rh][ch][i][j] = fmaf(a[rh][i], b[ch][j], acc[rh][ch][i][j]);
        }
    }
    float4 bi4[2] = {make_float4(0.f, 0.f, 0.f, 0.f), make_float4(0.f, 0.f, 0.f, 0.f)};
    if (bias) {
        bi4[0] = *(const float4*)(bias + bn + (tx << 2));
        bi4[1] = *(const float4*)(bias + bn + 64 + (tx << 2));
    }
#pragma unroll
    for (int rh = 0; rh < 2; ++rh)
#pragma unroll
        for (int i = 0; i < 4; ++i) {
            const int row = bm + rh * 64 + (ty << 2) + i;
#pragma unroll
            for (int ch = 0; ch < 2; ++ch) {
                const int col = bn + ch * 64 + (tx << 2);
                float v0 = acc[rh][ch][i][0] + bi4[ch].x;
                float v1 = acc[rh][ch][i][1] + bi4[ch].y;
                float v2 = acc[rh][ch][i][2] + bi4[ch].z;
                float v3 = acc[rh][ch][i][3] + bi4[ch].w;
                if (ACT == 1) { v0 = tanhf(v0); v1 = tanhf(v1); v2 = tanhf(v2); v3 = tanhf(v3); }
                *(float4*)(C + (size_t)row * ldc + col) = make_float4(v0, v1, v2, v3);
            }
        }
}

// ---------------- transpose + split: in[K][N] f32 -> hi/lo [N][K] f16 ----------------
__global__ __launch_bounds__(256)
void tsplit(const float* __restrict__ in, int ldin, int K,
            f16* __restrict__ ohi, f16* __restrict__ olo)
{
    __shared__ float t[32][33];
    const int kb = blockIdx.x << 5, nb = blockIdx.y << 5;
    const int cx = threadIdx.x & 31, ry = threadIdx.x >> 5;
#pragma unroll
    for (int q = 0; q < 4; ++q)
        t[ry + q * 8][cx] = in[(size_t)(kb + ry + q * 8) * ldin + nb + cx];
    __syncthreads();
#pragma unroll
    for (int q = 0; q < 4; ++q) {
        const int n = ry + q * 8;
        const float v = t[cx][n];
        const f16 hi = (f16)v;
        ohi[(size_t)(nb + n) * K + kb + cx] = hi;
        olo[(size_t)(nb + n) * K + kb + cx] = (f16)((v - (float)hi) * LO_SCALE);
    }
}

// ---------------- split f32 -> hi/lo f16 ----------------
__global__ __launch_bounds__(256)
void split_h(const float* __restrict__ h, f16* __restrict__ hi, f16* __restrict__ lo)
{
    const size_t i = (size_t)blockIdx.x * 256 + threadIdx.x;
    const float v = h[i];
    const f16 a = (f16)v;
    hi[i] = a;
    lo[i] = (f16)((v - (float)a) * LO_SCALE);
}

// ---------------- LSTM pointwise: gates -> c, h(split) ----------------
__global__ __launch_bounds__(256)
void lstm_pw(const float* __restrict__ gates, float* __restrict__ c,
             f16* __restrict__ h_hi, f16* __restrict__ h_lo)
{
    const size_t idx = (size_t)blockIdx.x * 256 + threadIdx.x;
    const int b = (int)(idx >> 9);
    const int j = (int)(idx & 511);
    const float* gr = gates + (size_t)b * NG;
    const float ig = gr[j];
    const float gg = gr[512 + j];
    const float fg = gr[1024 + j];
    const float og = gr[1536 + j];
    const float cx = c[idx];
    const float cy = cx * sigm(fg + 1.0f) + sigm(ig) * tanhf(gg);
    const float hy = sigm(og) * tanhf(cy);
    c[idx] = cy;
    const f16 a = (f16)hy;
    h_hi[idx] = a;
    h_lo[idx] = (f16)((hy - (float)a) * LO_SCALE);
}

// ---------------- argmax + one-hot ----------------
__global__ __launch_bounds__(256)
void argmax_onehot(const float* __restrict__ logits, const float* __restrict__ gu,
                   float* __restrict__ out0, int* __restrict__ kidx, int t)
{
    const int b = blockIdx.x;
    const int tid = threadIdx.x;
    const float* lrow = logits + (size_t)b * NN;
    const float* urow = gu + ((size_t)t * NB + b) * NN;
    float best = -INFINITY;
    int bi = 0x7fffffff;
#pragma unroll
    for (int q = 0; q < 2; ++q) {
        const int j = tid + q * 256;
        const float u = urow[j];
        const float g = -logf(-logf(u + 1e-20f) + 1e-20f);
        const float v = lrow[j] + g;
        if (v > best || (v == best && j < bi)) { best = v; bi = j; }
    }
#pragma unroll
    for (int off = 32; off > 0; off >>= 1) {
        const float ov = __shfl_down(best, off);
        const int oi = __shfl_down(bi, off);
        if (ov > best || (ov == best && oi < bi)) { best = ov; bi = oi; }
    }
    __shared__ float sv[4];
    __shared__ int si[4];
    const int lane = tid & 63, w = tid >> 6;
    if (lane == 0) { sv[w] = best; si[w] = bi; }
    __syncthreads();
    if (tid == 0) {
        for (int q = 1; q < 4; ++q)
            if (sv[q] > best || (sv[q] == best && si[q] < bi)) { best = sv[q]; bi = si[q]; }
        si[0] = bi;
        kidx[(size_t)t * NB + b] = bi;
    }
    __syncthreads();
    const int win = si[0];
    float* orow = out0 + ((size_t)b * NRW + t) * NN;
#pragma unroll
    for (int q = 0; q < 2; ++q) {
        const int j = tid + q * 256;
        orow[j] = (j == win) ? 1.0f : 0.0f;
    }
}

// ---------------- out1 row-dot from split h ----------------
__global__ __launch_bounds__(256)
void rowdot(const f16* __restrict__ hhi, const f16* __restrict__ hlo,
            const float* __restrict__ Woutl, const float* __restrict__ boutl,
            float* __restrict__ out1, int t)
{
    const int w = threadIdx.x >> 6;
    const int lane = threadIdx.x & 63;
    const int b = blockIdx.x * 4 + w;
    const f16* hr = hhi + (size_t)b * NH;
    const f16* lr = hlo + (size_t)b * NH;
    float s = 0.f;
#pragma unroll
    for (int q = 0; q < 8; ++q) {
        const int j = lane + q * 64;
        const float hv = (float)hr[j] + (float)lr[j] * LO_INV;
        s = fmaf(hv, Woutl[j], s);
    }
#pragma unroll
    for (int off = 32; off > 0; off >>= 1) s += __shfl_down(s, off);
    if (lane == 0) out1[(size_t)b * NRW + t] = s + boutl[0];
}

extern "C" void kernel_launch(void* const* d_in, const int* in_sizes, int n_in,
                              void* d_out, int out_size, void* d_ws, size_t ws_size,
                              hipStream_t stream)
{
    const float* latent  = (const float*)d_in[0];
    const float* gu      = (const float*)d_in[2];
    const float* W_int   = (const float*)d_in[3];
    const float* b_int   = (const float*)d_in[4];
    const float* W_intl  = (const float*)d_in[5];
    const float* b_intl  = (const float*)d_in[6];
    const float* W_hup   = (const float*)d_in[7];
    const float* b_hup   = (const float*)d_in[8];
    const float* W_cup   = (const float*)d_in[9];
    const float* b_cup   = (const float*)d_in[10];
    const float* W_hupl  = (const float*)d_in[11];
    const float* b_hupl  = (const float*)d_in[12];
    const float* W_cupl  = (const float*)d_in[13];
    const float* b_cupl  = (const float*)d_in[14];
    const float* W_lstm  = (const float*)d_in[15];
    const float* b_lstm  = (const float*)d_in[16];
    const float* W_up    = (const float*)d_in[17];
    const float* b_up    = (const float*)d_in[18];
    const float* W_down  = (const float*)d_in[19];
    const float* W_downl = (const float*)d_in[20];
    const float* W_outl  = (const float*)d_in[21];
    const float* b_outl  = (const float*)d_in[22];

    float* out0 = (float*)d_out;                 // [B, RW, N]
    float* out1 = out0 + (size_t)NB * NRW * NN;  // [B, RW, 1]

    // workspace
    float* ws     = (float*)d_ws;
    float* c      = ws;                               // NB*NH
    float* logits = c + (size_t)NB * NH;              // NB*NH (also inter f32)
    float* gates  = logits + (size_t)NB * NH;         // NB*NG (also htmp)
    float* gdown  = gates + (size_t)NB * NG;          // NN*NG
    float* gdownl = gdown + (size_t)NN * NG;          // NN*NG
    f16* fp = (f16*)(gdownl + (size_t)NN * NG);
    f16* h_hi   = fp;                fp += (size_t)NB * NH;
    f16* h_lo   = fp;                fp += (size_t)NB * NH;
    f16* i_hi   = fp;                fp += (size_t)NB * NH;
    f16* i_lo   = fp;                fp += (size_t)NB * NH;
    f16* WlT_hi = fp;                fp += (size_t)NG * NH;
    f16* WlT_lo = fp;                fp += (size_t)NG * NH;
    f16* WupT_hi = fp;               fp += (size_t)NN * NH;
    f16* WupT_lo = fp;               fp += (size_t)NN * NH;
    f16* WhT_hi = fp;                fp += (size_t)NH * NH;
    f16* WhT_lo = fp;                fp += (size_t)NH * NH;
    f16* WcT_hi = fp;                fp += (size_t)NH * NH;
    f16* WcT_lo = fp;                fp += (size_t)NH * NH;
    f16* WhlT_hi = fp;               fp += (size_t)NH * NH;
    f16* WhlT_lo = fp;               fp += (size_t)NH * NH;
    f16* WclT_hi = fp;               fp += (size_t)NH * NH;
    f16* WclT_lo = fp;               fp += (size_t)NH * NH;
    int* kidx = (int*)fp;

    const dim3 blk(256);
    const dim3 g_gates(NG / 128, NB / 128);   // 16 x 64
    const dim3 g_h(NH / 128, NB / 128);       // 4 x 64
    const dim3 g_pre(NG / 128, NN / 128);     // 16 x 4
    const dim3 g_sph(NB * NH / 256);

    // ---- prep: weight transpose+split; gather-fused G_down matrices ----
    tsplit<<<dim3(NH / 32, NG / 32), blk, 0, stream>>>(W_lstm + (size_t)NIN * NG, NG, NH, WlT_hi, WlT_lo);
    tsplit<<<dim3(NH / 32, NN / 32), blk, 0, stream>>>(W_up, NH, NH, WupT_hi, WupT_lo);
    tsplit<<<dim3(NH / 32, NH / 32), blk, 0, stream>>>(W_hup, NH, NH, WhT_hi, WhT_lo);
    tsplit<<<dim3(NH / 32, NH / 32), blk, 0, stream>>>(W_cup, NH, NH, WcT_hi, WcT_lo);
    tsplit<<<dim3(NH / 32, NH / 32), blk, 0, stream>>>(W_hupl, NH, NH, WhlT_hi, WhlT_lo);
    tsplit<<<dim3(NH / 32, NH / 32), blk, 0, stream>>>(W_cupl, NH, NH, WclT_hi, WclT_lo);
    gemm128<0><<<g_pre, blk, 0, stream>>>(W_down, NIN, W_lstm, NG, nullptr, gdown, NG, NIN);
    gemm128<0><<<g_pre, blk, 0, stream>>>(W_downl, NIN, W_lstm, NG, nullptr, gdownl, NG, NIN);

    // ---- loop 1 init ----
    gemm128<1><<<g_h, blk, 0, stream>>>(latent, NZ, W_int, NH, b_int, logits, NH, NZ);
    split_h<<<g_sph, blk, 0, stream>>>(logits, i_hi, i_lo);
    mfma_gemm<0, 1><<<g_h, blk, 0, stream>>>(i_hi, i_lo, WhT_hi, WhT_lo, b_hup,
                                             nullptr, nullptr, gates, NH, NH);
    split_h<<<g_sph, blk, 0, stream>>>(gates, h_hi, h_lo);
    mfma_gemm<0, 1><<<g_h, blk, 0, stream>>>(i_hi, i_lo, WcT_hi, WcT_lo, b_cup,
                                             nullptr, nullptr, c, NH, NH);

    for (int t = 0; t < NRW; ++t) {
        if (t == 0)
            mfma_gemm<0, 0><<<g_gates, blk, 0, stream>>>(h_hi, h_lo, WlT_hi, WlT_lo, b_lstm,
                                                         nullptr, nullptr, gates, NG, NH);
        else
            mfma_gemm<1, 0><<<g_gates, blk, 0, stream>>>(h_hi, h_lo, WlT_hi, WlT_lo, b_lstm,
                                                         gdown, kidx + (size_t)(t - 1) * NB,
                                                         gates, NG, NH);
        lstm_pw<<<g_sph, blk, 0, stream>>>(gates, c, h_hi, h_lo);
        mfma_gemm<0, 0><<<g_h, blk, 0, stream>>>(h_hi, h_lo, WupT_hi, WupT_lo, b_up,
                                                 nullptr, nullptr, logits, NN, NH);
        argmax_onehot<<<dim3(NB), blk, 0, stream>>>(logits, gu, out0, kidx, t);
    }

    // ---- loop 2 init ----
    gemm128<1><<<g_h, blk, 0, stream>>>(latent, NZ, W_intl, NH, b_intl, logits, NH, NZ);
    split_h<<<g_sph, blk, 0, stream>>>(logits, i_hi, i_lo);
    mfma_gemm<0, 1><<<g_h, blk, 0, stream>>>(i_hi, i_lo, WhlT_hi, WhlT_lo, b_hupl,
                                             nullptr, nullptr, gates, NH, NH);
    split_h<<<g_sph, blk, 0, stream>>>(gates, h_hi, h_lo);
    mfma_gemm<0, 1><<<g_h, blk, 0, stream>>>(i_hi, i_lo, WclT_hi, WclT_lo, b_cupl,
                                             nullptr, nullptr, c, NH, NH);

    for (int t = 0; t < NRW; ++t) {
        mfma_gemm<1, 0><<<g_gates, blk, 0, stream>>>(h_hi, h_lo, WlT_hi, WlT_lo, b_lstm,
                                                     gdownl, kidx + (size_t)t * NB,
                                                     gates, NG, NH);
        lstm_pw<<<g_sph, blk, 0, stream>>>(gates, c, h_hi, h_lo);
        rowdot<<<dim3(NB / 4), blk, 0, stream>>>(h_hi, h_lo, W_outl, b_outl, out1, t);
    }
}

// Round 6
// 3231.004 us; speedup vs baseline: 3.7369x; 1.3254x over previous
//
#include <hip/hip_runtime.h>

#define NB 8192
#define NH 512
#define NZ 128
#define NIN 128
#define NN 512
#define NRW 16
#define NG 2048   // 4*NH

typedef _Float16 f16;
typedef _Float16 f16x8 __attribute__((ext_vector_type(8)));
typedef float f32x4 __attribute__((ext_vector_type(4)));

#define LO_SCALE 2048.0f
#define LO_INV   (1.0f / 2048.0f)

__device__ __forceinline__ float sigm(float x) { return 1.0f / (1.0f + expf(-x)); }

// gate-interleaved column permutation: stored col c <- original col oc(c)
// oc(c) = gate*512 + jj ; gate=(c>>4)&3 ; jj=((c>>6)<<4)|(c&15)
__device__ __forceinline__ int oc_of(int c)
{
    return (((c >> 4) & 3) << 9) + ((c >> 6) << 4) + (c & 15);
}
// inverse: original col j -> stored col
__device__ __forceinline__ int cperm(int j)
{
    return (j & 15) | (((j >> 4) & 31) << 6) | (((j >> 9) & 3) << 4);
}

// ---------------- async 16B global->LDS ----------------
__device__ __forceinline__ void gload16(const f16* g, f16* l)
{
    __builtin_amdgcn_global_load_lds(
        (const __attribute__((address_space(1))) void*)g,
        (__attribute__((address_space(3))) void*)l, 16, 0, 0);
}

// Stage one 128x32 f16 tile (8KB): linear LDS dest + inverse-swizzled global src.
__device__ __forceinline__ void stage_tile(f16* tilebase, const f16* src,
                                           int rowbase, int K, int kb,
                                           int wid, int lane)
{
#pragma unroll
    for (int q = 0; q < 2; ++q) {
        const int iw = wid * 2 + q;
        const int chunk = (iw << 6) | lane;
        const int row = chunk >> 2;
        const int p = (chunk & 3) ^ (row & 3);
        const f16* g = src + (size_t)(rowbase + row) * K + kb + (p << 3);
        gload16(g, tilebase + (iw << 9));
    }
}

__device__ __forceinline__ f16x8 frag(const f16* tile, int row, int sl)
{
    return *(const f16x8*)(tile + row * 32 + ((sl ^ (row & 3)) << 3));
}

// ---------------- shared GEMM core (macro-free via inline) ----------------
// Computes accA (hi*hi) and accB (cross terms) for a 128x128 tile.
__device__ __forceinline__ void gemm_core(const f16* Ahi, const f16* Alo,
                                          const f16* Bhi, const f16* Blo,
                                          f16 (*sT)[4][128 * 32],
                                          int bm, int bn, int K,
                                          int wid, int lane, int wr, int wc,
                                          f32x4 (&accA)[4][4], f32x4 (&accB)[4][4])
{
    const int NT = K >> 5;
    stage_tile(sT[0][0], Ahi, bm, K, 0, wid, lane);
    stage_tile(sT[0][1], Alo, bm, K, 0, wid, lane);
    stage_tile(sT[0][2], Bhi, bn, K, 0, wid, lane);
    stage_tile(sT[0][3], Blo, bn, K, 0, wid, lane);

    const int r16 = lane & 15, sl = lane >> 4;

    for (int kt = 0; kt < NT; ++kt) {
        const int cur = kt & 1;
        __syncthreads();
        if (kt + 1 < NT) {
            const int kb = (kt + 1) << 5;
            stage_tile(sT[cur ^ 1][0], Ahi, bm, K, kb, wid, lane);
            stage_tile(sT[cur ^ 1][1], Alo, bm, K, kb, wid, lane);
            stage_tile(sT[cur ^ 1][2], Bhi, bn, K, kb, wid, lane);
            stage_tile(sT[cur ^ 1][3], Blo, bn, K, kb, wid, lane);
        }
        f16x8 ah[4], al[4], bh[4], bl[4];
#pragma unroll
        for (int f = 0; f < 4; ++f) {
            ah[f] = frag(sT[cur][0], wr + f * 16 + r16, sl);
            al[f] = frag(sT[cur][1], wr + f * 16 + r16, sl);
            bh[f] = frag(sT[cur][2], wc + f * 16 + r16, sl);
            bl[f] = frag(sT[cur][3], wc + f * 16 + r16, sl);
        }
#pragma unroll
        for (int i = 0; i < 4; ++i)
#pragma unroll
            for (int j = 0; j < 4; ++j) {
                accA[i][j] = __builtin_amdgcn_mfma_f32_16x16x32_f16(ah[i], bh[j], accA[i][j], 0, 0, 0);
                accB[i][j] = __builtin_amdgcn_mfma_f32_16x16x32_f16(al[i], bh[j], accB[i][j], 0, 0, 0);
                accB[i][j] = __builtin_amdgcn_mfma_f32_16x16x32_f16(ah[i], bl[j], accB[i][j], 0, 0, 0);
            }
    }
}

// ---------------- plain split GEMM (logits / inits) ----------------
template<int HAS_EXTRA, int ACT>
__global__ __launch_bounds__(256, 2)
void mfma_gemm(const f16* __restrict__ Ahi, const f16* __restrict__ Alo,
               const f16* __restrict__ Bhi, const f16* __restrict__ Blo,
               const float* __restrict__ bias,
               const float* __restrict__ extra, const int* __restrict__ eidx,
               float* __restrict__ C, int N, int K)
{
    __shared__ f16 sT[2][4][128 * 32];
    const int bm = blockIdx.y << 7;
    const int bn = blockIdx.x << 7;
    const int tid = threadIdx.x;
    const int wid = tid >> 6, lane = tid & 63;
    const int wr = ((wid >> 1) & 1) << 6;
    const int wc = (wid & 1) << 6;

    f32x4 accA[4][4], accB[4][4];
#pragma unroll
    for (int i = 0; i < 4; ++i)
#pragma unroll
        for (int j = 0; j < 4; ++j) { accA[i][j] = (f32x4)(0.0f); accB[i][j] = (f32x4)(0.0f); }

    gemm_core(Ahi, Alo, Bhi, Blo, sT, bm, bn, K, wid, lane, wr, wc, accA, accB);

    const int r16 = lane & 15;
    const int rg = lane >> 4;
#pragma unroll
    for (int i = 0; i < 4; ++i) {
#pragma unroll
        for (int r = 0; r < 4; ++r) {
            const int row = bm + wr + i * 16 + rg * 4 + r;
            const float* exrow = nullptr;
            if (HAS_EXTRA) exrow = extra + (size_t)eidx[row] * N;
#pragma unroll
            for (int j = 0; j < 4; ++j) {
                const int col = bn + wc + j * 16 + r16;
                float v = accA[i][j][r] + accB[i][j][r] * LO_INV;
                if (bias) v += bias[col];
                if (HAS_EXTRA) v += exrow[col];
                if (ACT == 1) v = tanhf(v);
                C[(size_t)row * N + col] = v;
            }
        }
    }
}

// ---------------- fused gate GEMM + LSTM pointwise ----------------
// B = gate-interleaved WlT' [NG][NH]; blp/extra in permuted col space.
// Thread's 4 col-frags are gates i,g,f,o of unit jj = ((bn+wc)>>6)*16 + (lane&15).
template<int HAS_EXTRA>
__global__ __launch_bounds__(256, 2)
void mfma_gate_lstm(const f16* __restrict__ Ahi, const f16* __restrict__ Alo,
                    const f16* __restrict__ Bhi, const f16* __restrict__ Blo,
                    const float* __restrict__ blp,
                    const float* __restrict__ extra, const int* __restrict__ eidx,
                    float* __restrict__ c,
                    f16* __restrict__ h_hi, f16* __restrict__ h_lo)
{
    __shared__ f16 sT[2][4][128 * 32];
    const int bm = blockIdx.y << 7;
    const int bn = blockIdx.x << 7;
    const int tid = threadIdx.x;
    const int wid = tid >> 6, lane = tid & 63;
    const int wr = ((wid >> 1) & 1) << 6;
    const int wc = (wid & 1) << 6;

    f32x4 accA[4][4], accB[4][4];
#pragma unroll
    for (int i = 0; i < 4; ++i)
#pragma unroll
        for (int j = 0; j < 4; ++j) { accA[i][j] = (f32x4)(0.0f); accB[i][j] = (f32x4)(0.0f); }

    gemm_core(Ahi, Alo, Bhi, Blo, sT, bm, bn, NH, wid, lane, wr, wc, accA, accB);

    const int m = lane & 15;
    const int rg = lane >> 4;
    const int colb = bn + wc;                 // multiple of 64
    const int jj = ((colb >> 6) << 4) + m;    // LSTM unit index, 0..511
    float bi[4];
#pragma unroll
    for (int g = 0; g < 4; ++g) bi[g] = blp[colb + g * 16 + m];

#pragma unroll
    for (int i = 0; i < 4; ++i) {
#pragma unroll
        for (int r = 0; r < 4; ++r) {
            const int row = bm + wr + i * 16 + rg * 4 + r;
            float ex[4] = {0.f, 0.f, 0.f, 0.f};
            if (HAS_EXTRA) {
                const float* exr = extra + (size_t)eidx[row] * NG;
#pragma unroll
                for (int g = 0; g < 4; ++g) ex[g] = exr[colb + g * 16 + m];
            }
            const float ig = accA[i][0][r] + accB[i][0][r] * LO_INV + bi[0] + ex[0];
            const float gg = accA[i][1][r] + accB[i][1][r] * LO_INV + bi[1] + ex[1];
            const float fg = accA[i][2][r] + accB[i][2][r] * LO_INV + bi[2] + ex[2];
            const float og = accA[i][3][r] + accB[i][3][r] * LO_INV + bi[3] + ex[3];
            const size_t cidx = (size_t)row * NH + jj;
            const float cx = c[cidx];
            const float cy = cx * sigm(fg + 1.0f) + sigm(ig) * tanhf(gg);
            const float hy = sigm(og) * tanhf(cy);
            c[cidx] = cy;
            const f16 a = (f16)hy;
            h_hi[cidx] = a;
            h_lo[cidx] = (f16)((hy - (float)a) * LO_SCALE);
        }
    }
}

// ---------------- f32 vector GEMM (K=128 prep/init only) ----------------
template<int ACT, int PERM>
__global__ __launch_bounds__(256)
void gemm128(const float* __restrict__ A, int lda,
             const float* __restrict__ W, int ldw,
             const float* __restrict__ bias,
             float* __restrict__ C, int ldc, int K)
{
    __shared__ float As[16][128];
    __shared__ float Bs[16][128];
    const int bm = blockIdx.y << 7, bn = blockIdx.x << 7;
    const int tid = threadIdx.x;
    const int tx = tid & 15, ty = tid >> 4;
    const int sar = tid >> 1, sac = (tid & 1) << 3;
    const int sbk = tid >> 4, sbc = (tid & 15) << 3;
    float acc[2][2][4][4] = {};
    const float* Ap = A + (size_t)(bm + sar) * lda + sac;
    const float* Wp = W + (size_t)sbk * ldw + bn + sbc;
    for (int kb = 0; kb < K; kb += 16) {
        const float4 av0 = *(const float4*)(Ap + kb);
        const float4 av1 = *(const float4*)(Ap + kb + 4);
        const float4 bv0 = *(const float4*)(Wp + (size_t)kb * ldw);
        const float4 bv1 = *(const float4*)(Wp + (size_t)kb * ldw + 4);
        __syncthreads();
        As[sac + 0][sar] = av0.x; As[sac + 1][sar] = av0.y;
        As[sac + 2][sar] = av0.z; As[sac + 3][sar] = av0.w;
        As[sac + 4][sar] = av1.x; As[sac + 5][sar] = av1.y;
        As[sac + 6][sar] = av1.z; As[sac + 7][sar] = av1.w;
        *(float4*)&Bs[sbk][sbc] = bv0;
        *(float4*)&Bs[sbk][sbc + 4] = bv1;
        __syncthreads();
#pragma unroll
        for (int kk = 0; kk < 16; ++kk) {
            float a[2][4], b[2][4];
            *(float4*)a[0] = *(const float4*)&As[kk][ty << 2];
            *(float4*)a[1] = *(const float4*)&As[kk][64 + (ty << 2)];
            *(float4*)b[0] = *(const float4*)&Bs[kk][tx << 2];
            *(float4*)b[1] = *(const float4*)&Bs[kk][64 + (tx << 2)];
#pragma unroll
            for (int rh = 0; rh < 2; ++rh)
#pragma unroll
                for (int ch = 0; ch < 2; ++ch)
#pragma unroll
                    for (int i = 0; i < 4; ++i)
#pragma unroll
                        for (int j = 0; j < 4; ++j)
                            acc[rh][ch][i][j] = fmaf(a[rh][i], b[ch][j], acc[rh][ch][i][j]);
        }
    }
    float4 bi4[2] = {make_float4(0.f, 0.f, 0.f, 0.f), make_float4(0.f, 0.f, 0.f, 0.f)};
    if (bias) {
        bi4[0] = *(const float4*)(bias + bn + (tx << 2));
        bi4[1] = *(const float4*)(bias + bn + 64 + (tx << 2));
    }
#pragma unroll
    for (int rh = 0; rh < 2; ++rh)
#pragma unroll
        for (int i = 0; i < 4; ++i) {
            const int row = bm + rh * 64 + (ty << 2) + i;
#pragma unroll
            for (int ch = 0; ch < 2; ++ch) {
                const int col = bn + ch * 64 + (tx << 2);
                float v0 = acc[rh][ch][i][0] + bi4[ch].x;
                float v1 = acc[rh][ch][i][1] + bi4[ch].y;
                float v2 = acc[rh][ch][i][2] + bi4[ch].z;
                float v3 = acc[rh][ch][i][3] + bi4[ch].w;
                if (ACT == 1) { v0 = tanhf(v0); v1 = tanhf(v1); v2 = tanhf(v2); v3 = tanhf(v3); }
                const int wcol = PERM ? cperm(col) : col;
                *(float4*)(C + (size_t)row * ldc + wcol) = make_float4(v0, v1, v2, v3);
            }
        }
}

// ---------------- transpose + split (optional gate-interleave on cols) ----------------
template<int PERM>
__global__ __launch_bounds__(256)
void tsplit(const float* __restrict__ in, int ldin, int K,
            f16* __restrict__ ohi, f16* __restrict__ olo)
{
    __shared__ float t[32][33];
    const int kb = blockIdx.x << 5, nb = blockIdx.y << 5;
    const int cx = threadIdx.x & 31, ry = threadIdx.x >> 5;
    const int col = PERM ? oc_of(nb + cx) : (nb + cx);
#pragma unroll
    for (int q = 0; q < 4; ++q)
        t[ry + q * 8][cx] = in[(size_t)(kb + ry + q * 8) * ldin + col];
    __syncthreads();
#pragma unroll
    for (int q = 0; q < 4; ++q) {
        const int n = ry + q * 8;
        const float v = t[cx][n];
        const f16 hi = (f16)v;
        ohi[(size_t)(nb + n) * K + kb + cx] = hi;
        olo[(size_t)(nb + n) * K + kb + cx] = (f16)((v - (float)hi) * LO_SCALE);
    }
}

// ---------------- bias permute ----------------
__global__ __launch_bounds__(256)
void permb(const float* __restrict__ b, float* __restrict__ bp)
{
    const int c = blockIdx.x * 256 + threadIdx.x;
    bp[c] = b[oc_of(c)];
}

// ---------------- split f32 -> hi/lo f16 ----------------
__global__ __launch_bounds__(256)
void split_h(const float* __restrict__ h, f16* __restrict__ hi, f16* __restrict__ lo)
{
    const size_t i = (size_t)blockIdx.x * 256 + threadIdx.x;
    const float v = h[i];
    const f16 a = (f16)v;
    hi[i] = a;
    lo[i] = (f16)((v - (float)a) * LO_SCALE);
}

// ---------------- argmax + one-hot ----------------
__global__ __launch_bounds__(256)
void argmax_onehot(const float* __restrict__ logits, const float* __restrict__ gu,
                   float* __restrict__ out0, int* __restrict__ kidx, int t)
{
    const int b = blockIdx.x;
    const int tid = threadIdx.x;
    const float* lrow = logits + (size_t)b * NN;
    const float* urow = gu + ((size_t)t * NB + b) * NN;
    float best = -INFINITY;
    int bi = 0x7fffffff;
#pragma unroll
    for (int q = 0; q < 2; ++q) {
        const int j = tid + q * 256;
        const float u = urow[j];
        const float g = -logf(-logf(u + 1e-20f) + 1e-20f);
        const float v = lrow[j] + g;
        if (v > best || (v == best && j < bi)) { best = v; bi = j; }
    }
#pragma unroll
    for (int off = 32; off > 0; off >>= 1) {
        const float ov = __shfl_down(best, off);
        const int oi = __shfl_down(bi, off);
        if (ov > best || (ov == best && oi < bi)) { best = ov; bi = oi; }
    }
    __shared__ float sv[4];
    __shared__ int si[4];
    const int lane = tid & 63, w = tid >> 6;
    if (lane == 0) { sv[w] = best; si[w] = bi; }
    __syncthreads();
    if (tid == 0) {
        for (int q = 1; q < 4; ++q)
            if (sv[q] > best || (sv[q] == best && si[q] < bi)) { best = sv[q]; bi = si[q]; }
        si[0] = bi;
        kidx[(size_t)t * NB + b] = bi;
    }
    __syncthreads();
    const int win = si[0];
    float* orow = out0 + ((size_t)b * NRW + t) * NN;
#pragma unroll
    for (int q = 0; q < 2; ++q) {
        const int j = tid + q * 256;
        orow[j] = (j == win) ? 1.0f : 0.0f;
    }
}

// ---------------- out1 row-dot from split h ----------------
__global__ __launch_bounds__(256)
void rowdot(const f16* __restrict__ hhi, const f16* __restrict__ hlo,
            const float* __restrict__ Woutl, const float* __restrict__ boutl,
            float* __restrict__ out1, int t)
{
    const int w = threadIdx.x >> 6;
    const int lane = threadIdx.x & 63;
    const int b = blockIdx.x * 4 + w;
    const f16* hr = hhi + (size_t)b * NH;
    const f16* lr = hlo + (size_t)b * NH;
    float s = 0.f;
#pragma unroll
    for (int q = 0; q < 8; ++q) {
        const int j = lane + q * 64;
        const float hv = (float)hr[j] + (float)lr[j] * LO_INV;
        s = fmaf(hv, Woutl[j], s);
    }
#pragma unroll
    for (int off = 32; off > 0; off >>= 1) s += __shfl_down(s, off);
    if (lane == 0) out1[(size_t)b * NRW + t] = s + boutl[0];
}

extern "C" void kernel_launch(void* const* d_in, const int* in_sizes, int n_in,
                              void* d_out, int out_size, void* d_ws, size_t ws_size,
                              hipStream_t stream)
{
    const float* latent  = (const float*)d_in[0];
    const float* gu      = (const float*)d_in[2];
    const float* W_int   = (const float*)d_in[3];
    const float* b_int   = (const float*)d_in[4];
    const float* W_intl  = (const float*)d_in[5];
    const float* b_intl  = (const float*)d_in[6];
    const float* W_hup   = (const float*)d_in[7];
    const float* b_hup   = (const float*)d_in[8];
    const float* W_cup   = (const float*)d_in[9];
    const float* b_cup   = (const float*)d_in[10];
    const float* W_hupl  = (const float*)d_in[11];
    const float* b_hupl  = (const float*)d_in[12];
    const float* W_cupl  = (const float*)d_in[13];
    const float* b_cupl  = (const float*)d_in[14];
    const float* W_lstm  = (const float*)d_in[15];
    const float* b_lstm  = (const float*)d_in[16];
    const float* W_up    = (const float*)d_in[17];
    const float* b_up    = (const float*)d_in[18];
    const float* W_down  = (const float*)d_in[19];
    const float* W_downl = (const float*)d_in[20];
    const float* W_outl  = (const float*)d_in[21];
    const float* b_outl  = (const float*)d_in[22];

    float* out0 = (float*)d_out;                 // [B, RW, N]
    float* out1 = out0 + (size_t)NB * NRW * NN;  // [B, RW, 1]

    // workspace
    float* ws     = (float*)d_ws;
    float* c      = ws;                               // NB*NH
    float* logits = c + (size_t)NB * NH;              // NB*NH (also inter)
    float* htmp   = logits + (size_t)NB * NH;         // NB*NH f32 (init only)
    float* gdown  = htmp + (size_t)NB * NH;           // NN*NG (permuted cols)
    float* gdownl = gdown + (size_t)NN * NG;          // NN*NG (permuted cols)
    float* blp    = gdownl + (size_t)NN * NG;         // NG (permuted b_lstm)
    f16* fp = (f16*)(blp + NG);
    f16* h_hi[2]; f16* h_lo[2];
    h_hi[0] = fp;                    fp += (size_t)NB * NH;
    h_lo[0] = fp;                    fp += (size_t)NB * NH;
    h_hi[1] = fp;                    fp += (size_t)NB * NH;
    h_lo[1] = fp;                    fp += (size_t)NB * NH;
    f16* i_hi   = fp;                fp += (size_t)NB * NH;
    f16* i_lo   = fp;                fp += (size_t)NB * NH;
    f16* WlT_hi = fp;                fp += (size_t)NG * NH;   // permuted rows
    f16* WlT_lo = fp;                fp += (size_t)NG * NH;
    f16* WupT_hi = fp;               fp += (size_t)NN * NH;
    f16* WupT_lo = fp;               fp += (size_t)NN * NH;
    f16* WhT_hi = fp;                fp += (size_t)NH * NH;
    f16* WhT_lo = fp;                fp += (size_t)NH * NH;
    f16* WcT_hi = fp;                fp += (size_t)NH * NH;
    f16* WcT_lo = fp;                fp += (size_t)NH * NH;
    f16* WhlT_hi = fp;               fp += (size_t)NH * NH;
    f16* WhlT_lo = fp;               fp += (size_t)NH * NH;
    f16* WclT_hi = fp;               fp += (size_t)NH * NH;
    f16* WclT_lo = fp;               fp += (size_t)NH * NH;
    int* kidx = (int*)fp;

    const dim3 blk(256);
    const dim3 g_gates(NG / 128, NB / 128);   // 16 x 64
    const dim3 g_h(NH / 128, NB / 128);       // 4 x 64
    const dim3 g_pre(NG / 128, NN / 128);     // 16 x 4
    const dim3 g_sph(NB * NH / 256);

    // ---- prep: weight transpose+split (gate-interleaved for W_lstm); permuted bias;
    //      gather-fused G_down matrices (permuted cols) ----
    tsplit<1><<<dim3(NH / 32, NG / 32), blk, 0, stream>>>(W_lstm + (size_t)NIN * NG, NG, NH, WlT_hi, WlT_lo);
    tsplit<0><<<dim3(NH / 32, NN / 32), blk, 0, stream>>>(W_up, NH, NH, WupT_hi, WupT_lo);
    tsplit<0><<<dim3(NH / 32, NH / 32), blk, 0, stream>>>(W_hup, NH, NH, WhT_hi, WhT_lo);
    tsplit<0><<<dim3(NH / 32, NH / 32), blk, 0, stream>>>(W_cup, NH, NH, WcT_hi, WcT_lo);
    tsplit<0><<<dim3(NH / 32, NH / 32), blk, 0, stream>>>(W_hupl, NH, NH, WhlT_hi, WhlT_lo);
    tsplit<0><<<dim3(NH / 32, NH / 32), blk, 0, stream>>>(W_cupl, NH, NH, WclT_hi, WclT_lo);
    permb<<<dim3(NG / 256), blk, 0, stream>>>(b_lstm, blp);
    gemm128<0, 1><<<g_pre, blk, 0, stream>>>(W_down, NIN, W_lstm, NG, nullptr, gdown, NG, NIN);
    gemm128<0, 1><<<g_pre, blk, 0, stream>>>(W_downl, NIN, W_lstm, NG, nullptr, gdownl, NG, NIN);

    // ---- loop 1 init ----
    gemm128<1, 0><<<g_h, blk, 0, stream>>>(latent, NZ, W_int, NH, b_int, logits, NH, NZ);
    split_h<<<g_sph, blk, 0, stream>>>(logits, i_hi, i_lo);
    mfma_gemm<0, 1><<<g_h, blk, 0, stream>>>(i_hi, i_lo, WhT_hi, WhT_lo, b_hup,
                                             nullptr, nullptr, htmp, NH, NH);
    split_h<<<g_sph, blk, 0, stream>>>(htmp, h_hi[0], h_lo[0]);
    mfma_gemm<0, 1><<<g_h, blk, 0, stream>>>(i_hi, i_lo, WcT_hi, WcT_lo, b_cup,
                                             nullptr, nullptr, c, NH, NH);

    int cur = 0;
    for (int t = 0; t < NRW; ++t) {
        const int nxt = cur ^ 1;
        if (t == 0)
            mfma_gate_lstm<0><<<g_gates, blk, 0, stream>>>(h_hi[cur], h_lo[cur], WlT_hi, WlT_lo,
                                                           blp, nullptr, nullptr,
                                                           c, h_hi[nxt], h_lo[nxt]);
        else
            mfma_gate_lstm<1><<<g_gates, blk, 0, stream>>>(h_hi[cur], h_lo[cur], WlT_hi, WlT_lo,
                                                           blp, gdown, kidx + (size_t)(t - 1) * NB,
                                                           c, h_hi[nxt], h_lo[nxt]);
        mfma_gemm<0, 0><<<g_h, blk, 0, stream>>>(h_hi[nxt], h_lo[nxt], WupT_hi, WupT_lo, b_up,
                                                 nullptr, nullptr, logits, NN, NH);
        argmax_onehot<<<dim3(NB), blk, 0, stream>>>(logits, gu, out0, kidx, t);
        cur = nxt;
    }

    // ---- loop 2 init ----
    gemm128<1, 0><<<g_h, blk, 0, stream>>>(latent, NZ, W_intl, NH, b_intl, logits, NH, NZ);
    split_h<<<g_sph, blk, 0, stream>>>(logits, i_hi, i_lo);
    mfma_gemm<0, 1><<<g_h, blk, 0, stream>>>(i_hi, i_lo, WhlT_hi, WhlT_lo, b_hupl,
                                             nullptr, nullptr, htmp, NH, NH);
    split_h<<<g_sph, blk, 0, stream>>>(htmp, h_hi[0], h_lo[0]);
    mfma_gemm<0, 1><<<g_h, blk, 0, stream>>>(i_hi, i_lo, WclT_hi, WclT_lo, b_cupl,
                                             nullptr, nullptr, c, NH, NH);

    cur = 0;
    for (int t = 0; t < NRW; ++t) {
        const int nxt = cur ^ 1;
        mfma_gate_lstm<1><<<g_gates, blk, 0, stream>>>(h_hi[cur], h_lo[cur], WlT_hi, WlT_lo,
                                                       blp, gdownl, kidx + (size_t)t * NB,
                                                       c, h_hi[nxt], h_lo[nxt]);
        rowdot<<<dim3(NB / 4), blk, 0, stream>>>(h_hi[nxt], h_lo[nxt], W_outl, b_outl, out1, t);
        cur = nxt;
    }
}

// Round 7
// 3225.313 us; speedup vs baseline: 3.7434x; 1.0018x over previous
//
#include <hip/hip_runtime.h>

#define NB 8192
#define NH 512
#define NZ 128
#define NIN 128
#define NN 512
#define NRW 16
#define NG 2048   // 4*NH

typedef _Float16 f16;
typedef _Float16 f16x8 __attribute__((ext_vector_type(8)));
typedef float f32x4 __attribute__((ext_vector_type(4)));

#define LO_SCALE 2048.0f
#define LO_INV   (1.0f / 2048.0f)

__device__ __forceinline__ float sigm(float x) { return 1.0f / (1.0f + expf(-x)); }

// gate-interleaved column permutation: stored col c <- original col oc(c)
__device__ __forceinline__ int oc_of(int c)
{
    return (((c >> 4) & 3) << 9) + ((c >> 6) << 4) + (c & 15);
}
__device__ __forceinline__ int cperm(int j)
{
    return (j & 15) | (((j >> 4) & 31) << 6) | (((j >> 9) & 3) << 4);
}

// ---------------- async 16B global->LDS ----------------
__device__ __forceinline__ void gload16(const f16* g, f16* l)
{
    __builtin_amdgcn_global_load_lds(
        (const __attribute__((address_space(1))) void*)g,
        (__attribute__((address_space(3))) void*)l, 16, 0, 0);
}

// 16B-slot swizzle: 2-way (free) bank aliasing for 16-row b128 column reads.
__device__ __forceinline__ int swz4(int row) { return (row & 3) ^ ((row >> 2) & 3); }

// Stage one 128x32 f16 tile (8KB): linear LDS dest + inverse-swizzled global src.
// 2 global_load_lds per thread.
__device__ __forceinline__ void stage_tile(f16* tilebase, const f16* src,
                                           int rowbase, int K, int kb,
                                           int wid, int lane)
{
#pragma unroll
    for (int q = 0; q < 2; ++q) {
        const int iw = wid * 2 + q;
        const int chunk = (iw << 6) | lane;
        const int row = chunk >> 2;
        const int p = (chunk & 3) ^ swz4(row);
        const f16* g = src + (size_t)(rowbase + row) * K + kb + (p << 3);
        gload16(g, tilebase + (iw << 9));
    }
}

__device__ __forceinline__ f16x8 frag(const f16* tile, int row, int sl)
{
    return *(const f16x8*)(tile + row * 32 + ((sl ^ swz4(row)) << 3));
}

// ---------------- 3-phase counted-vmcnt split-GEMM core ----------------
// accA = Ahi*Bhi ; accB = Alo*Bhi + Ahi*Blo   (C = accA + accB/2048)
// Per k-step: Ph1{wait vmcnt(2); bar; stage Ahi,Alo(t+1); read ah,bh; 16 MFMA}
//             Ph2{bar; stage Bhi(t+1); read al; 16 MFMA}
//             Ph3{wait vmcnt(6|0); bar; stage Blo(t+1); read bl; 16 MFMA}
// Raw s_barrier (no counter drain); issue order pinned by sched_barrier(0).
__device__ __forceinline__ void gemm_core(const f16* Ahi, const f16* Alo,
                                          const f16* Bhi, const f16* Blo,
                                          f16 (*sT)[4][128 * 32],
                                          int bm, int bn, int K,
                                          int wid, int lane, int wr, int wc,
                                          f32x4 (&accA)[4][4], f32x4 (&accB)[4][4])
{
    const int NT = K >> 5;
    stage_tile(sT[0][0], Ahi, bm, K, 0, wid, lane);
    stage_tile(sT[0][1], Alo, bm, K, 0, wid, lane);
    __builtin_amdgcn_sched_barrier(0);
    stage_tile(sT[0][2], Bhi, bn, K, 0, wid, lane);
    __builtin_amdgcn_sched_barrier(0);
    stage_tile(sT[0][3], Blo, bn, K, 0, wid, lane);

    const int r16 = lane & 15, sl = lane >> 4;

    for (int kt = 0; kt < NT; ++kt) {
        const int cur = kt & 1;
        const int nxt = cur ^ 1;
        const bool more = (kt + 1 < NT);
        const int kb = (kt + 1) << 5;

        // ---- phase 1: accA += ah*bh ----
        asm volatile("s_waitcnt vmcnt(2)" ::: "memory");
        __builtin_amdgcn_s_barrier();
        __builtin_amdgcn_sched_barrier(0);
        if (more) {
            stage_tile(sT[nxt][0], Ahi, bm, K, kb, wid, lane);
            stage_tile(sT[nxt][1], Alo, bm, K, kb, wid, lane);
        }
        f16x8 ah[4], bh[4];
#pragma unroll
        for (int f = 0; f < 4; ++f) {
            ah[f] = frag(sT[cur][0], wr + f * 16 + r16, sl);
            bh[f] = frag(sT[cur][2], wc + f * 16 + r16, sl);
        }
        __builtin_amdgcn_s_setprio(1);
#pragma unroll
        for (int i = 0; i < 4; ++i)
#pragma unroll
            for (int j = 0; j < 4; ++j)
                accA[i][j] = __builtin_amdgcn_mfma_f32_16x16x32_f16(ah[i], bh[j], accA[i][j], 0, 0, 0);
        __builtin_amdgcn_s_setprio(0);

        // ---- phase 2: accB += al*bh ----
        __builtin_amdgcn_s_barrier();
        __builtin_amdgcn_sched_barrier(0);
        if (more) stage_tile(sT[nxt][2], Bhi, bn, K, kb, wid, lane);
        f16x8 al[4];
#pragma unroll
        for (int f = 0; f < 4; ++f) al[f] = frag(sT[cur][1], wr + f * 16 + r16, sl);
        __builtin_amdgcn_s_setprio(1);
#pragma unroll
        for (int i = 0; i < 4; ++i)
#pragma unroll
            for (int j = 0; j < 4; ++j)
                accB[i][j] = __builtin_amdgcn_mfma_f32_16x16x32_f16(al[i], bh[j], accB[i][j], 0, 0, 0);
        __builtin_amdgcn_s_setprio(0);

        // ---- phase 3: accB += ah*bl ----
        if (more) asm volatile("s_waitcnt vmcnt(6)" ::: "memory");
        else      asm volatile("s_waitcnt vmcnt(0)" ::: "memory");
        __builtin_amdgcn_s_barrier();
        __builtin_amdgcn_sched_barrier(0);
        if (more) stage_tile(sT[nxt][3], Blo, bn, K, kb, wid, lane);
        f16x8 bl[4];
#pragma unroll
        for (int f = 0; f < 4; ++f) bl[f] = frag(sT[cur][3], wc + f * 16 + r16, sl);
        __builtin_amdgcn_s_setprio(1);
#pragma unroll
        for (int i = 0; i < 4; ++i)
#pragma unroll
            for (int j = 0; j < 4; ++j)
                accB[i][j] = __builtin_amdgcn_mfma_f32_16x16x32_f16(ah[i], bl[j], accB[i][j], 0, 0, 0);
        __builtin_amdgcn_s_setprio(0);
    }
}

// ---------------- plain split GEMM (logits / inits) ----------------
template<int HAS_EXTRA, int ACT>
__global__ __launch_bounds__(256, 2)
void mfma_gemm(const f16* __restrict__ Ahi, const f16* __restrict__ Alo,
               const f16* __restrict__ Bhi, const f16* __restrict__ Blo,
               const float* __restrict__ bias,
               const float* __restrict__ extra, const int* __restrict__ eidx,
               float* __restrict__ C, int N, int K)
{
    __shared__ f16 sT[2][4][128 * 32];
    const int bm = blockIdx.y << 7;
    const int bn = blockIdx.x << 7;
    const int tid = threadIdx.x;
    const int wid = tid >> 6, lane = tid & 63;
    const int wr = ((wid >> 1) & 1) << 6;
    const int wc = (wid & 1) << 6;

    f32x4 accA[4][4], accB[4][4];
#pragma unroll
    for (int i = 0; i < 4; ++i)
#pragma unroll
        for (int j = 0; j < 4; ++j) { accA[i][j] = (f32x4)(0.0f); accB[i][j] = (f32x4)(0.0f); }

    gemm_core(Ahi, Alo, Bhi, Blo, sT, bm, bn, K, wid, lane, wr, wc, accA, accB);

    const int r16 = lane & 15;
    const int rg = lane >> 4;
#pragma unroll
    for (int i = 0; i < 4; ++i) {
#pragma unroll
        for (int r = 0; r < 4; ++r) {
            const int row = bm + wr + i * 16 + rg * 4 + r;
            const float* exrow = nullptr;
            if (HAS_EXTRA) exrow = extra + (size_t)eidx[row] * N;
#pragma unroll
            for (int j = 0; j < 4; ++j) {
                const int col = bn + wc + j * 16 + r16;
                float v = accA[i][j][r] + accB[i][j][r] * LO_INV;
                if (bias) v += bias[col];
                if (HAS_EXTRA) v += exrow[col];
                if (ACT == 1) v = tanhf(v);
                C[(size_t)row * N + col] = v;
            }
        }
    }
}

// ---------------- fused gate GEMM + LSTM pointwise ----------------
template<int HAS_EXTRA>
__global__ __launch_bounds__(256, 2)
void mfma_gate_lstm(const f16* __restrict__ Ahi, const f16* __restrict__ Alo,
                    const f16* __restrict__ Bhi, const f16* __restrict__ Blo,
                    const float* __restrict__ blp,
                    const float* __restrict__ extra, const int* __restrict__ eidx,
                    float* __restrict__ c,
                    f16* __restrict__ h_hi, f16* __restrict__ h_lo)
{
    __shared__ f16 sT[2][4][128 * 32];
    const int bm = blockIdx.y << 7;
    const int bn = blockIdx.x << 7;
    const int tid = threadIdx.x;
    const int wid = tid >> 6, lane = tid & 63;
    const int wr = ((wid >> 1) & 1) << 6;
    const int wc = (wid & 1) << 6;

    f32x4 accA[4][4], accB[4][4];
#pragma unroll
    for (int i = 0; i < 4; ++i)
#pragma unroll
        for (int j = 0; j < 4; ++j) { accA[i][j] = (f32x4)(0.0f); accB[i][j] = (f32x4)(0.0f); }

    gemm_core(Ahi, Alo, Bhi, Blo, sT, bm, bn, NH, wid, lane, wr, wc, accA, accB);

    const int m = lane & 15;
    const int rg = lane >> 4;
    const int colb = bn + wc;                 // multiple of 64
    const int jj = ((colb >> 6) << 4) + m;    // LSTM unit index
    float bi[4];
#pragma unroll
    for (int g = 0; g < 4; ++g) bi[g] = blp[colb + g * 16 + m];

#pragma unroll
    for (int i = 0; i < 4; ++i) {
#pragma unroll
        for (int r = 0; r < 4; ++r) {
            const int row = bm + wr + i * 16 + rg * 4 + r;
            float ex[4] = {0.f, 0.f, 0.f, 0.f};
            if (HAS_EXTRA) {
                const float* exr = extra + (size_t)eidx[row] * NG;
#pragma unroll
                for (int g = 0; g < 4; ++g) ex[g] = exr[colb + g * 16 + m];
            }
            const float ig = accA[i][0][r] + accB[i][0][r] * LO_INV + bi[0] + ex[0];
            const float gg = accA[i][1][r] + accB[i][1][r] * LO_INV + bi[1] + ex[1];
            const float fg = accA[i][2][r] + accB[i][2][r] * LO_INV + bi[2] + ex[2];
            const float og = accA[i][3][r] + accB[i][3][r] * LO_INV + bi[3] + ex[3];
            const size_t cidx = (size_t)row * NH + jj;
            const float cx = c[cidx];
            const float cy = cx * sigm(fg + 1.0f) + sigm(ig) * tanhf(gg);
            const float hy = sigm(og) * tanhf(cy);
            c[cidx] = cy;
            const f16 a = (f16)hy;
            h_hi[cidx] = a;
            h_lo[cidx] = (f16)((hy - (float)a) * LO_SCALE);
        }
    }
}

// ---------------- f32 vector GEMM (K=128 prep/init only) ----------------
template<int ACT, int PERM>
__global__ __launch_bounds__(256)
void gemm128(const float* __restrict__ A, int lda,
             const float* __restrict__ W, int ldw,
             const float* __restrict__ bias,
             float* __restrict__ C, int ldc, int K)
{
    __shared__ float As[16][128];
    __shared__ float Bs[16][128];
    const int bm = blockIdx.y << 7, bn = blockIdx.x << 7;
    const int tid = threadIdx.x;
    const int tx = tid & 15, ty = tid >> 4;
    const int sar = tid >> 1, sac = (tid & 1) << 3;
    const int sbk = tid >> 4, sbc = (tid & 15) << 3;
    float acc[2][2][4][4] = {};
    const float* Ap = A + (size_t)(bm + sar) * lda + sac;
    const float* Wp = W + (size_t)sbk * ldw + bn + sbc;
    for (int kb = 0; kb < K; kb += 16) {
        const float4 av0 = *(const float4*)(Ap + kb);
        const float4 av1 = *(const float4*)(Ap + kb + 4);
        const float4 bv0 = *(const float4*)(Wp + (size_t)kb * ldw);
        const float4 bv1 = *(const float4*)(Wp + (size_t)kb * ldw + 4);
        __syncthreads();
        As[sac + 0][sar] = av0.x; As[sac + 1][sar] = av0.y;
        As[sac + 2][sar] = av0.z; As[sac + 3][sar] = av0.w;
        As[sac + 4][sar] = av1.x; As[sac + 5][sar] = av1.y;
        As[sac + 6][sar] = av1.z; As[sac + 7][sar] = av1.w;
        *(float4*)&Bs[sbk][sbc] = bv0;
        *(float4*)&Bs[sbk][sbc + 4] = bv1;
        __syncthreads();
#pragma unroll
        for (int kk = 0; kk < 16; ++kk) {
            float a[2][4], b[2][4];
            *(float4*)a[0] = *(const float4*)&As[kk][ty << 2];
            *(float4*)a[1] = *(const float4*)&As[kk][64 + (ty << 2)];
            *(float4*)b[0] = *(const float4*)&Bs[kk][tx << 2];
            *(float4*)b[1] = *(const float4*)&Bs[kk][64 + (tx << 2)];
#pragma unroll
            for (int rh = 0; rh < 2; ++rh)
#pragma unroll
                for (int ch = 0; ch < 2; ++ch)
#pragma unroll
                    for (int i = 0; i < 4; ++i)
#pragma unroll
                        for (int j = 0; j < 4; ++j)
                            acc[rh][ch][i][j] = fmaf(a[rh][i], b[ch][j], acc[rh][ch][i][j]);
        }
    }
    float4 bi4[2] = {make_float4(0.f, 0.f, 0.f, 0.f), make_float4(0.f, 0.f, 0.f, 0.f)};
    if (bias) {
        bi4[0] = *(const float4*)(bias + bn + (tx << 2));
        bi4[1] = *(const float4*)(bias + bn + 64 + (tx << 2));
    }
#pragma unroll
    for (int rh = 0; rh < 2; ++rh)
#pragma unroll
        for (int i = 0; i < 4; ++i) {
            const int row = bm + rh * 64 + (ty << 2) + i;
#pragma unroll
            for (int ch = 0; ch < 2; ++ch) {
                const int col = bn + ch * 64 + (tx << 2);
                float v0 = acc[rh][ch][i][0] + bi4[ch].x;
                float v1 = acc[rh][ch][i][1] + bi4[ch].y;
                float v2 = acc[rh][ch][i][2] + bi4[ch].z;
                float v3 = acc[rh][ch][i][3] + bi4[ch].w;
                if (ACT == 1) { v0 = tanhf(v0); v1 = tanhf(v1); v2 = tanhf(v2); v3 = tanhf(v3); }
                const int wcol = PERM ? cperm(col) : col;
                *(float4*)(C + (size_t)row * ldc + wcol) = make_float4(v0, v1, v2, v3);
            }
        }
}

// ---------------- transpose + split (optional gate-interleave on cols) ----------------
template<int PERM>
__global__ __launch_bounds__(256)
void tsplit(const float* __restrict__ in, int ldin, int K,
            f16* __restrict__ ohi, f16* __restrict__ olo)
{
    __shared__ float t[32][33];
    const int kb = blockIdx.x << 5, nb = blockIdx.y << 5;
    const int cx = threadIdx.x & 31, ry = threadIdx.x >> 5;
    const int col = PERM ? oc_of(nb + cx) : (nb + cx);
#pragma unroll
    for (int q = 0; q < 4; ++q)
        t[ry + q * 8][cx] = in[(size_t)(kb + ry + q * 8) * ldin + col];
    __syncthreads();
#pragma unroll
    for (int q = 0; q < 4; ++q) {
        const int n = ry + q * 8;
        const float v = t[cx][n];
        const f16 hi = (f16)v;
        ohi[(size_t)(nb + n) * K + kb + cx] = hi;
        olo[(size_t)(nb + n) * K + kb + cx] = (f16)((v - (float)hi) * LO_SCALE);
    }
}

// ---------------- bias permute ----------------
__global__ __launch_bounds__(256)
void permb(const float* __restrict__ b, float* __restrict__ bp)
{
    const int c = blockIdx.x * 256 + threadIdx.x;
    bp[c] = b[oc_of(c)];
}

// ---------------- split f32 -> hi/lo f16 ----------------
__global__ __launch_bounds__(256)
void split_h(const float* __restrict__ h, f16* __restrict__ hi, f16* __restrict__ lo)
{
    const size_t i = (size_t)blockIdx.x * 256 + threadIdx.x;
    const float v = h[i];
    const f16 a = (f16)v;
    hi[i] = a;
    lo[i] = (f16)((v - (float)a) * LO_SCALE);
}

// ---------------- argmax + one-hot ----------------
__global__ __launch_bounds__(256)
void argmax_onehot(const float* __restrict__ logits, const float* __restrict__ gu,
                   float* __restrict__ out0, int* __restrict__ kidx, int t)
{
    const int b = blockIdx.x;
    const int tid = threadIdx.x;
    const float* lrow = logits + (size_t)b * NN;
    const float* urow = gu + ((size_t)t * NB + b) * NN;
    float best = -INFINITY;
    int bi = 0x7fffffff;
#pragma unroll
    for (int q = 0; q < 2; ++q) {
        const int j = tid + q * 256;
        const float u = urow[j];
        const float g = -logf(-logf(u + 1e-20f) + 1e-20f);
        const float v = lrow[j] + g;
        if (v > best || (v == best && j < bi)) { best = v; bi = j; }
    }
#pragma unroll
    for (int off = 32; off > 0; off >>= 1) {
        const float ov = __shfl_down(best, off);
        const int oi = __shfl_down(bi, off);
        if (ov > best || (ov == best && oi < bi)) { best = ov; bi = oi; }
    }
    __shared__ float sv[4];
    __shared__ int si[4];
    const int lane = tid & 63, w = tid >> 6;
    if (lane == 0) { sv[w] = best; si[w] = bi; }
    __syncthreads();
    if (tid == 0) {
        for (int q = 1; q < 4; ++q)
            if (sv[q] > best || (sv[q] == best && si[q] < bi)) { best = sv[q]; bi = si[q]; }
        si[0] = bi;
        kidx[(size_t)t * NB + b] = bi;
    }
    __syncthreads();
    const int win = si[0];
    float* orow = out0 + ((size_t)b * NRW + t) * NN;
#pragma unroll
    for (int q = 0; q < 2; ++q) {
        const int j = tid + q * 256;
        orow[j] = (j == win) ? 1.0f : 0.0f;
    }
}

// ---------------- out1 row-dot from split h ----------------
__global__ __launch_bounds__(256)
void rowdot(const f16* __restrict__ hhi, const f16* __restrict__ hlo,
            const float* __restrict__ Woutl, const float* __restrict__ boutl,
            float* __restrict__ out1, int t)
{
    const int w = threadIdx.x >> 6;
    const int lane = threadIdx.x & 63;
    const int b = blockIdx.x * 4 + w;
    const f16* hr = hhi + (size_t)b * NH;
    const f16* lr = hlo + (size_t)b * NH;
    float s = 0.f;
#pragma unroll
    for (int q = 0; q < 8; ++q) {
        const int j = lane + q * 64;
        const float hv = (float)hr[j] + (float)lr[j] * LO_INV;
        s = fmaf(hv, Woutl[j], s);
    }
#pragma unroll
    for (int off = 32; off > 0; off >>= 1) s += __shfl_down(s, off);
    if (lane == 0) out1[(size_t)b * NRW + t] = s + boutl[0];
}

extern "C" void kernel_launch(void* const* d_in, const int* in_sizes, int n_in,
                              void* d_out, int out_size, void* d_ws, size_t ws_size,
                              hipStream_t stream)
{
    const float* latent  = (const float*)d_in[0];
    const float* gu      = (const float*)d_in[2];
    const float* W_int   = (const float*)d_in[3];
    const float* b_int   = (const float*)d_in[4];
    const float* W_intl  = (const float*)d_in[5];
    const float* b_intl  = (const float*)d_in[6];
    const float* W_hup   = (const float*)d_in[7];
    const float* b_hup   = (const float*)d_in[8];
    const float* W_cup   = (const float*)d_in[9];
    const float* b_cup   = (const float*)d_in[10];
    const float* W_hupl  = (const float*)d_in[11];
    const float* b_hupl  = (const float*)d_in[12];
    const float* W_cupl  = (const float*)d_in[13];
    const float* b_cupl  = (const float*)d_in[14];
    const float* W_lstm  = (const float*)d_in[15];
    const float* b_lstm  = (const float*)d_in[16];
    const float* W_up    = (const float*)d_in[17];
    const float* b_up    = (const float*)d_in[18];
    const float* W_down  = (const float*)d_in[19];
    const float* W_downl = (const float*)d_in[20];
    const float* W_outl  = (const float*)d_in[21];
    const float* b_outl  = (const float*)d_in[22];

    float* out0 = (float*)d_out;                 // [B, RW, N]
    float* out1 = out0 + (size_t)NB * NRW * NN;  // [B, RW, 1]

    // workspace
    float* ws     = (float*)d_ws;
    float* c      = ws;                               // NB*NH
    float* logits = c + (size_t)NB * NH;              // NB*NH (also inter)
    float* htmp   = logits + (size_t)NB * NH;         // NB*NH f32 (init only)
    float* gdown  = htmp + (size_t)NB * NH;           // NN*NG (permuted cols)
    float* gdownl = gdown + (size_t)NN * NG;          // NN*NG (permuted cols)
    float* blp    = gdownl + (size_t)NN * NG;         // NG (permuted b_lstm)
    f16* fp = (f16*)(blp + NG);
    f16* h_hi[2]; f16* h_lo[2];
    h_hi[0] = fp;                    fp += (size_t)NB * NH;
    h_lo[0] = fp;                    fp += (size_t)NB * NH;
    h_hi[1] = fp;                    fp += (size_t)NB * NH;
    h_lo[1] = fp;                    fp += (size_t)NB * NH;
    f16* i_hi   = fp;                fp += (size_t)NB * NH;
    f16* i_lo   = fp;                fp += (size_t)NB * NH;
    f16* WlT_hi = fp;                fp += (size_t)NG * NH;   // permuted rows
    f16* WlT_lo = fp;                fp += (size_t)NG * NH;
    f16* WupT_hi = fp;               fp += (size_t)NN * NH;
    f16* WupT_lo = fp;               fp += (size_t)NN * NH;
    f16* WhT_hi = fp;                fp += (size_t)NH * NH;
    f16* WhT_lo = fp;                fp += (size_t)NH * NH;
    f16* WcT_hi = fp;                fp += (size_t)NH * NH;
    f16* WcT_lo = fp;                fp += (size_t)NH * NH;
    f16* WhlT_hi = fp;               fp += (size_t)NH * NH;
    f16* WhlT_lo = fp;               fp += (size_t)NH * NH;
    f16* WclT_hi = fp;               fp += (size_t)NH * NH;
    f16* WclT_lo = fp;               fp += (size_t)NH * NH;
    int* kidx = (int*)fp;

    const dim3 blk(256);
    const dim3 g_gates(NG / 128, NB / 128);   // 16 x 64
    const dim3 g_h(NH / 128, NB / 128);       // 4 x 64
    const dim3 g_pre(NG / 128, NN / 128);     // 16 x 4
    const dim3 g_sph(NB * NH / 256);

    // ---- prep ----
    tsplit<1><<<dim3(NH / 32, NG / 32), blk, 0, stream>>>(W_lstm + (size_t)NIN * NG, NG, NH, WlT_hi, WlT_lo);
    tsplit<0><<<dim3(NH / 32, NN / 32), blk, 0, stream>>>(W_up, NH, NH, WupT_hi, WupT_lo);
    tsplit<0><<<dim3(NH / 32, NH / 32), blk, 0, stream>>>(W_hup, NH, NH, WhT_hi, WhT_lo);
    tsplit<0><<<dim3(NH / 32, NH / 32), blk, 0, stream>>>(W_cup, NH, NH, WcT_hi, WcT_lo);
    tsplit<0><<<dim3(NH / 32, NH / 32), blk, 0, stream>>>(W_hupl, NH, NH, WhlT_hi, WhlT_lo);
    tsplit<0><<<dim3(NH / 32, NH / 32), blk, 0, stream>>>(W_cupl, NH, NH, WclT_hi, WclT_lo);
    permb<<<dim3(NG / 256), blk, 0, stream>>>(b_lstm, blp);
    gemm128<0, 1><<<g_pre, blk, 0, stream>>>(W_down, NIN, W_lstm, NG, nullptr, gdown, NG, NIN);
    gemm128<0, 1><<<g_pre, blk, 0, stream>>>(W_downl, NIN, W_lstm, NG, nullptr, gdownl, NG, NIN);

    // ---- loop 1 init ----
    gemm128<1, 0><<<g_h, blk, 0, stream>>>(latent, NZ, W_int, NH, b_int, logits, NH, NZ);
    split_h<<<g_sph, blk, 0, stream>>>(logits, i_hi, i_lo);
    mfma_gemm<0, 1><<<g_h, blk, 0, stream>>>(i_hi, i_lo, WhT_hi, WhT_lo, b_hup,
                                             nullptr, nullptr, htmp, NH, NH);
    split_h<<<g_sph, blk, 0, stream>>>(htmp, h_hi[0], h_lo[0]);
    mfma_gemm<0, 1><<<g_h, blk, 0, stream>>>(i_hi, i_lo, WcT_hi, WcT_lo, b_cup,
                                             nullptr, nullptr, c, NH, NH);

    int cur = 0;
    for (int t = 0; t < NRW; ++t) {
        const int nxt = cur ^ 1;
        if (t == 0)
            mfma_gate_lstm<0><<<g_gates, blk, 0, stream>>>(h_hi[cur], h_lo[cur], WlT_hi, WlT_lo,
                                                           blp, nullptr, nullptr,
                                                           c, h_hi[nxt], h_lo[nxt]);
        else
            mfma_gate_lstm<1><<<g_gates, blk, 0, stream>>>(h_hi[cur], h_lo[cur], WlT_hi, WlT_lo,
                                                           blp, gdown, kidx + (size_t)(t - 1) * NB,
                                                           c, h_hi[nxt], h_lo[nxt]);
        mfma_gemm<0, 0><<<g_h, blk, 0, stream>>>(h_hi[nxt], h_lo[nxt], WupT_hi, WupT_lo, b_up,
                                                 nullptr, nullptr, logits, NN, NH);
        argmax_onehot<<<dim3(NB), blk, 0, stream>>>(logits, gu, out0, kidx, t);
        cur = nxt;
    }

    // ---- loop 2 init ----
    gemm128<1, 0><<<g_h, blk, 0, stream>>>(latent, NZ, W_intl, NH, b_intl, logits, NH, NZ);
    split_h<<<g_sph, blk, 0, stream>>>(logits, i_hi, i_lo);
    mfma_gemm<0, 1><<<g_h, blk, 0, stream>>>(i_hi, i_lo, WhlT_hi, WhlT_lo, b_hupl,
                                             nullptr, nullptr, htmp, NH, NH);
    split_h<<<g_sph, blk, 0, stream>>>(htmp, h_hi[0], h_lo[0]);
    mfma_gemm<0, 1><<<g_h, blk, 0, stream>>>(i_hi, i_lo, WclT_hi, WclT_lo, b_cupl,
                                             nullptr, nullptr, c, NH, NH);

    cur = 0;
    for (int t = 0; t < NRW; ++t) {
        const int nxt = cur ^ 1;
        mfma_gate_lstm<1><<<g_gates, blk, 0, stream>>>(h_hi[cur], h_lo[cur], WlT_hi, WlT_lo,
                                                       blp, gdownl, kidx + (size_t)t * NB,
                                                       c, h_hi[nxt], h_lo[nxt]);
        rowdot<<<dim3(NB / 4), blk, 0, stream>>>(h_hi[nxt], h_lo[nxt], W_outl, b_outl, out1, t);
        cur = nxt;
    }
}

// Round 8
// 3091.736 us; speedup vs baseline: 3.9052x; 1.0432x over previous
//
#include <hip/hip_runtime.h>

#define NB 8192
#define NH 512
#define NZ 128
#define NIN 128
#define NN 512
#define NRW 16
#define NG 2048   // 4*NH

typedef _Float16 f16;
typedef _Float16 f16x8 __attribute__((ext_vector_type(8)));
typedef float f32x4 __attribute__((ext_vector_type(4)));

#define LO_SCALE 2048.0f
#define LO_INV   (1.0f / 2048.0f)

__device__ __forceinline__ float sigm(float x) { return 1.0f / (1.0f + expf(-x)); }

// gate-interleaved column permutation: stored col c <- original col oc(c)
__device__ __forceinline__ int oc_of(int c)
{
    return (((c >> 4) & 3) << 9) + ((c >> 6) << 4) + (c & 15);
}
__device__ __forceinline__ int cperm(int j)
{
    return (j & 15) | (((j >> 4) & 31) << 6) | (((j >> 9) & 3) << 4);
}

// Bijective XCD-aware block swizzle (requires nwg % 8 == 0; all our grids comply).
__device__ __forceinline__ void swz_xcd(int& bx, int& by)
{
    const int gx = gridDim.x;
    const int nwg = gx * gridDim.y;
    int lin = by * gx + bx;
    lin = (lin & 7) * (nwg >> 3) + (lin >> 3);
    const int sh = 31 - __clz(gx);     // gx is a power of two (4 or 16)
    bx = lin & (gx - 1);
    by = lin >> sh;
}

// ---------------- async 16B global->LDS ----------------
__device__ __forceinline__ void gload16(const f16* g, f16* l)
{
    __builtin_amdgcn_global_load_lds(
        (const __attribute__((address_space(1))) void*)g,
        (__attribute__((address_space(3))) void*)l, 16, 0, 0);
}

// 16B-slot swizzle: 2-way (free) bank aliasing for 16-row b128 column reads.
__device__ __forceinline__ int swz4(int row) { return (row & 3) ^ ((row >> 2) & 3); }

// Stage one 128x32 f16 tile (8KB): linear LDS dest + inverse-swizzled global src.
__device__ __forceinline__ void stage_tile(f16* tilebase, const f16* src,
                                           int rowbase, int K, int kb,
                                           int wid, int lane)
{
#pragma unroll
    for (int q = 0; q < 2; ++q) {
        const int iw = wid * 2 + q;
        const int chunk = (iw << 6) | lane;
        const int row = chunk >> 2;
        const int p = (chunk & 3) ^ swz4(row);
        const f16* g = src + (size_t)(rowbase + row) * K + kb + (p << 3);
        gload16(g, tilebase + (iw << 9));
    }
}

__device__ __forceinline__ f16x8 frag(const f16* tile, int row, int sl)
{
    return *(const f16x8*)(tile + row * 32 + ((sl ^ swz4(row)) << 3));
}

// ---------------- 3-pass counted-vmcnt split-GEMM core (loop-1 precision) ----------------
__device__ __forceinline__ void gemm_core(const f16* Ahi, const f16* Alo,
                                          const f16* Bhi, const f16* Blo,
                                          f16 (*sT)[4][128 * 32],
                                          int bm, int bn, int K,
                                          int wid, int lane, int wr, int wc,
                                          f32x4 (&accA)[4][4], f32x4 (&accB)[4][4])
{
    const int NT = K >> 5;
    stage_tile(sT[0][0], Ahi, bm, K, 0, wid, lane);
    stage_tile(sT[0][1], Alo, bm, K, 0, wid, lane);
    __builtin_amdgcn_sched_barrier(0);
    stage_tile(sT[0][2], Bhi, bn, K, 0, wid, lane);
    __builtin_amdgcn_sched_barrier(0);
    stage_tile(sT[0][3], Blo, bn, K, 0, wid, lane);

    const int r16 = lane & 15, sl = lane >> 4;

    for (int kt = 0; kt < NT; ++kt) {
        const int cur = kt & 1;
        const int nxt = cur ^ 1;
        const bool more = (kt + 1 < NT);
        const int kb = (kt + 1) << 5;

        // ---- phase 1: accA += ah*bh ----
        asm volatile("s_waitcnt vmcnt(2)" ::: "memory");
        __builtin_amdgcn_s_barrier();
        __builtin_amdgcn_sched_barrier(0);
        if (more) {
            stage_tile(sT[nxt][0], Ahi, bm, K, kb, wid, lane);
            stage_tile(sT[nxt][1], Alo, bm, K, kb, wid, lane);
        }
        f16x8 ah[4], bh[4];
#pragma unroll
        for (int f = 0; f < 4; ++f) {
            ah[f] = frag(sT[cur][0], wr + f * 16 + r16, sl);
            bh[f] = frag(sT[cur][2], wc + f * 16 + r16, sl);
        }
        __builtin_amdgcn_s_setprio(1);
#pragma unroll
        for (int i = 0; i < 4; ++i)
#pragma unroll
            for (int j = 0; j < 4; ++j)
                accA[i][j] = __builtin_amdgcn_mfma_f32_16x16x32_f16(ah[i], bh[j], accA[i][j], 0, 0, 0);
        __builtin_amdgcn_s_setprio(0);

        // ---- phase 2: accB += al*bh ----
        __builtin_amdgcn_s_barrier();
        __builtin_amdgcn_sched_barrier(0);
        if (more) stage_tile(sT[nxt][2], Bhi, bn, K, kb, wid, lane);
        f16x8 al[4];
#pragma unroll
        for (int f = 0; f < 4; ++f) al[f] = frag(sT[cur][1], wr + f * 16 + r16, sl);
        __builtin_amdgcn_s_setprio(1);
#pragma unroll
        for (int i = 0; i < 4; ++i)
#pragma unroll
            for (int j = 0; j < 4; ++j)
                accB[i][j] = __builtin_amdgcn_mfma_f32_16x16x32_f16(al[i], bh[j], accB[i][j], 0, 0, 0);
        __builtin_amdgcn_s_setprio(0);

        // ---- phase 3: accB += ah*bl ----
        if (more) asm volatile("s_waitcnt vmcnt(6)" ::: "memory");
        else      asm volatile("s_waitcnt vmcnt(0)" ::: "memory");
        __builtin_amdgcn_s_barrier();
        __builtin_amdgcn_sched_barrier(0);
        if (more) stage_tile(sT[nxt][3], Blo, bn, K, kb, wid, lane);
        f16x8 bl[4];
#pragma unroll
        for (int f = 0; f < 4; ++f) bl[f] = frag(sT[cur][3], wc + f * 16 + r16, sl);
        __builtin_amdgcn_s_setprio(1);
#pragma unroll
        for (int i = 0; i < 4; ++i)
#pragma unroll
            for (int j = 0; j < 4; ++j)
                accB[i][j] = __builtin_amdgcn_mfma_f32_16x16x32_f16(ah[i], bl[j], accB[i][j], 0, 0, 0);
        __builtin_amdgcn_s_setprio(0);
    }
}

// ---------------- 2-pass core (loop-2: f16-rounded weights, exact-split A) ----------------
__device__ __forceinline__ void gemm_core2(const f16* Ahi, const f16* Alo, const f16* Bhi,
                                           f16 (*sT)[3][128 * 32],
                                           int bm, int bn, int K,
                                           int wid, int lane, int wr, int wc,
                                           f32x4 (&accA)[4][4], f32x4 (&accB)[4][4])
{
    const int NT = K >> 5;
    stage_tile(sT[0][0], Ahi, bm, K, 0, wid, lane);
    stage_tile(sT[0][1], Alo, bm, K, 0, wid, lane);
    stage_tile(sT[0][2], Bhi, bn, K, 0, wid, lane);

    const int r16 = lane & 15, sl = lane >> 4;

    for (int kt = 0; kt < NT; ++kt) {
        const int cur = kt & 1;
        const int nxt = cur ^ 1;
        __syncthreads();                 // drains vmcnt: buf[cur] ready
        if (kt + 1 < NT) {
            const int kb = (kt + 1) << 5;
            stage_tile(sT[nxt][0], Ahi, bm, K, kb, wid, lane);
            stage_tile(sT[nxt][1], Alo, bm, K, kb, wid, lane);
            stage_tile(sT[nxt][2], Bhi, bn, K, kb, wid, lane);
        }
        f16x8 ah[4], al[4], bh[4];
#pragma unroll
        for (int f = 0; f < 4; ++f) {
            ah[f] = frag(sT[cur][0], wr + f * 16 + r16, sl);
            al[f] = frag(sT[cur][1], wr + f * 16 + r16, sl);
            bh[f] = frag(sT[cur][2], wc + f * 16 + r16, sl);
        }
        __builtin_amdgcn_s_setprio(1);
#pragma unroll
        for (int i = 0; i < 4; ++i)
#pragma unroll
            for (int j = 0; j < 4; ++j) {
                accA[i][j] = __builtin_amdgcn_mfma_f32_16x16x32_f16(ah[i], bh[j], accA[i][j], 0, 0, 0);
                accB[i][j] = __builtin_amdgcn_mfma_f32_16x16x32_f16(al[i], bh[j], accB[i][j], 0, 0, 0);
            }
        __builtin_amdgcn_s_setprio(0);
    }
}

// ---------------- plain split GEMM (logits / inits, 3-pass) ----------------
template<int HAS_EXTRA, int ACT>
__global__ __launch_bounds__(256, 2)
void mfma_gemm(const f16* __restrict__ Ahi, const f16* __restrict__ Alo,
               const f16* __restrict__ Bhi, const f16* __restrict__ Blo,
               const float* __restrict__ bias,
               const float* __restrict__ extra, const int* __restrict__ eidx,
               float* __restrict__ C, int N, int K)
{
    __shared__ f16 sT[2][4][128 * 32];
    int bx = blockIdx.x, by = blockIdx.y;
    swz_xcd(bx, by);
    const int bm = by << 7;
    const int bn = bx << 7;
    const int tid = threadIdx.x;
    const int wid = tid >> 6, lane = tid & 63;
    const int wr = ((wid >> 1) & 1) << 6;
    const int wc = (wid & 1) << 6;

    f32x4 accA[4][4], accB[4][4];
#pragma unroll
    for (int i = 0; i < 4; ++i)
#pragma unroll
        for (int j = 0; j < 4; ++j) { accA[i][j] = (f32x4)(0.0f); accB[i][j] = (f32x4)(0.0f); }

    gemm_core(Ahi, Alo, Bhi, Blo, sT, bm, bn, K, wid, lane, wr, wc, accA, accB);

    const int r16 = lane & 15;
    const int rg = lane >> 4;
#pragma unroll
    for (int i = 0; i < 4; ++i) {
#pragma unroll
        for (int r = 0; r < 4; ++r) {
            const int row = bm + wr + i * 16 + rg * 4 + r;
            const float* exrow = nullptr;
            if (HAS_EXTRA) exrow = extra + (size_t)eidx[row] * N;
#pragma unroll
            for (int j = 0; j < 4; ++j) {
                const int col = bn + wc + j * 16 + r16;
                float v = accA[i][j][r] + accB[i][j][r] * LO_INV;
                if (bias) v += bias[col];
                if (HAS_EXTRA) v += exrow[col];
                if (ACT == 1) v = tanhf(v);
                C[(size_t)row * N + col] = v;
            }
        }
    }
}

// ---------------- loop-1 fused gate GEMM + LSTM pointwise (3-pass) ----------------
template<int HAS_EXTRA>
__global__ __launch_bounds__(256, 2)
void mfma_gate_lstm(const f16* __restrict__ Ahi, const f16* __restrict__ Alo,
                    const f16* __restrict__ Bhi, const f16* __restrict__ Blo,
                    const float* __restrict__ blp,
                    const float* __restrict__ extra, const int* __restrict__ eidx,
                    float* __restrict__ c,
                    f16* __restrict__ h_hi, f16* __restrict__ h_lo)
{
    __shared__ f16 sT[2][4][128 * 32];
    int bx = blockIdx.x, by = blockIdx.y;
    swz_xcd(bx, by);
    const int bm = by << 7;
    const int bn = bx << 7;
    const int tid = threadIdx.x;
    const int wid = tid >> 6, lane = tid & 63;
    const int wr = ((wid >> 1) & 1) << 6;
    const int wc = (wid & 1) << 6;

    f32x4 accA[4][4], accB[4][4];
#pragma unroll
    for (int i = 0; i < 4; ++i)
#pragma unroll
        for (int j = 0; j < 4; ++j) { accA[i][j] = (f32x4)(0.0f); accB[i][j] = (f32x4)(0.0f); }

    gemm_core(Ahi, Alo, Bhi, Blo, sT, bm, bn, NH, wid, lane, wr, wc, accA, accB);

    const int m = lane & 15;
    const int rg = lane >> 4;
    const int colb = bn + wc;                 // multiple of 64
    const int jj = ((colb >> 6) << 4) + m;    // LSTM unit index
    float bi[4];
#pragma unroll
    for (int g = 0; g < 4; ++g) bi[g] = blp[colb + g * 16 + m];

#pragma unroll
    for (int i = 0; i < 4; ++i) {
#pragma unroll
        for (int r = 0; r < 4; ++r) {
            const int row = bm + wr + i * 16 + rg * 4 + r;
            float ex[4] = {0.f, 0.f, 0.f, 0.f};
            if (HAS_EXTRA) {
                const float* exr = extra + (size_t)eidx[row] * NG;
#pragma unroll
                for (int g = 0; g < 4; ++g) ex[g] = exr[colb + g * 16 + m];
            }
            const float ig = accA[i][0][r] + accB[i][0][r] * LO_INV + bi[0] + ex[0];
            const float gg = accA[i][1][r] + accB[i][1][r] * LO_INV + bi[1] + ex[1];
            const float fg = accA[i][2][r] + accB[i][2][r] * LO_INV + bi[2] + ex[2];
            const float og = accA[i][3][r] + accB[i][3][r] * LO_INV + bi[3] + ex[3];
            const size_t cidx = (size_t)row * NH + jj;
            const float cx = c[cidx];
            const float cy = cx * sigm(fg + 1.0f) + sigm(ig) * tanhf(gg);
            const float hy = sigm(og) * tanhf(cy);
            c[cidx] = cy;
            const f16 a = (f16)hy;
            h_hi[cidx] = a;
            h_lo[cidx] = (f16)((hy - (float)a) * LO_SCALE);
        }
    }
}

// ---------------- loop-2 fused gate GEMM + LSTM + rowdot (2-pass) ----------------
__global__ __launch_bounds__(256, 2)
void mfma_gate_lstm2(const f16* __restrict__ Ahi, const f16* __restrict__ Alo,
                     const f16* __restrict__ Bhi,
                     const float* __restrict__ blp,
                     const float* __restrict__ extra, const int* __restrict__ eidx,
                     float* __restrict__ c,
                     f16* __restrict__ h_hi, f16* __restrict__ h_lo,
                     const float* __restrict__ Woutl,
                     float* __restrict__ out1, int t)
{
    __shared__ f16 sT[2][3][128 * 32];
    int bx = blockIdx.x, by = blockIdx.y;
    swz_xcd(bx, by);
    const int bm = by << 7;
    const int bn = bx << 7;
    const int tid = threadIdx.x;
    const int wid = tid >> 6, lane = tid & 63;
    const int wr = ((wid >> 1) & 1) << 6;
    const int wc = (wid & 1) << 6;

    f32x4 accA[4][4], accB[4][4];
#pragma unroll
    for (int i = 0; i < 4; ++i)
#pragma unroll
        for (int j = 0; j < 4; ++j) { accA[i][j] = (f32x4)(0.0f); accB[i][j] = (f32x4)(0.0f); }

    gemm_core2(Ahi, Alo, Bhi, sT, bm, bn, NH, wid, lane, wr, wc, accA, accB);

    const int m = lane & 15;
    const int rg = lane >> 4;
    const int colb = bn + wc;
    const int jj = ((colb >> 6) << 4) + m;    // LSTM unit index (original)
    const float wout = Woutl[jj];
    float bi[4];
#pragma unroll
    for (int g = 0; g < 4; ++g) bi[g] = blp[colb + g * 16 + m];

#pragma unroll
    for (int i = 0; i < 4; ++i) {
#pragma unroll
        for (int r = 0; r < 4; ++r) {
            const int row = bm + wr + i * 16 + rg * 4 + r;
            const float* exr = extra + (size_t)eidx[row] * NG;
            float ex[4];
#pragma unroll
            for (int g = 0; g < 4; ++g) ex[g] = exr[colb + g * 16 + m];
            const float ig = accA[i][0][r] + accB[i][0][r] * LO_INV + bi[0] + ex[0];
            const float gg = accA[i][1][r] + accB[i][1][r] * LO_INV + bi[1] + ex[1];
            const float fg = accA[i][2][r] + accB[i][2][r] * LO_INV + bi[2] + ex[2];
            const float og = accA[i][3][r] + accB[i][3][r] * LO_INV + bi[3] + ex[3];
            const size_t cidx = (size_t)row * NH + jj;
            const float cx = c[cidx];
            const float cy = cx * sigm(fg + 1.0f) + sigm(ig) * tanhf(gg);
            const float hy = sigm(og) * tanhf(cy);
            c[cidx] = cy;
            const f16 a = (f16)hy;
            h_hi[cidx] = a;
            h_lo[cidx] = (f16)((hy - (float)a) * LO_SCALE);
            // fused rowdot partial: reduce 16 units (m-group) then one atomic
            float part = hy * wout;
#pragma unroll
            for (int msk = 1; msk < 16; msk <<= 1) part += __shfl_xor(part, msk);
            if (m == 0) atomicAdd(&out1[(size_t)row * NRW + t], part);
        }
    }
}

// ---------------- out1 init to b_outl ----------------
__global__ __launch_bounds__(256)
void out1_init(float* __restrict__ out1, const float* __restrict__ boutl)
{
    const size_t i = (size_t)blockIdx.x * 256 + threadIdx.x;
    out1[i] = boutl[0];
}

// ---------------- f32 vector GEMM (K=128 prep/init only) ----------------
template<int ACT, int PERM>
__global__ __launch_bounds__(256)
void gemm128(const float* __restrict__ A, int lda,
             const float* __restrict__ W, int ldw,
             const float* __restrict__ bias,
             float* __restrict__ C, int ldc, int K)
{
    __shared__ float As[16][128];
    __shared__ float Bs[16][128];
    const int bm = blockIdx.y << 7, bn = blockIdx.x << 7;
    const int tid = threadIdx.x;
    const int tx = tid & 15, ty = tid >> 4;
    const int sar = tid >> 1, sac = (tid & 1) << 3;
    const int sbk = tid >> 4, sbc = (tid & 15) << 3;
    float acc[2][2][4][4] = {};
    const float* Ap = A + (size_t)(bm + sar) * lda + sac;
    const float* Wp = W + (size_t)sbk * ldw + bn + sbc;
    for (int kb = 0; kb < K; kb += 16) {
        const float4 av0 = *(const float4*)(Ap + kb);
        const float4 av1 = *(const float4*)(Ap + kb + 4);
        const float4 bv0 = *(const float4*)(Wp + (size_t)kb * ldw);
        const float4 bv1 = *(const float4*)(Wp + (size_t)kb * ldw + 4);
        __syncthreads();
        As[sac + 0][sar] = av0.x; As[sac + 1][sar] = av0.y;
        As[sac + 2][sar] = av0.z; As[sac + 3][sar] = av0.w;
        As[sac + 4][sar] = av1.x; As[sac + 5][sar] = av1.y;
        As[sac + 6][sar] = av1.z; As[sac + 7][sar] = av1.w;
        *(float4*)&Bs[sbk][sbc] = bv0;
        *(float4*)&Bs[sbk][sbc + 4] = bv1;
        __syncthreads();
#pragma unroll
        for (int kk = 0; kk < 16; ++kk) {
            float a[2][4], b[2][4];
            *(float4*)a[0] = *(const float4*)&As[kk][ty << 2];
            *(float4*)a[1] = *(const float4*)&As[kk][64 + (ty << 2)];
            *(float4*)b[0] = *(const float4*)&Bs[kk][tx << 2];
            *(float4*)b[1] = *(const float4*)&Bs[kk][64 + (tx << 2)];
#pragma unroll
            for (int rh = 0; rh < 2; ++rh)
#pragma unroll
                for (int ch = 0; ch < 2; ++ch)
#pragma unroll
                    for (int i = 0; i < 4; ++i)
#pragma unroll
                        for (int j = 0; j < 4; ++j)
                            acc[rh][ch][i][j] = fmaf(a[rh][i], b[ch][j], acc[rh][ch][i][j]);
        }
    }
    float4 bi4[2] = {make_float4(0.f, 0.f, 0.f, 0.f), make_float4(0.f, 0.f, 0.f, 0.f)};
    if (bias) {
        bi4[0] = *(const float4*)(bias + bn + (tx << 2));
        bi4[1] = *(const float4*)(bias + bn + 64 + (tx << 2));
    }
#pragma unroll
    for (int rh = 0; rh < 2; ++rh)
#pragma unroll
        for (int i = 0; i < 4; ++i) {
            const int row = bm + rh * 64 + (ty << 2) + i;
#pragma unroll
            for (int ch = 0; ch < 2; ++ch) {
                const int col = bn + ch * 64 + (tx << 2);
                float v0 = acc[rh][ch][i][0] + bi4[ch].x;
                float v1 = acc[rh][ch][i][1] + bi4[ch].y;
                float v2 = acc[rh][ch][i][2] + bi4[ch].z;
                float v3 = acc[rh][ch][i][3] + bi4[ch].w;
                if (ACT == 1) { v0 = tanhf(v0); v1 = tanhf(v1); v2 = tanhf(v2); v3 = tanhf(v3); }
                const int wcol = PERM ? cperm(col) : col;
                *(float4*)(C + (size_t)row * ldc + wcol) = make_float4(v0, v1, v2, v3);
            }
        }
}

// ---------------- transpose + split (optional gate-interleave on cols) ----------------
template<int PERM>
__global__ __launch_bounds__(256)
void tsplit(const float* __restrict__ in, int ldin, int K,
            f16* __restrict__ ohi, f16* __restrict__ olo)
{
    __shared__ float t[32][33];
    const int kb = blockIdx.x << 5, nb = blockIdx.y << 5;
    const int cx = threadIdx.x & 31, ry = threadIdx.x >> 5;
    const int col = PERM ? oc_of(nb + cx) : (nb + cx);
#pragma unroll
    for (int q = 0; q < 4; ++q)
        t[ry + q * 8][cx] = in[(size_t)(kb + ry + q * 8) * ldin + col];
    __syncthreads();
#pragma unroll
    for (int q = 0; q < 4; ++q) {
        const int n = ry + q * 8;
        const float v = t[cx][n];
        const f16 hi = (f16)v;
        ohi[(size_t)(nb + n) * K + kb + cx] = hi;
        olo[(size_t)(nb + n) * K + kb + cx] = (f16)((v - (float)hi) * LO_SCALE);
    }
}

// ---------------- bias permute ----------------
__global__ __launch_bounds__(256)
void permb(const float* __restrict__ b, float* __restrict__ bp)
{
    const int c = blockIdx.x * 256 + threadIdx.x;
    bp[c] = b[oc_of(c)];
}

// ---------------- split f32 -> hi/lo f16 ----------------
__global__ __launch_bounds__(256)
void split_h(const float* __restrict__ h, f16* __restrict__ hi, f16* __restrict__ lo)
{
    const size_t i = (size_t)blockIdx.x * 256 + threadIdx.x;
    const float v = h[i];
    const f16 a = (f16)v;
    hi[i] = a;
    lo[i] = (f16)((v - (float)a) * LO_SCALE);
}

// ---------------- argmax + one-hot ----------------
__global__ __launch_bounds__(256)
void argmax_onehot(const float* __restrict__ logits, const float* __restrict__ gu,
                   float* __restrict__ out0, int* __restrict__ kidx, int t)
{
    const int b = blockIdx.x;
    const int tid = threadIdx.x;
    const float* lrow = logits + (size_t)b * NN;
    const float* urow = gu + ((size_t)t * NB + b) * NN;
    float best = -INFINITY;
    int bi = 0x7fffffff;
#pragma unroll
    for (int q = 0; q < 2; ++q) {
        const int j = tid + q * 256;
        const float u = urow[j];
        const float g = -logf(-logf(u + 1e-20f) + 1e-20f);
        const float v = lrow[j] + g;
        if (v > best || (v == best && j < bi)) { best = v; bi = j; }
    }
#pragma unroll
    for (int off = 32; off > 0; off >>= 1) {
        const float ov = __shfl_down(best, off);
        const int oi = __shfl_down(bi, off);
        if (ov > best || (ov == best && oi < bi)) { best = ov; bi = oi; }
    }
    __shared__ float sv[4];
    __shared__ int si[4];
    const int lane = tid & 63, w = tid >> 6;
    if (lane == 0) { sv[w] = best; si[w] = bi; }
    __syncthreads();
    if (tid == 0) {
        for (int q = 1; q < 4; ++q)
            if (sv[q] > best || (sv[q] == best && si[q] < bi)) { best = sv[q]; bi = si[q]; }
        si[0] = bi;
        kidx[(size_t)t * NB + b] = bi;
    }
    __syncthreads();
    const int win = si[0];
    float* orow = out0 + ((size_t)b * NRW + t) * NN;
#pragma unroll
    for (int q = 0; q < 2; ++q) {
        const int j = tid + q * 256;
        orow[j] = (j == win) ? 1.0f : 0.0f;
    }
}

extern "C" void kernel_launch(void* const* d_in, const int* in_sizes, int n_in,
                              void* d_out, int out_size, void* d_ws, size_t ws_size,
                              hipStream_t stream)
{
    const float* latent  = (const float*)d_in[0];
    const float* gu      = (const float*)d_in[2];
    const float* W_int   = (const float*)d_in[3];
    const float* b_int   = (const float*)d_in[4];
    const float* W_intl  = (const float*)d_in[5];
    const float* b_intl  = (const float*)d_in[6];
    const float* W_hup   = (const float*)d_in[7];
    const float* b_hup   = (const float*)d_in[8];
    const float* W_cup   = (const float*)d_in[9];
    const float* b_cup   = (const float*)d_in[10];
    const float* W_hupl  = (const float*)d_in[11];
    const float* b_hupl  = (const float*)d_in[12];
    const float* W_cupl  = (const float*)d_in[13];
    const float* b_cupl  = (const float*)d_in[14];
    const float* W_lstm  = (const float*)d_in[15];
    const float* b_lstm  = (const float*)d_in[16];
    const float* W_up    = (const float*)d_in[17];
    const float* b_up    = (const float*)d_in[18];
    const float* W_down  = (const float*)d_in[19];
    const float* W_downl = (const float*)d_in[20];
    const float* W_outl  = (const float*)d_in[21];
    const float* b_outl  = (const float*)d_in[22];

    float* out0 = (float*)d_out;                 // [B, RW, N]
    float* out1 = out0 + (size_t)NB * NRW * NN;  // [B, RW, 1]

    // workspace
    float* ws     = (float*)d_ws;
    float* c      = ws;                               // NB*NH
    float* logits = c + (size_t)NB * NH;              // NB*NH (also inter)
    float* htmp   = logits + (size_t)NB * NH;         // NB*NH f32 (init only)
    float* gdown  = htmp + (size_t)NB * NH;           // NN*NG (permuted cols)
    float* gdownl = gdown + (size_t)NN * NG;          // NN*NG (permuted cols)
    float* blp    = gdownl + (size_t)NN * NG;         // NG (permuted b_lstm)
    f16* fp = (f16*)(blp + NG);
    f16* h_hi[2]; f16* h_lo[2];
    h_hi[0] = fp;                    fp += (size_t)NB * NH;
    h_lo[0] = fp;                    fp += (size_t)NB * NH;
    h_hi[1] = fp;                    fp += (size_t)NB * NH;
    h_lo[1] = fp;                    fp += (size_t)NB * NH;
    f16* i_hi   = fp;                fp += (size_t)NB * NH;
    f16* i_lo   = fp;                fp += (size_t)NB * NH;
    f16* WlT_hi = fp;                fp += (size_t)NG * NH;   // permuted rows
    f16* WlT_lo = fp;                fp += (size_t)NG * NH;
    f16* WupT_hi = fp;               fp += (size_t)NN * NH;
    f16* WupT_lo = fp;               fp += (size_t)NN * NH;
    f16* WhT_hi = fp;                fp += (size_t)NH * NH;
    f16* WhT_lo = fp;                fp += (size_t)NH * NH;
    f16* WcT_hi = fp;                fp += (size_t)NH * NH;
    f16* WcT_lo = fp;                fp += (size_t)NH * NH;
    f16* WhlT_hi = fp;               fp += (size_t)NH * NH;
    f16* WhlT_lo = fp;               fp += (size_t)NH * NH;
    f16* WclT_hi = fp;               fp += (size_t)NH * NH;
    f16* WclT_lo = fp;               fp += (size_t)NH * NH;
    int* kidx = (int*)fp;

    const dim3 blk(256);
    const dim3 g_gates(NG / 128, NB / 128);   // 16 x 64
    const dim3 g_h(NH / 128, NB / 128);       // 4 x 64
    const dim3 g_pre(NG / 128, NN / 128);     // 16 x 4
    const dim3 g_sph(NB * NH / 256);

    // ---- prep ----
    tsplit<1><<<dim3(NH / 32, NG / 32), blk, 0, stream>>>(W_lstm + (size_t)NIN * NG, NG, NH, WlT_hi, WlT_lo);
    tsplit<0><<<dim3(NH / 32, NN / 32), blk, 0, stream>>>(W_up, NH, NH, WupT_hi, WupT_lo);
    tsplit<0><<<dim3(NH / 32, NH / 32), blk, 0, stream>>>(W_hup, NH, NH, WhT_hi, WhT_lo);
    tsplit<0><<<dim3(NH / 32, NH / 32), blk, 0, stream>>>(W_cup, NH, NH, WcT_hi, WcT_lo);
    tsplit<0><<<dim3(NH / 32, NH / 32), blk, 0, stream>>>(W_hupl, NH, NH, WhlT_hi, WhlT_lo);
    tsplit<0><<<dim3(NH / 32, NH / 32), blk, 0, stream>>>(W_cupl, NH, NH, WclT_hi, WclT_lo);
    permb<<<dim3(NG / 256), blk, 0, stream>>>(b_lstm, blp);
    gemm128<0, 1><<<g_pre, blk, 0, stream>>>(W_down, NIN, W_lstm, NG, nullptr, gdown, NG, NIN);
    gemm128<0, 1><<<g_pre, blk, 0, stream>>>(W_downl, NIN, W_lstm, NG, nullptr, gdownl, NG, NIN);

    // ---- loop 1 init ----
    gemm128<1, 0><<<g_h, blk, 0, stream>>>(latent, NZ, W_int, NH, b_int, logits, NH, NZ);
    split_h<<<g_sph, blk, 0, stream>>>(logits, i_hi, i_lo);
    mfma_gemm<0, 1><<<g_h, blk, 0, stream>>>(i_hi, i_lo, WhT_hi, WhT_lo, b_hup,
                                             nullptr, nullptr, htmp, NH, NH);
    split_h<<<g_sph, blk, 0, stream>>>(htmp, h_hi[0], h_lo[0]);
    mfma_gemm<0, 1><<<g_h, blk, 0, stream>>>(i_hi, i_lo, WcT_hi, WcT_lo, b_cup,
                                             nullptr, nullptr, c, NH, NH);

    int cur = 0;
    for (int t = 0; t < NRW; ++t) {
        const int nxt = cur ^ 1;
        if (t == 0)
            mfma_gate_lstm<0><<<g_gates, blk, 0, stream>>>(h_hi[cur], h_lo[cur], WlT_hi, WlT_lo,
                                                           blp, nullptr, nullptr,
                                                           c, h_hi[nxt], h_lo[nxt]);
        else
            mfma_gate_lstm<1><<<g_gates, blk, 0, stream>>>(h_hi[cur], h_lo[cur], WlT_hi, WlT_lo,
                                                           blp, gdown, kidx + (size_t)(t - 1) * NB,
                                                           c, h_hi[nxt], h_lo[nxt]);
        mfma_gemm<0, 0><<<g_h, blk, 0, stream>>>(h_hi[nxt], h_lo[nxt], WupT_hi, WupT_lo, b_up,
                                                 nullptr, nullptr, logits, NN, NH);
        argmax_onehot<<<dim3(NB), blk, 0, stream>>>(logits, gu, out0, kidx, t);
        cur = nxt;
    }

    // ---- loop 2 init ----
    gemm128<1, 0><<<g_h, blk, 0, stream>>>(latent, NZ, W_intl, NH, b_intl, logits, NH, NZ);
    split_h<<<g_sph, blk, 0, stream>>>(logits, i_hi, i_lo);
    mfma_gemm<0, 1><<<g_h, blk, 0, stream>>>(i_hi, i_lo, WhlT_hi, WhlT_lo, b_hupl,
                                             nullptr, nullptr, htmp, NH, NH);
    split_h<<<g_sph, blk, 0, stream>>>(htmp, h_hi[0], h_lo[0]);
    mfma_gemm<0, 1><<<g_h, blk, 0, stream>>>(i_hi, i_lo, WclT_hi, WclT_lo, b_cupl,
                                             nullptr, nullptr, c, NH, NH);
    out1_init<<<dim3(NB * NRW / 256), blk, 0, stream>>>(out1, b_outl);

    cur = 0;
    for (int t = 0; t < NRW; ++t) {
        const int nxt = cur ^ 1;
        mfma_gate_lstm2<<<g_gates, blk, 0, stream>>>(h_hi[cur], h_lo[cur], WlT_hi,
                                                     blp, gdownl, kidx + (size_t)t * NB,
                                                     c, h_hi[nxt], h_lo[nxt],
                                                     W_outl, out1, t);
        cur = nxt;
    }
}

// Round 9
// 3088.024 us; speedup vs baseline: 3.9099x; 1.0012x over previous
//
#include <hip/hip_runtime.h>

#define NB 8192
#define NH 512
#define NZ 128
#define NIN 128
#define NN 512
#define NRW 16
#define NG 2048   // 4*NH

typedef _Float16 f16;
typedef _Float16 f16x8 __attribute__((ext_vector_type(8)));
typedef float f32x4 __attribute__((ext_vector_type(4)));

#define LO_SCALE 2048.0f
#define LO_INV   (1.0f / 2048.0f)

__device__ __forceinline__ float sigm(float x) { return 1.0f / (1.0f + expf(-x)); }

// gate-interleaved column permutation: stored col c <- original col oc(c)
__device__ __forceinline__ int oc_of(int c)
{
    return (((c >> 4) & 3) << 9) + ((c >> 6) << 4) + (c & 15);
}
__device__ __forceinline__ int cperm(int j)
{
    return (j & 15) | (((j >> 4) & 31) << 6) | (((j >> 9) & 3) << 4);
}

// Bijective XCD-aware block swizzle (requires nwg % 8 == 0; all our grids comply).
__device__ __forceinline__ void swz_xcd(int& bx, int& by)
{
    const int gx = gridDim.x;
    const int nwg = gx * gridDim.y;
    int lin = by * gx + bx;
    lin = (lin & 7) * (nwg >> 3) + (lin >> 3);
    const int sh = 31 - __clz(gx);     // gx is a power of two (4 or 16)
    bx = lin & (gx - 1);
    by = lin >> sh;
}

// ---------------- async 16B global->LDS ----------------
__device__ __forceinline__ void gload16(const f16* g, f16* l)
{
    __builtin_amdgcn_global_load_lds(
        (const __attribute__((address_space(1))) void*)g,
        (__attribute__((address_space(3))) void*)l, 16, 0, 0);
}

// 16B-slot swizzle: 2-way (free) bank aliasing for 16-row b128 column reads.
__device__ __forceinline__ int swz4(int row) { return (row & 3) ^ ((row >> 2) & 3); }

// Stage one 128x32 f16 tile (8KB): linear LDS dest + inverse-swizzled global src.
__device__ __forceinline__ void stage_tile(f16* tilebase, const f16* src,
                                           int rowbase, int K, int kb,
                                           int wid, int lane)
{
#pragma unroll
    for (int q = 0; q < 2; ++q) {
        const int iw = wid * 2 + q;
        const int chunk = (iw << 6) | lane;
        const int row = chunk >> 2;
        const int p = (chunk & 3) ^ swz4(row);
        const f16* g = src + (size_t)(rowbase + row) * K + kb + (p << 3);
        gload16(g, tilebase + (iw << 9));
    }
}

__device__ __forceinline__ f16x8 frag(const f16* tile, int row, int sl)
{
    return *(const f16x8*)(tile + row * 32 + ((sl ^ swz4(row)) << 3));
}

// ---------------- 3-pass counted-vmcnt split-GEMM core (argmax-critical path) ----------------
__device__ __forceinline__ void gemm_core(const f16* Ahi, const f16* Alo,
                                          const f16* Bhi, const f16* Blo,
                                          f16 (*sT)[4][128 * 32],
                                          int bm, int bn, int K,
                                          int wid, int lane, int wr, int wc,
                                          f32x4 (&accA)[4][4], f32x4 (&accB)[4][4])
{
    const int NT = K >> 5;
    stage_tile(sT[0][0], Ahi, bm, K, 0, wid, lane);
    stage_tile(sT[0][1], Alo, bm, K, 0, wid, lane);
    __builtin_amdgcn_sched_barrier(0);
    stage_tile(sT[0][2], Bhi, bn, K, 0, wid, lane);
    __builtin_amdgcn_sched_barrier(0);
    stage_tile(sT[0][3], Blo, bn, K, 0, wid, lane);

    const int r16 = lane & 15, sl = lane >> 4;

    for (int kt = 0; kt < NT; ++kt) {
        const int cur = kt & 1;
        const int nxt = cur ^ 1;
        const bool more = (kt + 1 < NT);
        const int kb = (kt + 1) << 5;

        // ---- phase 1: accA += ah*bh ----
        asm volatile("s_waitcnt vmcnt(2)" ::: "memory");
        __builtin_amdgcn_s_barrier();
        __builtin_amdgcn_sched_barrier(0);
        if (more) {
            stage_tile(sT[nxt][0], Ahi, bm, K, kb, wid, lane);
            stage_tile(sT[nxt][1], Alo, bm, K, kb, wid, lane);
        }
        f16x8 ah[4], bh[4];
#pragma unroll
        for (int f = 0; f < 4; ++f) {
            ah[f] = frag(sT[cur][0], wr + f * 16 + r16, sl);
            bh[f] = frag(sT[cur][2], wc + f * 16 + r16, sl);
        }
        __builtin_amdgcn_s_setprio(1);
#pragma unroll
        for (int i = 0; i < 4; ++i)
#pragma unroll
            for (int j = 0; j < 4; ++j)
                accA[i][j] = __builtin_amdgcn_mfma_f32_16x16x32_f16(ah[i], bh[j], accA[i][j], 0, 0, 0);
        __builtin_amdgcn_s_setprio(0);

        // ---- phase 2: accB += al*bh ----
        __builtin_amdgcn_s_barrier();
        __builtin_amdgcn_sched_barrier(0);
        if (more) stage_tile(sT[nxt][2], Bhi, bn, K, kb, wid, lane);
        f16x8 al[4];
#pragma unroll
        for (int f = 0; f < 4; ++f) al[f] = frag(sT[cur][1], wr + f * 16 + r16, sl);
        __builtin_amdgcn_s_setprio(1);
#pragma unroll
        for (int i = 0; i < 4; ++i)
#pragma unroll
            for (int j = 0; j < 4; ++j)
                accB[i][j] = __builtin_amdgcn_mfma_f32_16x16x32_f16(al[i], bh[j], accB[i][j], 0, 0, 0);
        __builtin_amdgcn_s_setprio(0);

        // ---- phase 3: accB += ah*bl ----
        if (more) asm volatile("s_waitcnt vmcnt(6)" ::: "memory");
        else      asm volatile("s_waitcnt vmcnt(0)" ::: "memory");
        __builtin_amdgcn_s_barrier();
        __builtin_amdgcn_sched_barrier(0);
        if (more) stage_tile(sT[nxt][3], Blo, bn, K, kb, wid, lane);
        f16x8 bl[4];
#pragma unroll
        for (int f = 0; f < 4; ++f) bl[f] = frag(sT[cur][3], wc + f * 16 + r16, sl);
        __builtin_amdgcn_s_setprio(1);
#pragma unroll
        for (int i = 0; i < 4; ++i)
#pragma unroll
            for (int j = 0; j < 4; ++j)
                accB[i][j] = __builtin_amdgcn_mfma_f32_16x16x32_f16(ah[i], bl[j], accB[i][j], 0, 0, 0);
        __builtin_amdgcn_s_setprio(0);
    }
}

// ---------------- 1-pass f16 core (loop-2: f16 A, f16 B) ----------------
__device__ __forceinline__ void gemm_core1(const f16* Ahi, const f16* Bhi,
                                           f16 (*sT)[2][128 * 32],
                                           int bm, int bn, int K,
                                           int wid, int lane, int wr, int wc,
                                           f32x4 (&acc)[4][4])
{
    const int NT = K >> 5;
    stage_tile(sT[0][0], Ahi, bm, K, 0, wid, lane);
    stage_tile(sT[0][1], Bhi, bn, K, 0, wid, lane);

    const int r16 = lane & 15, sl = lane >> 4;

    for (int kt = 0; kt < NT; ++kt) {
        const int cur = kt & 1;
        const int nxt = cur ^ 1;
        __syncthreads();
        if (kt + 1 < NT) {
            const int kb = (kt + 1) << 5;
            stage_tile(sT[nxt][0], Ahi, bm, K, kb, wid, lane);
            stage_tile(sT[nxt][1], Bhi, bn, K, kb, wid, lane);
        }
        f16x8 ah[4], bh[4];
#pragma unroll
        for (int f = 0; f < 4; ++f) {
            ah[f] = frag(sT[cur][0], wr + f * 16 + r16, sl);
            bh[f] = frag(sT[cur][1], wc + f * 16 + r16, sl);
        }
        __builtin_amdgcn_s_setprio(1);
#pragma unroll
        for (int i = 0; i < 4; ++i)
#pragma unroll
            for (int j = 0; j < 4; ++j)
                acc[i][j] = __builtin_amdgcn_mfma_f32_16x16x32_f16(ah[i], bh[j], acc[i][j], 0, 0, 0);
        __builtin_amdgcn_s_setprio(0);
    }
}

// ---------------- plain split GEMM (inits). OUT: 0=f32, 1=tanh f32, 2=tanh split, 3=tanh f16 ----------------
template<int OUT>
__global__ __launch_bounds__(256, 2)
void mfma_gemm(const f16* __restrict__ Ahi, const f16* __restrict__ Alo,
               const f16* __restrict__ Bhi, const f16* __restrict__ Blo,
               const float* __restrict__ bias,
               float* __restrict__ C, f16* __restrict__ Ohi, f16* __restrict__ Olo,
               int N, int K)
{
    __shared__ f16 sT[2][4][128 * 32];
    int bx = blockIdx.x, by = blockIdx.y;
    swz_xcd(bx, by);
    const int bm = by << 7;
    const int bn = bx << 7;
    const int tid = threadIdx.x;
    const int wid = tid >> 6, lane = tid & 63;
    const int wr = ((wid >> 1) & 1) << 6;
    const int wc = (wid & 1) << 6;

    f32x4 accA[4][4], accB[4][4];
#pragma unroll
    for (int i = 0; i < 4; ++i)
#pragma unroll
        for (int j = 0; j < 4; ++j) { accA[i][j] = (f32x4)(0.0f); accB[i][j] = (f32x4)(0.0f); }

    gemm_core(Ahi, Alo, Bhi, Blo, sT, bm, bn, K, wid, lane, wr, wc, accA, accB);

    const int r16 = lane & 15;
    const int rg = lane >> 4;
#pragma unroll
    for (int i = 0; i < 4; ++i) {
#pragma unroll
        for (int r = 0; r < 4; ++r) {
            const int row = bm + wr + i * 16 + rg * 4 + r;
#pragma unroll
            for (int j = 0; j < 4; ++j) {
                const int col = bn + wc + j * 16 + r16;
                float v = accA[i][j][r] + accB[i][j][r] * LO_INV;
                if (bias) v += bias[col];
                if (OUT >= 1) v = tanhf(v);
                const size_t idx = (size_t)row * N + col;
                if (OUT <= 1) C[idx] = v;
                else {
                    const f16 a = (f16)v;
                    Ohi[idx] = a;
                    if (OUT == 2) Olo[idx] = (f16)((v - (float)a) * LO_SCALE);
                }
            }
        }
    }
}

// ---------------- loop-1 logits GEMM + fused gumbel-argmax partials ----------------
__global__ __launch_bounds__(256, 2)
void mfma_logits_argmax(const f16* __restrict__ Ahi, const f16* __restrict__ Alo,
                        const f16* __restrict__ Bhi, const f16* __restrict__ Blo,
                        const float* __restrict__ bias,
                        const float* __restrict__ gu,
                        float2* __restrict__ part, int t)
{
    __shared__ f16 sT[2][4][128 * 32];
    int bx = blockIdx.x, by = blockIdx.y;
    swz_xcd(bx, by);
    const int bm = by << 7;
    const int bn = bx << 7;
    const int tid = threadIdx.x;
    const int wid = tid >> 6, lane = tid & 63;
    const int wr = ((wid >> 1) & 1) << 6;
    const int wc = (wid & 1) << 6;

    f32x4 accA[4][4], accB[4][4];
#pragma unroll
    for (int i = 0; i < 4; ++i)
#pragma unroll
        for (int j = 0; j < 4; ++j) { accA[i][j] = (f32x4)(0.0f); accB[i][j] = (f32x4)(0.0f); }

    gemm_core(Ahi, Alo, Bhi, Blo, sT, bm, bn, NN, wid, lane, wr, wc, accA, accB);

    const int r16 = lane & 15;
    const int rg = lane >> 4;
    const int cb = bx * 2 + (wc >> 6);       // 64-col slice index 0..7
    float bi[4];
#pragma unroll
    for (int j = 0; j < 4; ++j) bi[j] = bias[bn + wc + j * 16 + r16];

#pragma unroll
    for (int i = 0; i < 4; ++i) {
#pragma unroll
        for (int r = 0; r < 4; ++r) {
            const int row = bm + wr + i * 16 + rg * 4 + r;
            const float* urow = gu + ((size_t)t * NB + row) * NN;
            float best = -INFINITY;
            int bidx = 0x7fffffff;
#pragma unroll
            for (int j = 0; j < 4; ++j) {
                const int col = bn + wc + j * 16 + r16;
                const float u = urow[col];
                const float g = -logf(-logf(u + 1e-20f) + 1e-20f);
                const float v = accA[i][j][r] + accB[i][j][r] * LO_INV + bi[j] + g;
                if (v > best || (v == best && col < bidx)) { best = v; bidx = col; }
            }
            // reduce over the 16-lane r16 group (same row)
#pragma unroll
            for (int msk = 1; msk < 16; msk <<= 1) {
                const float ov = __shfl_xor(best, msk);
                const int oi = __shfl_xor(bidx, msk);
                if (ov > best || (ov == best && oi < bidx)) { best = ov; bidx = oi; }
            }
            if (r16 == 0) part[(size_t)row * 8 + cb] = make_float2(best, (float)bidx);
        }
    }
}

// ---------------- finalize: pick over 8 slices, write one-hot + kidx (1 wave per row) ----------------
__global__ __launch_bounds__(256)
void finalize_argmax(const float2* __restrict__ part,
                     float* __restrict__ out0, int* __restrict__ kidx, int t)
{
    const int w = threadIdx.x >> 6;
    const int lane = threadIdx.x & 63;
    const int row = blockIdx.x * 4 + w;
    float best = -INFINITY;
    int bi = 0x7fffffff;
    if (lane < 8) {
        const float2 p = part[(size_t)row * 8 + lane];
        best = p.x;
        bi = (int)p.y;
    }
#pragma unroll
    for (int msk = 1; msk < 8; msk <<= 1) {
        const float ov = __shfl_xor(best, msk);
        const int oi = __shfl_xor(bi, msk);
        if (ov > best || (ov == best && oi < bi)) { best = ov; bi = oi; }
    }
    const int win = __shfl(bi, 0);
    if (lane == 0) kidx[(size_t)t * NB + row] = win;
    float* orow = out0 + ((size_t)row * NRW + t) * NN;
    const int c0 = lane * 8;
    float4 v0 = make_float4(c0 == win, c0 + 1 == win, c0 + 2 == win, c0 + 3 == win);
    float4 v1 = make_float4(c0 + 4 == win, c0 + 5 == win, c0 + 6 == win, c0 + 7 == win);
    *(float4*)(orow + c0) = v0;
    *(float4*)(orow + c0 + 4) = v1;
}

// ---------------- loop-1 fused gate GEMM + LSTM pointwise (3-pass) ----------------
template<int HAS_EXTRA>
__global__ __launch_bounds__(256, 2)
void mfma_gate_lstm(const f16* __restrict__ Ahi, const f16* __restrict__ Alo,
                    const f16* __restrict__ Bhi, const f16* __restrict__ Blo,
                    const float* __restrict__ blp,
                    const float* __restrict__ extra, const int* __restrict__ eidx,
                    float* __restrict__ c,
                    f16* __restrict__ h_hi, f16* __restrict__ h_lo)
{
    __shared__ f16 sT[2][4][128 * 32];
    int bx = blockIdx.x, by = blockIdx.y;
    swz_xcd(bx, by);
    const int bm = by << 7;
    const int bn = bx << 7;
    const int tid = threadIdx.x;
    const int wid = tid >> 6, lane = tid & 63;
    const int wr = ((wid >> 1) & 1) << 6;
    const int wc = (wid & 1) << 6;

    f32x4 accA[4][4], accB[4][4];
#pragma unroll
    for (int i = 0; i < 4; ++i)
#pragma unroll
        for (int j = 0; j < 4; ++j) { accA[i][j] = (f32x4)(0.0f); accB[i][j] = (f32x4)(0.0f); }

    gemm_core(Ahi, Alo, Bhi, Blo, sT, bm, bn, NH, wid, lane, wr, wc, accA, accB);

    const int m = lane & 15;
    const int rg = lane >> 4;
    const int colb = bn + wc;                 // multiple of 64
    const int jj = ((colb >> 6) << 4) + m;    // LSTM unit index
    float bi[4];
#pragma unroll
    for (int g = 0; g < 4; ++g) bi[g] = blp[colb + g * 16 + m];

#pragma unroll
    for (int i = 0; i < 4; ++i) {
#pragma unroll
        for (int r = 0; r < 4; ++r) {
            const int row = bm + wr + i * 16 + rg * 4 + r;
            float ex[4] = {0.f, 0.f, 0.f, 0.f};
            if (HAS_EXTRA) {
                const float* exr = extra + (size_t)eidx[row] * NG;
#pragma unroll
                for (int g = 0; g < 4; ++g) ex[g] = exr[colb + g * 16 + m];
            }
            const float ig = accA[i][0][r] + accB[i][0][r] * LO_INV + bi[0] + ex[0];
            const float gg = accA[i][1][r] + accB[i][1][r] * LO_INV + bi[1] + ex[1];
            const float fg = accA[i][2][r] + accB[i][2][r] * LO_INV + bi[2] + ex[2];
            const float og = accA[i][3][r] + accB[i][3][r] * LO_INV + bi[3] + ex[3];
            const size_t cidx = (size_t)row * NH + jj;
            const float cx = c[cidx];
            const float cy = cx * sigm(fg + 1.0f) + sigm(ig) * tanhf(gg);
            const float hy = sigm(og) * tanhf(cy);
            c[cidx] = cy;
            const f16 a = (f16)hy;
            h_hi[cidx] = a;
            h_lo[cidx] = (f16)((hy - (float)a) * LO_SCALE);
        }
    }
}

// ---------------- loop-2 fused gate GEMM + LSTM + rowdot (1-pass f16) ----------------
__global__ __launch_bounds__(256, 2)
void mfma_gate_lstm2(const f16* __restrict__ Ahi, const f16* __restrict__ Bhi,
                     const float* __restrict__ blp,
                     const float* __restrict__ extra, const int* __restrict__ eidx,
                     float* __restrict__ c,
                     f16* __restrict__ h_hi,
                     const float* __restrict__ Woutl,
                     float* __restrict__ out1, int t)
{
    __shared__ f16 sT[2][2][128 * 32];
    int bx = blockIdx.x, by = blockIdx.y;
    swz_xcd(bx, by);
    const int bm = by << 7;
    const int bn = bx << 7;
    const int tid = threadIdx.x;
    const int wid = tid >> 6, lane = tid & 63;
    const int wr = ((wid >> 1) & 1) << 6;
    const int wc = (wid & 1) << 6;

    f32x4 acc[4][4];
#pragma unroll
    for (int i = 0; i < 4; ++i)
#pragma unroll
        for (int j = 0; j < 4; ++j) acc[i][j] = (f32x4)(0.0f);

    gemm_core1(Ahi, Bhi, sT, bm, bn, NH, wid, lane, wr, wc, acc);

    const int m = lane & 15;
    const int rg = lane >> 4;
    const int colb = bn + wc;
    const int jj = ((colb >> 6) << 4) + m;    // LSTM unit index (original)
    const float wout = Woutl[jj];
    float bi[4];
#pragma unroll
    for (int g = 0; g < 4; ++g) bi[g] = blp[colb + g * 16 + m];

#pragma unroll
    for (int i = 0; i < 4; ++i) {
#pragma unroll
        for (int r = 0; r < 4; ++r) {
            const int row = bm + wr + i * 16 + rg * 4 + r;
            const float* exr = extra + (size_t)eidx[row] * NG;
            float ex[4];
#pragma unroll
            for (int g = 0; g < 4; ++g) ex[g] = exr[colb + g * 16 + m];
            const float ig = acc[i][0][r] + bi[0] + ex[0];
            const float gg = acc[i][1][r] + bi[1] + ex[1];
            const float fg = acc[i][2][r] + bi[2] + ex[2];
            const float og = acc[i][3][r] + bi[3] + ex[3];
            const size_t cidx = (size_t)row * NH + jj;
            const float cx = c[cidx];
            const float cy = cx * sigm(fg + 1.0f) + sigm(ig) * tanhf(gg);
            const float hy = sigm(og) * tanhf(cy);
            c[cidx] = cy;
            h_hi[cidx] = (f16)hy;
            float part = hy * wout;
#pragma unroll
            for (int msk = 1; msk < 16; msk <<= 1) part += __shfl_xor(part, msk);
            if (m == 0) atomicAdd(&out1[(size_t)row * NRW + t], part);
        }
    }
}

// ---------------- out1 init to b_outl ----------------
__global__ __launch_bounds__(256)
void out1_init(float* __restrict__ out1, const float* __restrict__ boutl)
{
    const size_t i = (size_t)blockIdx.x * 256 + threadIdx.x;
    out1[i] = boutl[0];
}

// ---------------- f32 vector GEMM (K=128 prep/init only) ----------------
template<int ACT, int PERM>
__global__ __launch_bounds__(256)
void gemm128(const float* __restrict__ A, int lda,
             const float* __restrict__ W, int ldw,
             const float* __restrict__ bias,
             float* __restrict__ C, int ldc, int K)
{
    __shared__ float As[16][128];
    __shared__ float Bs[16][128];
    const int bm = blockIdx.y << 7, bn = blockIdx.x << 7;
    const int tid = threadIdx.x;
    const int tx = tid & 15, ty = tid >> 4;
    const int sar = tid >> 1, sac = (tid & 1) << 3;
    const int sbk = tid >> 4, sbc = (tid & 15) << 3;
    float acc[2][2][4][4] = {};
    const float* Ap = A + (size_t)(bm + sar) * lda + sac;
    const float* Wp = W + (size_t)sbk * ldw + bn + sbc;
    for (int kb = 0; kb < K; kb += 16) {
        const float4 av0 = *(const float4*)(Ap + kb);
        const float4 av1 = *(const float4*)(Ap + kb + 4);
        const float4 bv0 = *(const float4*)(Wp + (size_t)kb * ldw);
        const float4 bv1 = *(const float4*)(Wp + (size_t)kb * ldw + 4);
        __syncthreads();
        As[sac + 0][sar] = av0.x; As[sac + 1][sar] = av0.y;
        As[sac + 2][sar] = av0.z; As[sac + 3][sar] = av0.w;
        As[sac + 4][sar] = av1.x; As[sac + 5][sar] = av1.y;
        As[sac + 6][sar] = av1.z; As[sac + 7][sar] = av1.w;
        *(float4*)&Bs[sbk][sbc] = bv0;
        *(float4*)&Bs[sbk][sbc + 4] = bv1;
        __syncthreads();
#pragma unroll
        for (int kk = 0; kk < 16; ++kk) {
            float a[2][4], b[2][4];
            *(float4*)a[0] = *(const float4*)&As[kk][ty << 2];
            *(float4*)a[1] = *(const float4*)&As[kk][64 + (ty << 2)];
            *(float4*)b[0] = *(const float4*)&Bs[kk][tx << 2];
            *(float4*)b[1] = *(const float4*)&Bs[kk][64 + (tx << 2)];
#pragma unroll
            for (int rh = 0; rh < 2; ++rh)
#pragma unroll
                for (int ch = 0; ch < 2; ++ch)
#pragma unroll
                    for (int i = 0; i < 4; ++i)
#pragma unroll
                        for (int j = 0; j < 4; ++j)
                            acc[rh][ch][i][j] = fmaf(a[rh][i], b[ch][j], acc[rh][ch][i][j]);
        }
    }
    float4 bi4[2] = {make_float4(0.f, 0.f, 0.f, 0.f), make_float4(0.f, 0.f, 0.f, 0.f)};
    if (bias) {
        bi4[0] = *(const float4*)(bias + bn + (tx << 2));
        bi4[1] = *(const float4*)(bias + bn + 64 + (tx << 2));
    }
#pragma unroll
    for (int rh = 0; rh < 2; ++rh)
#pragma unroll
        for (int i = 0; i < 4; ++i) {
            const int row = bm + rh * 64 + (ty << 2) + i;
#pragma unroll
            for (int ch = 0; ch < 2; ++ch) {
                const int col = bn + ch * 64 + (tx << 2);
                float v0 = acc[rh][ch][i][0] + bi4[ch].x;
                float v1 = acc[rh][ch][i][1] + bi4[ch].y;
                float v2 = acc[rh][ch][i][2] + bi4[ch].z;
                float v3 = acc[rh][ch][i][3] + bi4[ch].w;
                if (ACT == 1) { v0 = tanhf(v0); v1 = tanhf(v1); v2 = tanhf(v2); v3 = tanhf(v3); }
                const int wcol = PERM ? cperm(col) : col;
                *(float4*)(C + (size_t)row * ldc + wcol) = make_float4(v0, v1, v2, v3);
            }
        }
}

// ---------------- transpose + split (optional gate-interleave on cols) ----------------
template<int PERM>
__global__ __launch_bounds__(256)
void tsplit(const float* __restrict__ in, int ldin, int K,
            f16* __restrict__ ohi, f16* __restrict__ olo)
{
    __shared__ float t[32][33];
    const int kb = blockIdx.x << 5, nb = blockIdx.y << 5;
    const int cx = threadIdx.x & 31, ry = threadIdx.x >> 5;
    const int col = PERM ? oc_of(nb + cx) : (nb + cx);
#pragma unroll
    for (int q = 0; q < 4; ++q)
        t[ry + q * 8][cx] = in[(size_t)(kb + ry + q * 8) * ldin + col];
    __syncthreads();
#pragma unroll
    for (int q = 0; q < 4; ++q) {
        const int n = ry + q * 8;
        const float v = t[cx][n];
        const f16 hi = (f16)v;
        ohi[(size_t)(nb + n) * K + kb + cx] = hi;
        if (olo) olo[(size_t)(nb + n) * K + kb + cx] = (f16)((v - (float)hi) * LO_SCALE);
    }
}

// ---------------- bias permute ----------------
__global__ __launch_bounds__(256)
void permb(const float* __restrict__ b, float* __restrict__ bp)
{
    const int c = blockIdx.x * 256 + threadIdx.x;
    bp[c] = b[oc_of(c)];
}

// ---------------- split f32 -> hi/lo f16 ----------------
__global__ __launch_bounds__(256)
void split_h(const float* __restrict__ h, f16* __restrict__ hi, f16* __restrict__ lo)
{
    const size_t i = (size_t)blockIdx.x * 256 + threadIdx.x;
    const float v = h[i];
    const f16 a = (f16)v;
    hi[i] = a;
    lo[i] = (f16)((v - (float)a) * LO_SCALE);
}

extern "C" void kernel_launch(void* const* d_in, const int* in_sizes, int n_in,
                              void* d_out, int out_size, void* d_ws, size_t ws_size,
                              hipStream_t stream)
{
    const float* latent  = (const float*)d_in[0];
    const float* gu      = (const float*)d_in[2];
    const float* W_int   = (const float*)d_in[3];
    const float* b_int   = (const float*)d_in[4];
    const float* W_intl  = (const float*)d_in[5];
    const float* b_intl  = (const float*)d_in[6];
    const float* W_hup   = (const float*)d_in[7];
    const float* b_hup   = (const float*)d_in[8];
    const float* W_cup   = (const float*)d_in[9];
    const float* b_cup   = (const float*)d_in[10];
    const float* W_hupl  = (const float*)d_in[11];
    const float* b_hupl  = (const float*)d_in[12];
    const float* W_cupl  = (const float*)d_in[13];
    const float* b_cupl  = (const float*)d_in[14];
    const float* W_lstm  = (const float*)d_in[15];
    const float* b_lstm  = (const float*)d_in[16];
    const float* W_up    = (const float*)d_in[17];
    const float* b_up    = (const float*)d_in[18];
    const float* W_down  = (const float*)d_in[19];
    const float* W_downl = (const float*)d_in[20];
    const float* W_outl  = (const float*)d_in[21];
    const float* b_outl  = (const float*)d_in[22];

    float* out0 = (float*)d_out;                 // [B, RW, N]
    float* out1 = out0 + (size_t)NB * NRW * NN;  // [B, RW, 1]

    // workspace
    float* ws     = (float*)d_ws;
    float* c      = ws;                               // NB*NH
    float* logits = c + (size_t)NB * NH;              // NB*NH (inter f32)
    float* gdown  = logits + (size_t)NB * NH;         // NN*NG (permuted cols)
    float* gdownl = gdown + (size_t)NN * NG;          // NN*NG (permuted cols)
    float* blp    = gdownl + (size_t)NN * NG;         // NG (permuted b_lstm)
    float2* part  = (float2*)(blp + NG);              // NB*8 float2
    f16* fp = (f16*)(part + (size_t)NB * 8);
    f16* h_hi[2]; f16* h_lo[2];
    h_hi[0] = fp;                    fp += (size_t)NB * NH;
    h_lo[0] = fp;                    fp += (size_t)NB * NH;
    h_hi[1] = fp;                    fp += (size_t)NB * NH;
    h_lo[1] = fp;                    fp += (size_t)NB * NH;
    f16* i_hi   = fp;                fp += (size_t)NB * NH;
    f16* i_lo   = fp;                fp += (size_t)NB * NH;
    f16* WlT_hi = fp;                fp += (size_t)NG * NH;   // permuted rows
    f16* WlT_lo = fp;                fp += (size_t)NG * NH;
    f16* WupT_hi = fp;               fp += (size_t)NN * NH;
    f16* WupT_lo = fp;               fp += (size_t)NN * NH;
    f16* WhT_hi = fp;                fp += (size_t)NH * NH;
    f16* WhT_lo = fp;                fp += (size_t)NH * NH;
    f16* WcT_hi = fp;                fp += (size_t)NH * NH;
    f16* WcT_lo = fp;                fp += (size_t)NH * NH;
    f16* WhlT_hi = fp;               fp += (size_t)NH * NH;
    f16* WhlT_lo = fp;               fp += (size_t)NH * NH;
    f16* WclT_hi = fp;               fp += (size_t)NH * NH;
    f16* WclT_lo = fp;               fp += (size_t)NH * NH;
    int* kidx = (int*)fp;

    const dim3 blk(256);
    const dim3 g_gates(NG / 128, NB / 128);   // 16 x 64
    const dim3 g_h(NH / 128, NB / 128);       // 4 x 64
    const dim3 g_pre(NG / 128, NN / 128);     // 16 x 4
    const dim3 g_sph(NB * NH / 256);

    // ---- prep ----
    tsplit<1><<<dim3(NH / 32, NG / 32), blk, 0, stream>>>(W_lstm + (size_t)NIN * NG, NG, NH, WlT_hi, WlT_lo);
    tsplit<0><<<dim3(NH / 32, NN / 32), blk, 0, stream>>>(W_up, NH, NH, WupT_hi, WupT_lo);
    tsplit<0><<<dim3(NH / 32, NH / 32), blk, 0, stream>>>(W_hup, NH, NH, WhT_hi, WhT_lo);
    tsplit<0><<<dim3(NH / 32, NH / 32), blk, 0, stream>>>(W_cup, NH, NH, WcT_hi, WcT_lo);
    tsplit<0><<<dim3(NH / 32, NH / 32), blk, 0, stream>>>(W_hupl, NH, NH, WhlT_hi, WhlT_lo);
    tsplit<0><<<dim3(NH / 32, NH / 32), blk, 0, stream>>>(W_cupl, NH, NH, WclT_hi, WclT_lo);
    permb<<<dim3(NG / 256), blk, 0, stream>>>(b_lstm, blp);
    gemm128<0, 1><<<g_pre, blk, 0, stream>>>(W_down, NIN, W_lstm, NG, nullptr, gdown, NG, NIN);
    gemm128<0, 1><<<g_pre, blk, 0, stream>>>(W_downl, NIN, W_lstm, NG, nullptr, gdownl, NG, NIN);

    // ---- loop 1 init ----
    gemm128<1, 0><<<g_h, blk, 0, stream>>>(latent, NZ, W_int, NH, b_int, logits, NH, NZ);
    split_h<<<g_sph, blk, 0, stream>>>(logits, i_hi, i_lo);
    mfma_gemm<2><<<g_h, blk, 0, stream>>>(i_hi, i_lo, WhT_hi, WhT_lo, b_hup,
                                          nullptr, h_hi[0], h_lo[0], NH, NH);
    mfma_gemm<1><<<g_h, blk, 0, stream>>>(i_hi, i_lo, WcT_hi, WcT_lo, b_cup,
                                          c, nullptr, nullptr, NH, NH);

    int cur = 0;
    for (int t = 0; t < NRW; ++t) {
        const int nxt = cur ^ 1;
        if (t == 0)
            mfma_gate_lstm<0><<<g_gates, blk, 0, stream>>>(h_hi[cur], h_lo[cur], WlT_hi, WlT_lo,
                                                           blp, nullptr, nullptr,
                                                           c, h_hi[nxt], h_lo[nxt]);
        else
            mfma_gate_lstm<1><<<g_gates, blk, 0, stream>>>(h_hi[cur], h_lo[cur], WlT_hi, WlT_lo,
                                                           blp, gdown, kidx + (size_t)(t - 1) * NB,
                                                           c, h_hi[nxt], h_lo[nxt]);
        mfma_logits_argmax<<<g_h, blk, 0, stream>>>(h_hi[nxt], h_lo[nxt], WupT_hi, WupT_lo,
                                                    b_up, gu, part, t);
        finalize_argmax<<<dim3(NB / 4), blk, 0, stream>>>(part, out0, kidx, t);
        cur = nxt;
    }

    // ---- loop 2 init ----
    gemm128<1, 0><<<g_h, blk, 0, stream>>>(latent, NZ, W_intl, NH, b_intl, logits, NH, NZ);
    split_h<<<g_sph, blk, 0, stream>>>(logits, i_hi, i_lo);
    mfma_gemm<3><<<g_h, blk, 0, stream>>>(i_hi, i_lo, WhlT_hi, WhlT_lo, b_hupl,
                                          nullptr, h_hi[0], nullptr, NH, NH);
    mfma_gemm<1><<<g_h, blk, 0, stream>>>(i_hi, i_lo, WclT_hi, WclT_lo, b_cupl,
                                          c, nullptr, nullptr, NH, NH);
    out1_init<<<dim3(NB * NRW / 256), blk, 0, stream>>>(out1, b_outl);

    cur = 0;
    for (int t = 0; t < NRW; ++t) {
        const int nxt = cur ^ 1;
        mfma_gate_lstm2<<<g_gates, blk, 0, stream>>>(h_hi[cur], WlT_hi,
                                                     blp, gdownl, kidx + (size_t)t * NB,
                                                     c, h_hi[nxt],
                                                     W_outl, out1, t);
        cur = nxt;
    }
}

// Round 11
// 2882.358 us; speedup vs baseline: 4.1889x; 1.0714x over previous
//
#include <hip/hip_runtime.h>

#define NB 8192
#define NH 512
#define NZ 128
#define NIN 128
#define NN 512
#define NRW 16
#define NG 2048   // 4*NH

typedef _Float16 f16;
typedef _Float16 f16x8 __attribute__((ext_vector_type(8)));
typedef float f32x4 __attribute__((ext_vector_type(4)));

__device__ __forceinline__ float sigm(float x) { return 1.0f / (1.0f + expf(-x)); }

// gate-interleaved column permutation: stored col c <- original col oc(c)
__device__ __forceinline__ int oc_of(int c)
{
    return (((c >> 4) & 3) << 9) + ((c >> 6) << 4) + (c & 15);
}
__device__ __forceinline__ int cperm(int j)
{
    return (j & 15) | (((j >> 4) & 31) << 6) | (((j >> 9) & 3) << 4);
}

// Bijective XCD-aware block swizzle (nwg % 8 == 0 for all our grids).
__device__ __forceinline__ void swz_xcd(int& bx, int& by)
{
    const int gx = gridDim.x;
    const int nwg = gx * gridDim.y;
    int lin = by * gx + bx;
    lin = (lin & 7) * (nwg >> 3) + (lin >> 3);
    const int sh = 31 - __clz(gx);
    bx = lin & (gx - 1);
    by = lin >> sh;
}

// ---------------- async 16B global->LDS ----------------
__device__ __forceinline__ void gload16(const f16* g, f16* l)
{
    __builtin_amdgcn_global_load_lds(
        (const __attribute__((address_space(1))) void*)g,
        (__attribute__((address_space(3))) void*)l, 16, 0, 0);
}

// 16B-slot swizzle: 2-way (free) bank aliasing for 16-row b128 column reads.
__device__ __forceinline__ int swz4(int row) { return (row & 3) ^ ((row >> 2) & 3); }

// Stage one 128x32 f16 A-tile (8KB): linear LDS dest + inverse-swizzled global src.
__device__ __forceinline__ void stage_tile(f16* tilebase, const f16* src,
                                           int rowbase, int kb, int wid, int lane)
{
#pragma unroll
    for (int q = 0; q < 2; ++q) {
        const int iw = wid * 2 + q;
        const int chunk = (iw << 6) | lane;
        const int row = chunk >> 2;
        const int p = (chunk & 3) ^ swz4(row);
        const f16* g = src + (size_t)(rowbase + row) * NH + kb + (p << 3);
        gload16(g, tilebase + (iw << 9));
    }
}

__device__ __forceinline__ f16x8 frag(const f16* tile, int row, int sl)
{
    return *(const f16x8*)(tile + row * 32 + ((sl ^ swz4(row)) << 3));
}

__device__ __forceinline__ void readA(f16x8 (&a)[4], const f16* sbuf, int wr, int r16, int sl)
{
#pragma unroll
    for (int f = 0; f < 4; ++f) a[f] = frag(sbuf, wr + f * 16 + r16, sl);
}

// Packed-B frag load: per (nblk,kt) an 8KB chunk (4096 f16).
// group g = wc2*256 + f*64 + lane  ->  element offset wc2*2048 + f*512 + lane*8.
__device__ __forceinline__ void loadBfr(f16x8 (&d)[4], const f16* p, size_t base)
{
#pragma unroll
    for (int f = 0; f < 4; ++f) d[f] = *(const f16x8*)(p + base + f * 512);
}

__device__ __forceinline__ f32x4 MM(const f16x8 a, const f16x8 b, f32x4 c)
{
    return __builtin_amdgcn_mfma_f32_16x16x32_f16(a, b, c, 0, 0, 0);
}

// ---------------- single-acc split core: acc = (Ahi+Alo)(Bhi+Blo) [al*bl dropped] ----------------
// A staged in LDS (double-buffered); B read directly from packed global (L2-hot).
// K = 512 fixed (16 k-tiles of 32).
template<int SPLIT>
__device__ __forceinline__ void core3(const f16* Ahi, const f16* Alo,
                                      const f16* Bph, const f16* Bpl,
                                      f16* s0h, f16* s0l, f16* s1h, f16* s1l,
                                      int bm, int bnblk, int wid, int lane, int wr, int wc2,
                                      f32x4 (&acc)[4][4])
{
    const int r16 = lane & 15, sl = lane >> 4;
    const size_t bwoff = (size_t)(wc2 << 11) + lane * 8;
    f16x8 bAh[4], bAl[4], bBh[4], bBl[4];

    stage_tile(s0h, Ahi, bm, 0, wid, lane);
    if (SPLIT) stage_tile(s0l, Alo, bm, 0, wid, lane);
    loadBfr(bAh, Bph, (((size_t)bnblk << 4) << 12) + bwoff);
    if (SPLIT) loadBfr(bAl, Bpl, (((size_t)bnblk << 4) << 12) + bwoff);

#pragma unroll 1
    for (int kt = 0; kt < 16; kt += 2) {
        // ---- even step: buf0, bA ----
        __syncthreads();
        {
            const int kn = kt + 1;
            stage_tile(s1h, Ahi, bm, kn << 5, wid, lane);
            if (SPLIT) stage_tile(s1l, Alo, bm, kn << 5, wid, lane);
            loadBfr(bBh, Bph, ((((size_t)bnblk << 4) + kn) << 12) + bwoff);
            if (SPLIT) loadBfr(bBl, Bpl, ((((size_t)bnblk << 4) + kn) << 12) + bwoff);
        }
        f16x8 ah[4], al[4];
        readA(ah, s0h, wr, r16, sl);
        if (SPLIT) readA(al, s0l, wr, r16, sl);
        __builtin_amdgcn_s_setprio(1);
#pragma unroll
        for (int i = 0; i < 4; ++i)
#pragma unroll
            for (int j = 0; j < 4; ++j) {
                acc[i][j] = MM(ah[i], bAh[j], acc[i][j]);
                if (SPLIT) {
                    acc[i][j] = MM(al[i], bAh[j], acc[i][j]);
                    acc[i][j] = MM(ah[i], bAl[j], acc[i][j]);
                }
            }
        __builtin_amdgcn_s_setprio(0);
        // ---- odd step: buf1, bB ----
        __syncthreads();
        if (kt + 2 < 16) {
            const int kn = kt + 2;
            stage_tile(s0h, Ahi, bm, kn << 5, wid, lane);
            if (SPLIT) stage_tile(s0l, Alo, bm, kn << 5, wid, lane);
            loadBfr(bAh, Bph, ((((size_t)bnblk << 4) + kn) << 12) + bwoff);
            if (SPLIT) loadBfr(bAl, Bpl, ((((size_t)bnblk << 4) + kn) << 12) + bwoff);
        }
        readA(ah, s1h, wr, r16, sl);
        if (SPLIT) readA(al, s1l, wr, r16, sl);
        __builtin_amdgcn_s_setprio(1);
#pragma unroll
        for (int i = 0; i < 4; ++i)
#pragma unroll
            for (int j = 0; j < 4; ++j) {
                acc[i][j] = MM(ah[i], bBh[j], acc[i][j]);
                if (SPLIT) {
                    acc[i][j] = MM(al[i], bBh[j], acc[i][j]);
                    acc[i][j] = MM(ah[i], bBl[j], acc[i][j]);
                }
            }
        __builtin_amdgcn_s_setprio(0);
    }
}

// ---------------- plain split GEMM (inits). OUT: 1=tanh f32, 2=tanh split, 3=tanh f16 ----------------
template<int OUT>
__global__ __launch_bounds__(256, 2)
void mfma_gemm(const f16* __restrict__ Ahi, const f16* __restrict__ Alo,
               const f16* __restrict__ Bph, const f16* __restrict__ Bpl,
               const float* __restrict__ bias,
               float* __restrict__ C, f16* __restrict__ Ohi, f16* __restrict__ Olo)
{
    __shared__ f16 s[4][4096];
    int bx = blockIdx.x, by = blockIdx.y;
    swz_xcd(bx, by);
    const int bm = by << 7;
    const int tid = threadIdx.x;
    const int wid = tid >> 6, lane = tid & 63;
    const int wr = ((wid >> 1) & 1) << 6;
    const int wc2 = wid & 1;

    f32x4 acc[4][4];
#pragma unroll
    for (int i = 0; i < 4; ++i)
#pragma unroll
        for (int j = 0; j < 4; ++j) acc[i][j] = (f32x4)(0.0f);

    core3<1>(Ahi, Alo, Bph, Bpl, s[0], s[1], s[2], s[3], bm, bx, wid, lane, wr, wc2, acc);

    const int r16 = lane & 15, rg = lane >> 4;
#pragma unroll
    for (int i = 0; i < 4; ++i) {
#pragma unroll
        for (int r = 0; r < 4; ++r) {
            const int row = bm + wr + i * 16 + rg * 4 + r;
#pragma unroll
            for (int j = 0; j < 4; ++j) {
                const int col = (bx << 7) + (wc2 << 6) + j * 16 + r16;
                float v = acc[i][j][r] + bias[col];
                v = tanhf(v);
                const size_t idx = (size_t)row * NH + col;
                if (OUT == 1) C[idx] = v;
                else {
                    const f16 a = (f16)v;
                    Ohi[idx] = a;
                    if (OUT == 2) Olo[idx] = (f16)(v - (float)a);
                }
            }
        }
    }
}

// ---------------- logits GEMM + fused gumbel-argmax partials ----------------
__global__ __launch_bounds__(256, 2)
void mfma_logits_argmax(const f16* __restrict__ Ahi, const f16* __restrict__ Alo,
                        const f16* __restrict__ Bph, const f16* __restrict__ Bpl,
                        const float* __restrict__ bias,
                        const float* __restrict__ gu,
                        float2* __restrict__ part, int t)
{
    __shared__ f16 s[4][4096];
    int bx = blockIdx.x, by = blockIdx.y;
    swz_xcd(bx, by);
    const int bm = by << 7;
    const int tid = threadIdx.x;
    const int wid = tid >> 6, lane = tid & 63;
    const int wr = ((wid >> 1) & 1) << 6;
    const int wc2 = wid & 1;

    f32x4 acc[4][4];
#pragma unroll
    for (int i = 0; i < 4; ++i)
#pragma unroll
        for (int j = 0; j < 4; ++j) acc[i][j] = (f32x4)(0.0f);

    core3<1>(Ahi, Alo, Bph, Bpl, s[0], s[1], s[2], s[3], bm, bx, wid, lane, wr, wc2, acc);

    const int r16 = lane & 15, rg = lane >> 4;
    const int cb = (bx << 1) + wc2;          // 64-col slice 0..7
    float bi[4];
#pragma unroll
    for (int j = 0; j < 4; ++j) bi[j] = bias[(bx << 7) + (wc2 << 6) + j * 16 + r16];

#pragma unroll
    for (int i = 0; i < 4; ++i) {
#pragma unroll
        for (int r = 0; r < 4; ++r) {
            const int row = bm + wr + i * 16 + rg * 4 + r;
            const float* urow = gu + ((size_t)t * NB + row) * NN;
            float best = -INFINITY;
            int bidx = 0x7fffffff;
#pragma unroll
            for (int j = 0; j < 4; ++j) {
                const int col = (bx << 7) + (wc2 << 6) + j * 16 + r16;
                const float u = urow[col];
                const float g = -logf(-logf(u + 1e-20f) + 1e-20f);
                const float v = acc[i][j][r] + bi[j] + g;
                if (v > best || (v == best && col < bidx)) { best = v; bidx = col; }
            }
#pragma unroll
            for (int msk = 1; msk < 16; msk <<= 1) {
                const float ov = __shfl_xor(best, msk);
                const int oi = __shfl_xor(bidx, msk);
                if (ov > best || (ov == best && oi < bidx)) { best = ov; bidx = oi; }
            }
            if (r16 == 0) part[(size_t)row * 8 + cb] = make_float2(best, (float)bidx);
        }
    }
}

// ---------------- finalize (t=15 only): winner over 8 slices -> one-hot + kidx ----------------
__global__ __launch_bounds__(256)
void finalize_argmax(const float2* __restrict__ part,
                     float* __restrict__ out0, int* __restrict__ kidx, int t)
{
    const int w = threadIdx.x >> 6;
    const int lane = threadIdx.x & 63;
    const int row = blockIdx.x * 4 + w;
    float best = -INFINITY;
    int bi = 0x7fffffff;
    if (lane < 8) {
        const float2 p = part[(size_t)row * 8 + lane];
        best = p.x;
        bi = (int)p.y;
    }
#pragma unroll
    for (int msk = 1; msk < 8; msk <<= 1) {
        const float ov = __shfl_xor(best, msk);
        const int oi = __shfl_xor(bi, msk);
        if (ov > best || (ov == best && oi < bi)) { best = ov; bi = oi; }
    }
    const int win = __shfl(bi, 0);
    if (lane == 0) kidx[(size_t)t * NB + row] = win;
    float* orow = out0 + ((size_t)row * NRW + t) * NN;
    const int c0 = lane * 8;
    *(float4*)(orow + c0) = make_float4(c0 == win, c0 + 1 == win, c0 + 2 == win, c0 + 3 == win);
    *(float4*)(orow + c0 + 4) = make_float4(c0 + 4 == win, c0 + 5 == win, c0 + 6 == win, c0 + 7 == win);
}

// ---------------- loop-1 fused gate GEMM + LSTM; also finalizes step t-1 ----------------
template<int HAS_PART>
__global__ __launch_bounds__(256, 2)
void mfma_gate_lstm(const f16* __restrict__ Ahi, const f16* __restrict__ Alo,
                    const f16* __restrict__ Bph, const f16* __restrict__ Bpl,
                    const float* __restrict__ blp,
                    const float* __restrict__ extra,
                    const float2* __restrict__ part,
                    int* __restrict__ kidx, float* __restrict__ out0, int t,
                    float* __restrict__ c,
                    f16* __restrict__ h_hi, f16* __restrict__ h_lo)
{
    __shared__ f16 s[4][4096];
    __shared__ int winlds[128];
    int bx = blockIdx.x, by = blockIdx.y;
    swz_xcd(bx, by);
    const int bm = by << 7;
    const int tid = threadIdx.x;
    const int wid = tid >> 6, lane = tid & 63;
    const int wr = ((wid >> 1) & 1) << 6;
    const int wc2 = wid & 1;

    if (HAS_PART && tid < 128) {
        const float2* p = part + (size_t)(bm + tid) * 8;
        float best = -INFINITY;
        int bi = 0x7fffffff;
#pragma unroll
        for (int q = 0; q < 8; ++q) {
            const float2 pv = p[q];
            if (pv.x > best || (pv.x == best && (int)pv.y < bi)) { best = pv.x; bi = (int)pv.y; }
        }
        winlds[tid] = bi;
        if (bx == 0) kidx[(size_t)(t - 1) * NB + bm + tid] = bi;
    }

    f32x4 acc[4][4];
#pragma unroll
    for (int i = 0; i < 4; ++i)
#pragma unroll
        for (int j = 0; j < 4; ++j) acc[i][j] = (f32x4)(0.0f);

    core3<1>(Ahi, Alo, Bph, Bpl, s[0], s[1], s[2], s[3], bm, bx, wid, lane, wr, wc2, acc);

    const int m = lane & 15, rg = lane >> 4;
    const int colb = (bx << 7) + (wc2 << 6);
    const int jj = ((colb >> 6) << 4) + m;    // LSTM unit index
    float bi4[4];
#pragma unroll
    for (int g = 0; g < 4; ++g) bi4[g] = blp[colb + g * 16 + m];

#pragma unroll
    for (int i = 0; i < 4; ++i) {
#pragma unroll
        for (int r = 0; r < 4; ++r) {
            const int row = bm + wr + i * 16 + rg * 4 + r;
            float ex[4] = {0.f, 0.f, 0.f, 0.f};
            if (HAS_PART) {
                const float* exr = extra + (size_t)winlds[row - bm] * NG;
#pragma unroll
                for (int g = 0; g < 4; ++g) ex[g] = exr[colb + g * 16 + m];
            }
            const float ig = acc[i][0][r] + bi4[0] + ex[0];
            const float gg = acc[i][1][r] + bi4[1] + ex[1];
            const float fg = acc[i][2][r] + bi4[2] + ex[2];
            const float og = acc[i][3][r] + bi4[3] + ex[3];
            const size_t cidx = (size_t)row * NH + jj;
            const float cx = c[cidx];
            const float cy = cx * sigm(fg + 1.0f) + sigm(ig) * tanhf(gg);
            const float hy = sigm(og) * tanhf(cy);
            c[cidx] = cy;
            const f16 a = (f16)hy;
            h_hi[cidx] = a;
            h_lo[cidx] = (f16)(hy - (float)a);
        }
    }

    // one-hot write for step t-1: this block covers cols [bx*32, bx*32+32)
    if (HAS_PART) {
        const int rr = tid >> 1;
        const int cs = (bx << 5) + ((tid & 1) << 4);
        const int win = winlds[rr];
        float* orow = out0 + ((size_t)(bm + rr) * NRW + (t - 1)) * NN + cs;
#pragma unroll
        for (int e = 0; e < 16; e += 4) {
            const int c0 = cs + e;
            *(float4*)(orow + e) = make_float4(c0 == win, c0 + 1 == win, c0 + 2 == win, c0 + 3 == win);
        }
    }
}

// ---------------- loop-2 fused gate GEMM + LSTM + rowdot (1-pass f16) ----------------
__global__ __launch_bounds__(256, 3)
void mfma_gate_lstm2(const f16* __restrict__ Ahi, const f16* __restrict__ Bph,
                     const float* __restrict__ blp,
                     const float* __restrict__ extra, const int* __restrict__ eidx,
                     float* __restrict__ c,
                     f16* __restrict__ h_hi,
                     const float* __restrict__ Woutl,
                     float* __restrict__ out1, int t)
{
    __shared__ f16 s[2][4096];
    int bx = blockIdx.x, by = blockIdx.y;
    swz_xcd(bx, by);
    const int bm = by << 7;
    const int tid = threadIdx.x;
    const int wid = tid >> 6, lane = tid & 63;
    const int wr = ((wid >> 1) & 1) << 6;
    const int wc2 = wid & 1;

    f32x4 acc[4][4];
#pragma unroll
    for (int i = 0; i < 4; ++i)
#pragma unroll
        for (int j = 0; j < 4; ++j) acc[i][j] = (f32x4)(0.0f);

    core3<0>(Ahi, nullptr, Bph, nullptr, s[0], nullptr, s[1], nullptr,
             bm, bx, wid, lane, wr, wc2, acc);

    const int m = lane & 15, rg = lane >> 4;
    const int colb = (bx << 7) + (wc2 << 6);
    const int jj = ((colb >> 6) << 4) + m;
    const float wout = Woutl[jj];
    float bi4[4];
#pragma unroll
    for (int g = 0; g < 4; ++g) bi4[g] = blp[colb + g * 16 + m];

#pragma unroll
    for (int i = 0; i < 4; ++i) {
#pragma unroll
        for (int r = 0; r < 4; ++r) {
            const int row = bm + wr + i * 16 + rg * 4 + r;
            const float* exr = extra + (size_t)eidx[row] * NG;
            float ex[4];
#pragma unroll
            for (int g = 0; g < 4; ++g) ex[g] = exr[colb + g * 16 + m];
            const float ig = acc[i][0][r] + bi4[0] + ex[0];
            const float gg = acc[i][1][r] + bi4[1] + ex[1];
            const float fg = acc[i][2][r] + bi4[2] + ex[2];
            const float og = acc[i][3][r] + bi4[3] + ex[3];
            const size_t cidx = (size_t)row * NH + jj;
            const float cx = c[cidx];
            const float cy = cx * sigm(fg + 1.0f) + sigm(ig) * tanhf(gg);
            const float hy = sigm(og) * tanhf(cy);
            c[cidx] = cy;
            h_hi[cidx] = (f16)hy;
            float pt = hy * wout;
#pragma unroll
            for (int msk = 1; msk < 16; msk <<= 1) pt += __shfl_xor(pt, msk);
            if (m == 0) atomicAdd(&out1[(size_t)row * NRW + t], pt);
        }
    }
}

// ---------------- out1 init to b_outl ----------------
__global__ __launch_bounds__(256)
void out1_init(float* __restrict__ out1, const float* __restrict__ boutl)
{
    const size_t i = (size_t)blockIdx.x * 256 + threadIdx.x;
    out1[i] = boutl[0];
}

// ---------------- f32 vector GEMM (K=128 prep/init only) ----------------
template<int ACT, int PERM>
__global__ __launch_bounds__(256)
void gemm128(const float* __restrict__ A, int lda,
             const float* __restrict__ W, int ldw,
             const float* __restrict__ bias,
             float* __restrict__ C, int ldc, int K)
{
    __shared__ float As[16][128];
    __shared__ float Bs[16][128];
    const int bm = blockIdx.y << 7, bn = blockIdx.x << 7;
    const int tid = threadIdx.x;
    const int tx = tid & 15, ty = tid >> 4;
    const int sar = tid >> 1, sac = (tid & 1) << 3;
    const int sbk = tid >> 4, sbc = (tid & 15) << 3;
    float acc[2][2][4][4] = {};
    const float* Ap = A + (size_t)(bm + sar) * lda + sac;
    const float* Wp = W + (size_t)sbk * ldw + bn + sbc;
    for (int kb = 0; kb < K; kb += 16) {
        const float4 av0 = *(const float4*)(Ap + kb);
        const float4 av1 = *(const float4*)(Ap + kb + 4);
        const float4 bv0 = *(const float4*)(Wp + (size_t)kb * ldw);
        const float4 bv1 = *(const float4*)(Wp + (size_t)kb * ldw + 4);
        __syncthreads();
        As[sac + 0][sar] = av0.x; As[sac + 1][sar] = av0.y;
        As[sac + 2][sar] = av0.z; As[sac + 3][sar] = av0.w;
        As[sac + 4][sar] = av1.x; As[sac + 5][sar] = av1.y;
        As[sac + 6][sar] = av1.z; As[sac + 7][sar] = av1.w;
        *(float4*)&Bs[sbk][sbc] = bv0;
        *(float4*)&Bs[sbk][sbc + 4] = bv1;
        __syncthreads();
#pragma unroll
        for (int kk = 0; kk < 16; ++kk) {
            float a[2][4], b[2][4];
            *(float4*)a[0] = *(const float4*)&As[kk][ty << 2];
            *(float4*)a[1] = *(const float4*)&As[kk][64 + (ty << 2)];
            *(float4*)b[0] = *(const float4*)&Bs[kk][tx << 2];
            *(float4*)b[1] = *(const float4*)&Bs[kk][64 + (tx << 2)];
#pragma unroll
            for (int rh = 0; rh < 2; ++rh)
#pragma unroll
                for (int ch = 0; ch < 2; ++ch)
#pragma unroll
                    for (int i = 0; i < 4; ++i)
#pragma unroll
                        for (int j = 0; j < 4; ++j)
                            acc[rh][ch][i][j] = fmaf(a[rh][i], b[ch][j], acc[rh][ch][i][j]);
        }
    }
    float4 bi4[2] = {make_float4(0.f, 0.f, 0.f, 0.f), make_float4(0.f, 0.f, 0.f, 0.f)};
    if (bias) {
        bi4[0] = *(const float4*)(bias + bn + (tx << 2));
        bi4[1] = *(const float4*)(bias + bn + 64 + (tx << 2));
    }
#pragma unroll
    for (int rh = 0; rh < 2; ++rh)
#pragma unroll
        for (int i = 0; i < 4; ++i) {
            const int row = bm + rh * 64 + (ty << 2) + i;
#pragma unroll
            for (int ch = 0; ch < 2; ++ch) {
                const int col = bn + ch * 64 + (tx << 2);
                float v0 = acc[rh][ch][i][0] + bi4[ch].x;
                float v1 = acc[rh][ch][i][1] + bi4[ch].y;
                float v2 = acc[rh][ch][i][2] + bi4[ch].z;
                float v3 = acc[rh][ch][i][3] + bi4[ch].w;
                if (ACT == 1) { v0 = tanhf(v0); v1 = tanhf(v1); v2 = tanhf(v2); v3 = tanhf(v3); }
                const int wcol = PERM ? cperm(col) : col;
                *(float4*)(C + (size_t)row * ldc + wcol) = make_float4(v0, v1, v2, v3);
            }
        }
}

// ---------------- pack weights: in [K=512][Norig] f32 -> frag-major packed hi/lo f16 ----------------
// group cch: wc2=cch>>8, f=(cch>>6)&3, slc=(cch>>4)&3, r16=cch&15
// n = nblk*128 + wc2*64 + f*16 + r16 ; k = kt*32 + slc*8 + e ; element offset cch*8.
template<int PERM>
__global__ __launch_bounds__(256)
void tsplit_pack(const float* __restrict__ in, int ldin,
                 f16* __restrict__ phi, f16* __restrict__ plo)
{
    const int kt = blockIdx.x;
    const int nblk = blockIdx.y;
#pragma unroll
    for (int q = 0; q < 2; ++q) {
        const int cch = threadIdx.x + q * 256;
        const int wc2 = cch >> 8, f = (cch >> 6) & 3, slc = (cch >> 4) & 3, r16 = cch & 15;
        const int n = (nblk << 7) + (wc2 << 6) + (f << 4) + r16;
        const int ncol = PERM ? oc_of(n) : n;
        const int k0 = (kt << 5) + (slc << 3);
        f16x8 h8, l8;
#pragma unroll
        for (int e = 0; e < 8; ++e) {
            const float v = in[(size_t)(k0 + e) * ldin + ncol];
            const f16 hi = (f16)v;
            h8[e] = hi;
            l8[e] = (f16)(v - (float)hi);
        }
        const size_t off = ((((size_t)nblk << 4) + kt) << 12) + (size_t)cch * 8;
        *(f16x8*)(phi + off) = h8;
        *(f16x8*)(plo + off) = l8;
    }
}

// ---------------- bias permute ----------------
__global__ __launch_bounds__(256)
void permb(const float* __restrict__ b, float* __restrict__ bp)
{
    const int c = blockIdx.x * 256 + threadIdx.x;
    bp[c] = b[oc_of(c)];
}

// ---------------- split f32 -> hi/lo f16 (unscaled lo) ----------------
__global__ __launch_bounds__(256)
void split_h(const float* __restrict__ h, f16* __restrict__ hi, f16* __restrict__ lo)
{
    const size_t i = (size_t)blockIdx.x * 256 + threadIdx.x;
    const float v = h[i];
    const f16 a = (f16)v;
    hi[i] = a;
    lo[i] = (f16)(v - (float)a);
}

extern "C" void kernel_launch(void* const* d_in, const int* in_sizes, int n_in,
                              void* d_out, int out_size, void* d_ws, size_t ws_size,
                              hipStream_t stream)
{
    const float* latent  = (const float*)d_in[0];
    const float* gu      = (const float*)d_in[2];
    const float* W_int   = (const float*)d_in[3];
    const float* b_int   = (const float*)d_in[4];
    const float* W_intl  = (const float*)d_in[5];
    const float* b_intl  = (const float*)d_in[6];
    const float* W_hup   = (const float*)d_in[7];
    const float* b_hup   = (const float*)d_in[8];
    const float* W_cup   = (const float*)d_in[9];
    const float* b_cup   = (const float*)d_in[10];
    const float* W_hupl  = (const float*)d_in[11];
    const float* b_hupl  = (const float*)d_in[12];
    const float* W_cupl  = (const float*)d_in[13];
    const float* b_cupl  = (const float*)d_in[14];
    const float* W_lstm  = (const float*)d_in[15];
    const float* b_lstm  = (const float*)d_in[16];
    const float* W_up    = (const float*)d_in[17];
    const float* b_up    = (const float*)d_in[18];
    const float* W_down  = (const float*)d_in[19];
    const float* W_downl = (const float*)d_in[20];
    const float* W_outl  = (const float*)d_in[21];
    const float* b_outl  = (const float*)d_in[22];

    float* out0 = (float*)d_out;                 // [B, RW, N]
    float* out1 = out0 + (size_t)NB * NRW * NN;  // [B, RW, 1]

    // workspace
    float* ws     = (float*)d_ws;
    float* c      = ws;                               // NB*NH
    float* logits = c + (size_t)NB * NH;              // NB*NH (f32 init scratch)
    float* gdown  = logits + (size_t)NB * NH;         // NN*NG (permuted cols)
    float* gdownl = gdown + (size_t)NN * NG;          // NN*NG
    float* blp    = gdownl + (size_t)NN * NG;         // NG
    float2* part  = (float2*)(blp + NG);              // NB*8
    f16* fp = (f16*)(part + (size_t)NB * 8);
    f16* h_hi[2]; f16* h_lo[2];
    h_hi[0] = fp;                    fp += (size_t)NB * NH;
    h_lo[0] = fp;                    fp += (size_t)NB * NH;
    h_hi[1] = fp;                    fp += (size_t)NB * NH;
    h_lo[1] = fp;                    fp += (size_t)NB * NH;
    f16* i_hi   = fp;                fp += (size_t)NB * NH;
    f16* i_lo   = fp;                fp += (size_t)NB * NH;
    f16* Wlp_hi = fp;                fp += (size_t)NG * NH;   // packed, gate-perm
    f16* Wlp_lo = fp;                fp += (size_t)NG * NH;
    f16* Wup_hi = fp;                fp += (size_t)NN * NH;
    f16* Wup_lo = fp;                fp += (size_t)NN * NH;
    f16* Whp_hi = fp;                fp += (size_t)NH * NH;
    f16* Whp_lo = fp;                fp += (size_t)NH * NH;
    f16* Wcp_hi = fp;                fp += (size_t)NH * NH;
    f16* Wcp_lo = fp;                fp += (size_t)NH * NH;
    f16* Whlp_hi = fp;               fp += (size_t)NH * NH;
    f16* Whlp_lo = fp;               fp += (size_t)NH * NH;
    f16* Wclp_hi = fp;               fp += (size_t)NH * NH;
    f16* Wclp_lo = fp;               fp += (size_t)NH * NH;
    int* kidx = (int*)fp;

    const dim3 blk(256);
    const dim3 g_gates(NG / 128, NB / 128);   // 16 x 64
    const dim3 g_h(NH / 128, NB / 128);       // 4 x 64
    const dim3 g_pre(NG / 128, NN / 128);     // 16 x 4
    const dim3 g_sph(NB * NH / 256);

    // ---- prep: packed weights, permuted bias, gather matrices ----
    tsplit_pack<1><<<dim3(16, NG / 128), blk, 0, stream>>>(W_lstm + (size_t)NIN * NG, NG, Wlp_hi, Wlp_lo);
    tsplit_pack<0><<<dim3(16, NN / 128), blk, 0, stream>>>(W_up, NH, Wup_hi, Wup_lo);
    tsplit_pack<0><<<dim3(16, NH / 128), blk, 0, stream>>>(W_hup, NH, Whp_hi, Whp_lo);
    tsplit_pack<0><<<dim3(16, NH / 128), blk, 0, stream>>>(W_cup, NH, Wcp_hi, Wcp_lo);
    tsplit_pack<0><<<dim3(16, NH / 128), blk, 0, stream>>>(W_hupl, NH, Whlp_hi, Whlp_lo);
    tsplit_pack<0><<<dim3(16, NH / 128), blk, 0, stream>>>(W_cupl, NH, Wclp_hi, Wclp_lo);
    permb<<<dim3(NG / 256), blk, 0, stream>>>(b_lstm, blp);
    gemm128<0, 1><<<g_pre, blk, 0, stream>>>(W_down, NIN, W_lstm, NG, nullptr, gdown, NG, NIN);
    gemm128<0, 1><<<g_pre, blk, 0, stream>>>(W_downl, NIN, W_lstm, NG, nullptr, gdownl, NG, NIN);

    // ---- loop 1 init ----
    gemm128<1, 0><<<g_h, blk, 0, stream>>>(latent, NZ, W_int, NH, b_int, logits, NH, NZ);
    split_h<<<g_sph, blk, 0, stream>>>(logits, i_hi, i_lo);
    mfma_gemm<2><<<g_h, blk, 0, stream>>>(i_hi, i_lo, Whp_hi, Whp_lo, b_hup,
                                          nullptr, h_hi[0], h_lo[0]);
    mfma_gemm<1><<<g_h, blk, 0, stream>>>(i_hi, i_lo, Wcp_hi, Wcp_lo, b_cup,
                                          c, nullptr, nullptr);

    int cur = 0;
    for (int t = 0; t < NRW; ++t) {
        const int nxt = cur ^ 1;
        if (t == 0)
            mfma_gate_lstm<0><<<g_gates, blk, 0, stream>>>(h_hi[cur], h_lo[cur], Wlp_hi, Wlp_lo,
                                                           blp, nullptr, nullptr, nullptr, nullptr, t,
                                                           c, h_hi[nxt], h_lo[nxt]);
        else
            mfma_gate_lstm<1><<<g_gates, blk, 0, stream>>>(h_hi[cur], h_lo[cur], Wlp_hi, Wlp_lo,
                                                           blp, gdown, part, kidx, out0, t,
                                                           c, h_hi[nxt], h_lo[nxt]);
        mfma_logits_argmax<<<g_h, blk, 0, stream>>>(h_hi[nxt], h_lo[nxt], Wup_hi, Wup_lo,
                                                    b_up, gu, part, t);
        cur = nxt;
    }
    finalize_argmax<<<dim3(NB / 4), blk, 0, stream>>>(part, out0, kidx, NRW - 1);

    // ---- loop 2 init ----
    gemm128<1, 0><<<g_h, blk, 0, stream>>>(latent, NZ, W_intl, NH, b_intl, logits, NH, NZ);
    split_h<<<g_sph, blk, 0, stream>>>(logits, i_hi, i_lo);
    mfma_gemm<3><<<g_h, blk, 0, stream>>>(i_hi, i_lo, Whlp_hi, Whlp_lo, b_hupl,
                                          nullptr, h_hi[0], nullptr);
    mfma_gemm<1><<<g_h, blk, 0, stream>>>(i_hi, i_lo, Wclp_hi, Wclp_lo, b_cupl,
                                          c, nullptr, nullptr);
    out1_init<<<dim3(NB * NRW / 256), blk, 0, stream>>>(out1, b_outl);

    cur = 0;
    for (int t = 0; t < NRW; ++t) {
        const int nxt = cur ^ 1;
        mfma_gate_lstm2<<<g_gates, blk, 0, stream>>>(h_hi[cur], Wlp_hi,
                                                     blp, gdownl, kidx + (size_t)t * NB,
                                                     c, h_hi[nxt],
                                                     W_outl, out1, t);
        cur = nxt;
    }
}

// Round 12
// 2759.425 us; speedup vs baseline: 4.3755x; 1.0446x over previous
//
#include <hip/hip_runtime.h>

#define NB 8192
#define NH 512
#define NZ 128
#define NIN 128
#define NN 512
#define NRW 16
#define NG 2048   // 4*NH

typedef _Float16 f16;
typedef _Float16 f16x8 __attribute__((ext_vector_type(8)));
typedef float f32x4 __attribute__((ext_vector_type(4)));

__device__ __forceinline__ float sigm(float x) { return 1.0f / (1.0f + expf(-x)); }

// gate-interleaved column permutation: stored col c <- original col oc(c)
__device__ __forceinline__ int oc_of(int c)
{
    return (((c >> 4) & 3) << 9) + ((c >> 6) << 4) + (c & 15);
}
__device__ __forceinline__ int cperm(int j)
{
    return (j & 15) | (((j >> 4) & 31) << 6) | (((j >> 9) & 3) << 4);
}

// Bijective XCD-aware block swizzle (nwg % 8 == 0 for all our grids).
__device__ __forceinline__ void swz_xcd(int& bx, int& by)
{
    const int gx = gridDim.x;
    const int nwg = gx * gridDim.y;
    int lin = by * gx + bx;
    lin = (lin & 7) * (nwg >> 3) + (lin >> 3);
    const int sh = 31 - __clz(gx);
    bx = lin & (gx - 1);
    by = lin >> sh;
}

// ---------------- async 16B global->LDS ----------------
__device__ __forceinline__ void gload16(const f16* g, f16* l)
{
    __builtin_amdgcn_global_load_lds(
        (const __attribute__((address_space(1))) void*)g,
        (__attribute__((address_space(3))) void*)l, 16, 0, 0);
}

// 16B-slot swizzle: 2-way (free) bank aliasing for 16-row b128 column reads.
__device__ __forceinline__ int swz4(int row) { return (row & 3) ^ ((row >> 2) & 3); }

// Stage one 128x32 f16 A-tile (8KB): linear LDS dest + inverse-swizzled global src.
__device__ __forceinline__ void stage_tile(f16* tilebase, const f16* src,
                                           int rowbase, int kb, int wid, int lane)
{
#pragma unroll
    for (int q = 0; q < 2; ++q) {
        const int iw = wid * 2 + q;
        const int chunk = (iw << 6) | lane;
        const int row = chunk >> 2;
        const int p = (chunk & 3) ^ swz4(row);
        const f16* g = src + (size_t)(rowbase + row) * NH + kb + (p << 3);
        gload16(g, tilebase + (iw << 9));
    }
}

__device__ __forceinline__ f16x8 frag(const f16* tile, int row, int sl)
{
    return *(const f16x8*)(tile + row * 32 + ((sl ^ swz4(row)) << 3));
}

__device__ __forceinline__ void readA(f16x8 (&a)[4], const f16* sbuf, int wr, int r16, int sl)
{
#pragma unroll
    for (int f = 0; f < 4; ++f) a[f] = frag(sbuf, wr + f * 16 + r16, sl);
}

// Packed-B frag load: per (nblk,kt) an 8KB chunk (4096 f16).
// group g = wc2*256 + f*64 + lane  ->  element offset wc2*2048 + f*512 + lane*8.
__device__ __forceinline__ void loadBfr(f16x8 (&d)[4], const f16* p, size_t base)
{
#pragma unroll
    for (int f = 0; f < 4; ++f) d[f] = *(const f16x8*)(p + base + f * 512);
}

__device__ __forceinline__ f32x4 MM(const f16x8 a, const f16x8 b, f32x4 c)
{
    return __builtin_amdgcn_mfma_f32_16x16x32_f16(a, b, c, 0, 0, 0);
}

// ---------------- single-acc split core: acc = (Ahi+Alo)(Bhi+Blo) [al*bl dropped] ----------------
// A staged in LDS (double-buffered); B read directly from packed global (L2-hot).
// K = 512 fixed (16 k-tiles of 32).
template<int SPLIT>
__device__ __forceinline__ void core3(const f16* Ahi, const f16* Alo,
                                      const f16* Bph, const f16* Bpl,
                                      f16* s0h, f16* s0l, f16* s1h, f16* s1l,
                                      int bm, int bnblk, int wid, int lane, int wr, int wc2,
                                      f32x4 (&acc)[4][4])
{
    const int r16 = lane & 15, sl = lane >> 4;
    const size_t bwoff = (size_t)(wc2 << 11) + lane * 8;
    f16x8 bAh[4], bAl[4], bBh[4], bBl[4];

    stage_tile(s0h, Ahi, bm, 0, wid, lane);
    if (SPLIT) stage_tile(s0l, Alo, bm, 0, wid, lane);
    loadBfr(bAh, Bph, (((size_t)bnblk << 4) << 12) + bwoff);
    if (SPLIT) loadBfr(bAl, Bpl, (((size_t)bnblk << 4) << 12) + bwoff);

#pragma unroll 1
    for (int kt = 0; kt < 16; kt += 2) {
        // ---- even step: buf0, bA ----
        __syncthreads();
        {
            const int kn = kt + 1;
            stage_tile(s1h, Ahi, bm, kn << 5, wid, lane);
            if (SPLIT) stage_tile(s1l, Alo, bm, kn << 5, wid, lane);
            loadBfr(bBh, Bph, ((((size_t)bnblk << 4) + kn) << 12) + bwoff);
            if (SPLIT) loadBfr(bBl, Bpl, ((((size_t)bnblk << 4) + kn) << 12) + bwoff);
        }
        f16x8 ah[4], al[4];
        readA(ah, s0h, wr, r16, sl);
        if (SPLIT) readA(al, s0l, wr, r16, sl);
        __builtin_amdgcn_s_setprio(1);
#pragma unroll
        for (int i = 0; i < 4; ++i)
#pragma unroll
            for (int j = 0; j < 4; ++j) {
                acc[i][j] = MM(ah[i], bAh[j], acc[i][j]);
                if (SPLIT) {
                    acc[i][j] = MM(al[i], bAh[j], acc[i][j]);
                    acc[i][j] = MM(ah[i], bAl[j], acc[i][j]);
                }
            }
        __builtin_amdgcn_s_setprio(0);
        // ---- odd step: buf1, bB ----
        __syncthreads();
        if (kt + 2 < 16) {
            const int kn = kt + 2;
            stage_tile(s0h, Ahi, bm, kn << 5, wid, lane);
            if (SPLIT) stage_tile(s0l, Alo, bm, kn << 5, wid, lane);
            loadBfr(bAh, Bph, ((((size_t)bnblk << 4) + kn) << 12) + bwoff);
            if (SPLIT) loadBfr(bAl, Bpl, ((((size_t)bnblk << 4) + kn) << 12) + bwoff);
        }
        readA(ah, s1h, wr, r16, sl);
        if (SPLIT) readA(al, s1l, wr, r16, sl);
        __builtin_amdgcn_s_setprio(1);
#pragma unroll
        for (int i = 0; i < 4; ++i)
#pragma unroll
            for (int j = 0; j < 4; ++j) {
                acc[i][j] = MM(ah[i], bBh[j], acc[i][j]);
                if (SPLIT) {
                    acc[i][j] = MM(al[i], bBh[j], acc[i][j]);
                    acc[i][j] = MM(ah[i], bBl[j], acc[i][j]);
                }
            }
        __builtin_amdgcn_s_setprio(0);
    }
}

// ---------------- dual-role fused gate kernel ----------------
// z=0 (when DO_L1): loop-1 gate for step t1 (winner gather from part = step t1-1),
//                   LSTM -> c1, h1 split; writes out0(t_out) one-hot when part != null.
// z=DO_L1 (when DO_L2): loop-2 gate for step t2 (same winners), LSTM -> c2, h2 f16,
//                   fused rowdot atomic into out1; writes out0(t_out) when !DO_L1 (last).
template<int DO_L1, int DO_L2>
__global__ __launch_bounds__(256, 2)
void fused_gate(const f16* __restrict__ a1hi, const f16* __restrict__ a1lo,
                const f16* __restrict__ a2hi,
                const f16* __restrict__ Wlp_hi, const f16* __restrict__ Wlp_lo,
                const float* __restrict__ blp,
                const float* __restrict__ gdown, const float* __restrict__ gdownl,
                const float2* __restrict__ part,
                float* __restrict__ out0, int t_out,
                float* __restrict__ c1, f16* __restrict__ o1hi, f16* __restrict__ o1lo,
                float* __restrict__ c2, f16* __restrict__ o2hi,
                const float* __restrict__ Woutl, float* __restrict__ out1, int t2)
{
    __shared__ f16 s[4][4096];
    __shared__ int winlds[128];
    int bx = blockIdx.x, by = blockIdx.y;
    swz_xcd(bx, by);
    const int bm = by << 7;
    const int tid = threadIdx.x;
    const int wid = tid >> 6, lane = tid & 63;
    const int wr = ((wid >> 1) & 1) << 6;
    const int wc2 = wid & 1;
    const bool isL1 = DO_L1 && (!DO_L2 || blockIdx.z == 0);

    if (part != nullptr && tid < 128) {
        const float2* p = part + (size_t)(bm + tid) * 8;
        float best = -INFINITY;
        int bi = 0x7fffffff;
#pragma unroll
        for (int q = 0; q < 8; ++q) {
            const float2 pv = p[q];
            if (pv.x > best || (pv.x == best && (int)pv.y < bi)) { best = pv.x; bi = (int)pv.y; }
        }
        winlds[tid] = bi;
    }

    f32x4 acc[4][4];
#pragma unroll
    for (int i = 0; i < 4; ++i)
#pragma unroll
        for (int j = 0; j < 4; ++j) acc[i][j] = (f32x4)(0.0f);

    const int m = lane & 15, rg = lane >> 4;
    const int colb = (bx << 7) + (wc2 << 6);
    const int jj = ((colb >> 6) << 4) + m;    // LSTM unit index (original space)
    float bi4[4];
#pragma unroll
    for (int g = 0; g < 4; ++g) bi4[g] = blp[colb + g * 16 + m];

    if (isL1) {
        core3<1>(a1hi, a1lo, Wlp_hi, Wlp_lo, s[0], s[1], s[2], s[3],
                 bm, bx, wid, lane, wr, wc2, acc);
#pragma unroll
        for (int i = 0; i < 4; ++i) {
#pragma unroll
            for (int r = 0; r < 4; ++r) {
                const int row = bm + wr + i * 16 + rg * 4 + r;
                float ex[4] = {0.f, 0.f, 0.f, 0.f};
                if (part != nullptr) {
                    const float* exr = gdown + (size_t)winlds[row - bm] * NG;
#pragma unroll
                    for (int g = 0; g < 4; ++g) ex[g] = exr[colb + g * 16 + m];
                }
                const float ig = acc[i][0][r] + bi4[0] + ex[0];
                const float gg = acc[i][1][r] + bi4[1] + ex[1];
                const float fg = acc[i][2][r] + bi4[2] + ex[2];
                const float og = acc[i][3][r] + bi4[3] + ex[3];
                const size_t cidx = (size_t)row * NH + jj;
                const float cx = c1[cidx];
                const float cy = cx * sigm(fg + 1.0f) + sigm(ig) * tanhf(gg);
                const float hy = sigm(og) * tanhf(cy);
                c1[cidx] = cy;
                const f16 a = (f16)hy;
                o1hi[cidx] = a;
                o1lo[cidx] = (f16)(hy - (float)a);
            }
        }
        // one-hot out0(t_out) for this block's 32-col slice
        if (part != nullptr) {
            const int rr = tid >> 1;
            const int cs = (bx << 5) + ((tid & 1) << 4);
            const int win = winlds[rr];
            float* orow = out0 + ((size_t)(bm + rr) * NRW + t_out) * NN + cs;
#pragma unroll
            for (int e = 0; e < 16; e += 4) {
                const int c0 = cs + e;
                *(float4*)(orow + e) = make_float4(c0 == win, c0 + 1 == win, c0 + 2 == win, c0 + 3 == win);
            }
        }
    } else {
        core3<0>(a2hi, nullptr, Wlp_hi, nullptr, s[0], nullptr, s[1], nullptr,
                 bm, bx, wid, lane, wr, wc2, acc);
        const float wout = Woutl[jj];
#pragma unroll
        for (int i = 0; i < 4; ++i) {
#pragma unroll
            for (int r = 0; r < 4; ++r) {
                const int row = bm + wr + i * 16 + rg * 4 + r;
                const float* exr = gdownl + (size_t)winlds[row - bm] * NG;
                float ex[4];
#pragma unroll
                for (int g = 0; g < 4; ++g) ex[g] = exr[colb + g * 16 + m];
                const float ig = acc[i][0][r] + bi4[0] + ex[0];
                const float gg = acc[i][1][r] + bi4[1] + ex[1];
                const float fg = acc[i][2][r] + bi4[2] + ex[2];
                const float og = acc[i][3][r] + bi4[3] + ex[3];
                const size_t cidx = (size_t)row * NH + jj;
                const float cx = c2[cidx];
                const float cy = cx * sigm(fg + 1.0f) + sigm(ig) * tanhf(gg);
                const float hy = sigm(og) * tanhf(cy);
                c2[cidx] = cy;
                o2hi[cidx] = (f16)hy;
                float pt = hy * wout;
#pragma unroll
                for (int msk = 1; msk < 16; msk <<= 1) pt += __shfl_xor(pt, msk);
                if (m == 0) atomicAdd(&out1[(size_t)row * NRW + t2], pt);
            }
        }
        if (!DO_L1) {   // last step: L2 blocks write out0(15)
            const int rr = tid >> 1;
            const int cs = (bx << 5) + ((tid & 1) << 4);
            const int win = winlds[rr];
            float* orow = out0 + ((size_t)(bm + rr) * NRW + t_out) * NN + cs;
#pragma unroll
            for (int e = 0; e < 16; e += 4) {
                const int c0 = cs + e;
                *(float4*)(orow + e) = make_float4(c0 == win, c0 + 1 == win, c0 + 2 == win, c0 + 3 == win);
            }
        }
    }
}

// ---------------- logits GEMM + fused gumbel-argmax partials ----------------
__global__ __launch_bounds__(256, 2)
void mfma_logits_argmax(const f16* __restrict__ Ahi, const f16* __restrict__ Alo,
                        const f16* __restrict__ Bph, const f16* __restrict__ Bpl,
                        const float* __restrict__ bias,
                        const float* __restrict__ gu,
                        float2* __restrict__ part, int t)
{
    __shared__ f16 s[4][4096];
    int bx = blockIdx.x, by = blockIdx.y;
    swz_xcd(bx, by);
    const int bm = by << 7;
    const int tid = threadIdx.x;
    const int wid = tid >> 6, lane = tid & 63;
    const int wr = ((wid >> 1) & 1) << 6;
    const int wc2 = wid & 1;

    f32x4 acc[4][4];
#pragma unroll
    for (int i = 0; i < 4; ++i)
#pragma unroll
        for (int j = 0; j < 4; ++j) acc[i][j] = (f32x4)(0.0f);

    core3<1>(Ahi, Alo, Bph, Bpl, s[0], s[1], s[2], s[3], bm, bx, wid, lane, wr, wc2, acc);

    const int r16 = lane & 15, rg = lane >> 4;
    const int cb = (bx << 1) + wc2;          // 64-col slice 0..7
    float bi[4];
#pragma unroll
    for (int j = 0; j < 4; ++j) bi[j] = bias[(bx << 7) + (wc2 << 6) + j * 16 + r16];

#pragma unroll
    for (int i = 0; i < 4; ++i) {
#pragma unroll
        for (int r = 0; r < 4; ++r) {
            const int row = bm + wr + i * 16 + rg * 4 + r;
            const float* urow = gu + ((size_t)t * NB + row) * NN;
            float best = -INFINITY;
            int bidx = 0x7fffffff;
#pragma unroll
            for (int j = 0; j < 4; ++j) {
                const int col = (bx << 7) + (wc2 << 6) + j * 16 + r16;
                const float u = urow[col];
                const float g = -logf(-logf(u + 1e-20f) + 1e-20f);
                const float v = acc[i][j][r] + bi[j] + g;
                if (v > best || (v == best && col < bidx)) { best = v; bidx = col; }
            }
#pragma unroll
            for (int msk = 1; msk < 16; msk <<= 1) {
                const float ov = __shfl_xor(best, msk);
                const int oi = __shfl_xor(bidx, msk);
                if (ov > best || (ov == best && oi < bidx)) { best = ov; bidx = oi; }
            }
            if (r16 == 0) part[(size_t)row * 8 + cb] = make_float2(best, (float)bidx);
        }
    }
}

// ---------------- init4: four [8192x512,K=512] split GEMMs (z-select), tanh epilogue ----------------
__global__ __launch_bounds__(256, 2)
void init4(const f16* __restrict__ i1hi, const f16* __restrict__ i1lo,
           const f16* __restrict__ i2hi, const f16* __restrict__ i2lo,
           const f16* __restrict__ Whp_hi, const f16* __restrict__ Whp_lo,
           const f16* __restrict__ Wcp_hi, const f16* __restrict__ Wcp_lo,
           const f16* __restrict__ Whlp_hi, const f16* __restrict__ Whlp_lo,
           const f16* __restrict__ Wclp_hi, const f16* __restrict__ Wclp_lo,
           const float* __restrict__ b_hup, const float* __restrict__ b_cup,
           const float* __restrict__ b_hupl, const float* __restrict__ b_cupl,
           float* __restrict__ c1, float* __restrict__ c2,
           f16* __restrict__ h1hi, f16* __restrict__ h1lo, f16* __restrict__ h2hi)
{
    __shared__ f16 s[4][4096];
    const int z = blockIdx.z;
    const f16 *Ahi, *Alo, *Bh, *Bl;
    const float* bias;
    switch (z) {
        case 0: Ahi = i1hi; Alo = i1lo; Bh = Whp_hi;  Bl = Whp_lo;  bias = b_hup;  break;
        case 1: Ahi = i1hi; Alo = i1lo; Bh = Wcp_hi;  Bl = Wcp_lo;  bias = b_cup;  break;
        case 2: Ahi = i2hi; Alo = i2lo; Bh = Whlp_hi; Bl = Whlp_lo; bias = b_hupl; break;
        default: Ahi = i2hi; Alo = i2lo; Bh = Wclp_hi; Bl = Wclp_lo; bias = b_cupl; break;
    }
    int bx = blockIdx.x, by = blockIdx.y;
    swz_xcd(bx, by);
    const int bm = by << 7;
    const int tid = threadIdx.x;
    const int wid = tid >> 6, lane = tid & 63;
    const int wr = ((wid >> 1) & 1) << 6;
    const int wc2 = wid & 1;

    f32x4 acc[4][4];
#pragma unroll
    for (int i = 0; i < 4; ++i)
#pragma unroll
        for (int j = 0; j < 4; ++j) acc[i][j] = (f32x4)(0.0f);

    core3<1>(Ahi, Alo, Bh, Bl, s[0], s[1], s[2], s[3], bm, bx, wid, lane, wr, wc2, acc);

    const int r16 = lane & 15, rg = lane >> 4;
#pragma unroll
    for (int i = 0; i < 4; ++i) {
#pragma unroll
        for (int r = 0; r < 4; ++r) {
            const int row = bm + wr + i * 16 + rg * 4 + r;
#pragma unroll
            for (int j = 0; j < 4; ++j) {
                const int col = (bx << 7) + (wc2 << 6) + j * 16 + r16;
                float v = tanhf(acc[i][j][r] + bias[col]);
                const size_t idx = (size_t)row * NH + col;
                if (z == 0) {
                    const f16 a = (f16)v;
                    h1hi[idx] = a;
                    h1lo[idx] = (f16)(v - (float)a);
                } else if (z == 1) c1[idx] = v;
                else if (z == 2) h2hi[idx] = (f16)v;
                else c2[idx] = v;
            }
        }
    }
}

// ---------------- latent init GEMM (f32 vector, K=128), tanh + split-f16 output; z selects ----------------
__global__ __launch_bounds__(256)
void gemm128_split(const float* __restrict__ A,
                   const float* __restrict__ W0, const float* __restrict__ b0,
                   const float* __restrict__ W1, const float* __restrict__ b1,
                   f16* __restrict__ o0hi, f16* __restrict__ o0lo,
                   f16* __restrict__ o1hi, f16* __restrict__ o1lo)
{
    const float* W = blockIdx.z ? W1 : W0;
    const float* bias = blockIdx.z ? b1 : b0;
    f16* ohi = blockIdx.z ? o1hi : o0hi;
    f16* olo = blockIdx.z ? o1lo : o0lo;
    __shared__ float As[16][128];
    __shared__ float Bs[16][128];
    const int bm = blockIdx.y << 7, bn = blockIdx.x << 7;
    const int tid = threadIdx.x;
    const int tx = tid & 15, ty = tid >> 4;
    const int sar = tid >> 1, sac = (tid & 1) << 3;
    const int sbk = tid >> 4, sbc = (tid & 15) << 3;
    float acc[2][2][4][4] = {};
    const float* Ap = A + (size_t)(bm + sar) * NZ + sac;
    const float* Wp = W + (size_t)sbk * NH + bn + sbc;
    for (int kb = 0; kb < NZ; kb += 16) {
        const float4 av0 = *(const float4*)(Ap + kb);
        const float4 av1 = *(const float4*)(Ap + kb + 4);
        const float4 bv0 = *(const float4*)(Wp + (size_t)kb * NH);
        const float4 bv1 = *(const float4*)(Wp + (size_t)kb * NH + 4);
        __syncthreads();
        As[sac + 0][sar] = av0.x; As[sac + 1][sar] = av0.y;
        As[sac + 2][sar] = av0.z; As[sac + 3][sar] = av0.w;
        As[sac + 4][sar] = av1.x; As[sac + 5][sar] = av1.y;
        As[sac + 6][sar] = av1.z; As[sac + 7][sar] = av1.w;
        *(float4*)&Bs[sbk][sbc] = bv0;
        *(float4*)&Bs[sbk][sbc + 4] = bv1;
        __syncthreads();
#pragma unroll
        for (int kk = 0; kk < 16; ++kk) {
            float a[2][4], b[2][4];
            *(float4*)a[0] = *(const float4*)&As[kk][ty << 2];
            *(float4*)a[1] = *(const float4*)&As[kk][64 + (ty << 2)];
            *(float4*)b[0] = *(const float4*)&Bs[kk][tx << 2];
            *(float4*)b[1] = *(const float4*)&Bs[kk][64 + (tx << 2)];
#pragma unroll
            for (int rh = 0; rh < 2; ++rh)
#pragma unroll
                for (int ch = 0; ch < 2; ++ch)
#pragma unroll
                    for (int i = 0; i < 4; ++i)
#pragma unroll
                        for (int j = 0; j < 4; ++j)
                            acc[rh][ch][i][j] = fmaf(a[rh][i], b[ch][j], acc[rh][ch][i][j]);
        }
    }
    float4 bi4[2];
    bi4[0] = *(const float4*)(bias + bn + (tx << 2));
    bi4[1] = *(const float4*)(bias + bn + 64 + (tx << 2));
    const float bia[2][4] = {{bi4[0].x, bi4[0].y, bi4[0].z, bi4[0].w},
                             {bi4[1].x, bi4[1].y, bi4[1].z, bi4[1].w}};
#pragma unroll
    for (int rh = 0; rh < 2; ++rh)
#pragma unroll
        for (int i = 0; i < 4; ++i) {
            const int row = bm + rh * 64 + (ty << 2) + i;
#pragma unroll
            for (int ch = 0; ch < 2; ++ch) {
                const int col = bn + ch * 64 + (tx << 2);
#pragma unroll
                for (int j = 0; j < 4; ++j) {
                    const float v = tanhf(acc[rh][ch][i][j] + bia[ch][j]);
                    const size_t idx = (size_t)row * NH + col + j;
                    const f16 a = (f16)v;
                    ohi[idx] = a;
                    olo[idx] = (f16)(v - (float)a);
                }
            }
        }
}

// ---------------- gdown pair: C = W_down{,l} @ W_lstm[:128] (f32 vector), permuted cols ----------------
__global__ __launch_bounds__(256)
void gemm128_gdown(const float* __restrict__ A0, const float* __restrict__ A1,
                   const float* __restrict__ W,
                   float* __restrict__ C0, float* __restrict__ C1)
{
    const float* A = blockIdx.z ? A1 : A0;
    float* C = blockIdx.z ? C1 : C0;
    __shared__ float As[16][128];
    __shared__ float Bs[16][128];
    const int bm = blockIdx.y << 7, bn = blockIdx.x << 7;
    const int tid = threadIdx.x;
    const int tx = tid & 15, ty = tid >> 4;
    const int sar = tid >> 1, sac = (tid & 1) << 3;
    const int sbk = tid >> 4, sbc = (tid & 15) << 3;
    float acc[2][2][4][4] = {};
    const float* Ap = A + (size_t)(bm + sar) * NIN + sac;
    const float* Wp = W + (size_t)sbk * NG + bn + sbc;
    for (int kb = 0; kb < NIN; kb += 16) {
        const float4 av0 = *(const float4*)(Ap + kb);
        const float4 av1 = *(const float4*)(Ap + kb + 4);
        const float4 bv0 = *(const float4*)(Wp + (size_t)kb * NG);
        const float4 bv1 = *(const float4*)(Wp + (size_t)kb * NG + 4);
        __syncthreads();
        As[sac + 0][sar] = av0.x; As[sac + 1][sar] = av0.y;
        As[sac + 2][sar] = av0.z; As[sac + 3][sar] = av0.w;
        As[sac + 4][sar] = av1.x; As[sac + 5][sar] = av1.y;
        As[sac + 6][sar] = av1.z; As[sac + 7][sar] = av1.w;
        *(float4*)&Bs[sbk][sbc] = bv0;
        *(float4*)&Bs[sbk][sbc + 4] = bv1;
        __syncthreads();
#pragma unroll
        for (int kk = 0; kk < 16; ++kk) {
            float a[2][4], b[2][4];
            *(float4*)a[0] = *(const float4*)&As[kk][ty << 2];
            *(float4*)a[1] = *(const float4*)&As[kk][64 + (ty << 2)];
            *(float4*)b[0] = *(const float4*)&Bs[kk][tx << 2];
            *(float4*)b[1] = *(const float4*)&Bs[kk][64 + (tx << 2)];
#pragma unroll
            for (int rh = 0; rh < 2; ++rh)
#pragma unroll
                for (int ch = 0; ch < 2; ++ch)
#pragma unroll
                    for (int i = 0; i < 4; ++i)
#pragma unroll
                        for (int j = 0; j < 4; ++j)
                            acc[rh][ch][i][j] = fmaf(a[rh][i], b[ch][j], acc[rh][ch][i][j]);
        }
    }
#pragma unroll
    for (int rh = 0; rh < 2; ++rh)
#pragma unroll
        for (int i = 0; i < 4; ++i) {
            const int row = bm + rh * 64 + (ty << 2) + i;
#pragma unroll
            for (int ch = 0; ch < 2; ++ch) {
                const int col = bn + ch * 64 + (tx << 2);
                *(float4*)(C + (size_t)row * NG + cperm(col)) =
                    make_float4(acc[rh][ch][i][0], acc[rh][ch][i][1],
                                acc[rh][ch][i][2], acc[rh][ch][i][3]);
            }
        }
}

// ---------------- pack all 6 weights (z-select): [K=512][Norig] f32 -> frag-major hi/lo f16 ----------------
__global__ __launch_bounds__(256)
void tsplit_pack_all(const float* __restrict__ Wl, const float* __restrict__ Wup,
                     const float* __restrict__ Whp, const float* __restrict__ Wcp,
                     const float* __restrict__ Whlp, const float* __restrict__ Wclp,
                     f16* __restrict__ Wlp_hi, f16* __restrict__ Wlp_lo,
                     f16* __restrict__ Wup_hi, f16* __restrict__ Wup_lo,
                     f16* __restrict__ Whp_hi, f16* __restrict__ Whp_lo,
                     f16* __restrict__ Wcp_hi, f16* __restrict__ Wcp_lo,
                     f16* __restrict__ Whlp_hi, f16* __restrict__ Whlp_lo,
                     f16* __restrict__ Wclp_hi, f16* __restrict__ Wclp_lo)
{
    const int z = blockIdx.z;
    const int nblkcnt = (z == 0) ? 16 : 4;
    if ((int)blockIdx.y >= nblkcnt) return;
    const float* src;
    int ldin, perm;
    f16 *ph, *pl;
    switch (z) {
        case 0: src = Wl;   ldin = NG; perm = 1; ph = Wlp_hi;  pl = Wlp_lo;  break;
        case 1: src = Wup;  ldin = NH; perm = 0; ph = Wup_hi;  pl = Wup_lo;  break;
        case 2: src = Whp;  ldin = NH; perm = 0; ph = Whp_hi;  pl = Whp_lo;  break;
        case 3: src = Wcp;  ldin = NH; perm = 0; ph = Wcp_hi;  pl = Wcp_lo;  break;
        case 4: src = Whlp; ldin = NH; perm = 0; ph = Whlp_hi; pl = Whlp_lo; break;
        default: src = Wclp; ldin = NH; perm = 0; ph = Wclp_hi; pl = Wclp_lo; break;
    }
    const int kt = blockIdx.x;
    const int nblk = blockIdx.y;
#pragma unroll
    for (int q = 0; q < 2; ++q) {
        const int cch = threadIdx.x + q * 256;
        const int wc2 = cch >> 8, f = (cch >> 6) & 3, slc = (cch >> 4) & 3, r16 = cch & 15;
        const int n = (nblk << 7) + (wc2 << 6) + (f << 4) + r16;
        const int ncol = perm ? oc_of(n) : n;
        const int k0 = (kt << 5) + (slc << 3);
        f16x8 h8, l8;
#pragma unroll
        for (int e = 0; e < 8; ++e) {
            const float v = src[(size_t)(k0 + e) * ldin + ncol];
            const f16 hi = (f16)v;
            h8[e] = hi;
            l8[e] = (f16)(v - (float)hi);
        }
        const size_t off = ((((size_t)nblk << 4) + kt) << 12) + (size_t)cch * 8;
        *(f16x8*)(ph + off) = h8;
        *(f16x8*)(pl + off) = l8;
    }
}

// ---------------- bias permute ----------------
__global__ __launch_bounds__(256)
void permb(const float* __restrict__ b, float* __restrict__ bp)
{
    const int c = blockIdx.x * 256 + threadIdx.x;
    bp[c] = b[oc_of(c)];
}

// ---------------- out1 init to b_outl ----------------
__global__ __launch_bounds__(256)
void out1_init(float* __restrict__ out1, const float* __restrict__ boutl)
{
    const size_t i = (size_t)blockIdx.x * 256 + threadIdx.x;
    out1[i] = boutl[0];
}

extern "C" void kernel_launch(void* const* d_in, const int* in_sizes, int n_in,
                              void* d_out, int out_size, void* d_ws, size_t ws_size,
                              hipStream_t stream)
{
    const float* latent  = (const float*)d_in[0];
    const float* gu      = (const float*)d_in[2];
    const float* W_int   = (const float*)d_in[3];
    const float* b_int   = (const float*)d_in[4];
    const float* W_intl  = (const float*)d_in[5];
    const float* b_intl  = (const float*)d_in[6];
    const float* W_hup   = (const float*)d_in[7];
    const float* b_hup   = (const float*)d_in[8];
    const float* W_cup   = (const float*)d_in[9];
    const float* b_cup   = (const float*)d_in[10];
    const float* W_hupl  = (const float*)d_in[11];
    const float* b_hupl  = (const float*)d_in[12];
    const float* W_cupl  = (const float*)d_in[13];
    const float* b_cupl  = (const float*)d_in[14];
    const float* W_lstm  = (const float*)d_in[15];
    const float* b_lstm  = (const float*)d_in[16];
    const float* W_up    = (const float*)d_in[17];
    const float* b_up    = (const float*)d_in[18];
    const float* W_down  = (const float*)d_in[19];
    const float* W_downl = (const float*)d_in[20];
    const float* W_outl  = (const float*)d_in[21];
    const float* b_outl  = (const float*)d_in[22];

    float* out0 = (float*)d_out;                 // [B, RW, N]
    float* out1 = out0 + (size_t)NB * NRW * NN;  // [B, RW, 1]

    // workspace
    float* ws     = (float*)d_ws;
    float* c1     = ws;                               // NB*NH
    float* c2     = c1 + (size_t)NB * NH;             // NB*NH
    float* gdown  = c2 + (size_t)NB * NH;             // NN*NG (permuted cols)
    float* gdownl = gdown + (size_t)NN * NG;          // NN*NG
    float* blp    = gdownl + (size_t)NN * NG;         // NG
    float2* part  = (float2*)(blp + NG);              // NB*8
    f16* fp = (f16*)(part + (size_t)NB * 8);
    f16* h1hi[2]; f16* h1lo[2]; f16* h2hi[2];
    h1hi[0] = fp;                    fp += (size_t)NB * NH;
    h1lo[0] = fp;                    fp += (size_t)NB * NH;
    h1hi[1] = fp;                    fp += (size_t)NB * NH;
    h1lo[1] = fp;                    fp += (size_t)NB * NH;
    h2hi[0] = fp;                    fp += (size_t)NB * NH;
    h2hi[1] = fp;                    fp += (size_t)NB * NH;
    f16* i1hi = fp;                  fp += (size_t)NB * NH;
    f16* i1lo = fp;                  fp += (size_t)NB * NH;
    f16* i2hi = fp;                  fp += (size_t)NB * NH;
    f16* i2lo = fp;                  fp += (size_t)NB * NH;
    f16* Wlp_hi = fp;                fp += (size_t)NG * NH;   // packed, gate-perm
    f16* Wlp_lo = fp;                fp += (size_t)NG * NH;
    f16* Wup_hi = fp;                fp += (size_t)NN * NH;
    f16* Wup_lo = fp;                fp += (size_t)NN * NH;
    f16* Whp_hi = fp;                fp += (size_t)NH * NH;
    f16* Whp_lo = fp;                fp += (size_t)NH * NH;
    f16* Wcp_hi = fp;                fp += (size_t)NH * NH;
    f16* Wcp_lo = fp;                fp += (size_t)NH * NH;
    f16* Whlp_hi = fp;               fp += (size_t)NH * NH;
    f16* Whlp_lo = fp;               fp += (size_t)NH * NH;
    f16* Wclp_hi = fp;               fp += (size_t)NH * NH;
    f16* Wclp_lo = fp;               fp += (size_t)NH * NH;

    const dim3 blk(256);

    // ---- prep (6 launches) ----
    tsplit_pack_all<<<dim3(16, 16, 6), blk, 0, stream>>>(
        W_lstm + (size_t)NIN * NG, W_up, W_hup, W_cup, W_hupl, W_cupl,
        Wlp_hi, Wlp_lo, Wup_hi, Wup_lo, Whp_hi, Whp_lo, Wcp_hi, Wcp_lo,
        Whlp_hi, Whlp_lo, Wclp_hi, Wclp_lo);
    permb<<<dim3(NG / 256), blk, 0, stream>>>(b_lstm, blp);
    gemm128_gdown<<<dim3(NG / 128, NN / 128, 2), blk, 0, stream>>>(W_down, W_downl, W_lstm,
                                                                   gdown, gdownl);
    gemm128_split<<<dim3(NH / 128, NB / 128, 2), blk, 0, stream>>>(latent, W_int, b_int,
                                                                   W_intl, b_intl,
                                                                   i1hi, i1lo, i2hi, i2lo);
    init4<<<dim3(NH / 128, NB / 128, 4), blk, 0, stream>>>(
        i1hi, i1lo, i2hi, i2lo,
        Whp_hi, Whp_lo, Wcp_hi, Wcp_lo, Whlp_hi, Whlp_lo, Wclp_hi, Wclp_lo,
        b_hup, b_cup, b_hupl, b_cupl,
        c1, c2, h1hi[0], h1lo[0], h2hi[0]);
    out1_init<<<dim3(NB * NRW / 256), blk, 0, stream>>>(out1, b_outl);

    const dim3 g1(NG / 128, NB / 128, 1);     // 16 x 64
    const dim3 g2(NG / 128, NB / 128, 2);
    const dim3 gl(NN / 128, NB / 128);        // 4 x 64

    // ---- t=0 loop-1 gate (x-contribution is zero: inputs == 0) ----
    fused_gate<1, 0><<<g1, blk, 0, stream>>>(h1hi[0], h1lo[0], nullptr,
                                             Wlp_hi, Wlp_lo, blp, gdown, gdownl,
                                             nullptr, out0, 0,
                                             c1, h1hi[1], h1lo[1],
                                             nullptr, nullptr, nullptr, nullptr, 0);
    mfma_logits_argmax<<<gl, blk, 0, stream>>>(h1hi[1], h1lo[1], Wup_hi, Wup_lo,
                                               b_up, gu, part, 0);

    int c1i = 1, c2i = 0;   // current h1 / h2 buffer indices
    for (int t = 0; t < NRW - 1; ++t) {
        const int n1 = c1i ^ 1, n2 = c2i ^ 1;
        fused_gate<1, 1><<<g2, blk, 0, stream>>>(h1hi[c1i], h1lo[c1i], h2hi[c2i],
                                                 Wlp_hi, Wlp_lo, blp, gdown, gdownl,
                                                 part, out0, t,
                                                 c1, h1hi[n1], h1lo[n1],
                                                 c2, h2hi[n2], W_outl, out1, t);
        mfma_logits_argmax<<<gl, blk, 0, stream>>>(h1hi[n1], h1lo[n1], Wup_hi, Wup_lo,
                                                   b_up, gu, part, t + 1);
        c1i = n1;
        c2i = n2;
    }
    // ---- last: loop-2 gate for t=15 + one-hot out0(15) ----
    fused_gate<0, 1><<<g1, blk, 0, stream>>>(nullptr, nullptr, h2hi[c2i],
                                             Wlp_hi, Wlp_lo, blp, gdown, gdownl,
                                             part, out0, NRW - 1,
                                             nullptr, nullptr, nullptr,
                                             c2, h2hi[c2i ^ 1], W_outl, out1, NRW - 1);
}